// Round 1
// baseline (5578.111 us; speedup 1.0000x reference)
//
#include <hip/hip_runtime.h>
#include <cstdint>

// ---------- types ----------
typedef __bf16 bf16x8 __attribute__((ext_vector_type(8)));
typedef float  f32x4  __attribute__((ext_vector_type(4)));

// B=2, S=512, D=1024, H=16, HD=64, L=12, V=50257, DFF=4096

__device__ __forceinline__ float gelu_f(float x) {
    // tanh-approx gelu; tanh via exp2-based __expf, no NaN at large |x|
    float u = 1.5957691216057308f * (x + 0.044715f * x * x * x); // 2*sqrt(2/pi)*(...)
    float e = __expf(u);
    float t = 1.0f - 2.0f / (e + 1.0f);     // tanh(u/2)
    return 0.5f * x * (1.0f + t);
}

// ---------- small GEMV path (img projections), deterministic ksplit ----------
// part[((z*8 + kz)*2 + b)*N + j]
__global__ __launch_bounds__(256) void gemv_part(
    const float* __restrict__ x, int xld,
    const float* __restrict__ W, long wzs,
    float* __restrict__ part, int K, int N)
{
    int jb = blockIdx.x, kz = blockIdx.y, z = blockIdx.z;
    int t = threadIdx.x;
    int j = (jb << 6) + (t & 63);
    int g = t >> 6;
    int klen = K / (gridDim.y * 4);        // 1024/(8*4)=32
    int kbase = (kz * 4 + g) * klen;
    const float* Wp = W + (long)z * wzs + (long)kbase * N + j;
    const float* x0 = x + kbase;
    const float* x1 = x + xld + kbase;
    float a0 = 0.f, a1 = 0.f;
    for (int k = 0; k < klen; k++) {
        float wv = Wp[(long)k * N];
        a0 += x0[k] * wv;
        a1 += x1[k] * wv;
    }
    __shared__ float r0[4][64], r1[4][64];
    r0[g][t & 63] = a0; r1[g][t & 63] = a1;
    __syncthreads();
    if (t < 64) {
        a0 = r0[0][t] + r0[1][t] + r0[2][t] + r0[3][t];
        a1 = r1[0][t] + r1[1][t] + r1[2][t] + r1[3][t];
        long base = (long)(z * gridDim.y + kz) * 2 * N + (jb << 6) + t;
        part[base]     = a0;
        part[base + N] = a1;
    }
}

__global__ __launch_bounds__(256) void gemv_reduce(
    const float* __restrict__ part, const float* __restrict__ bias, long bzs,
    float* __restrict__ out, int N, int nz, int act)
{
    int idx = blockIdx.x * 256 + threadIdx.x;     // over nz*2*N
    if (idx >= nz * 2 * N) return;
    int j  = idx % N;
    int bz = idx / N;        // z*2 + b
    int z  = bz >> 1;
    float s = bias[(long)z * bzs + j];
    const float* p = part + ((long)z * 8 * 2 + (bz & 1)) * N + j;
    #pragma unroll
    for (int kz = 0; kz < 8; kz++) s += p[(long)kz * 2 * N];
    if (act) s = fmaxf(s, 0.f);
    out[idx] = s;
}

// ---------- embedding: h = wte[ids] + wte[arange(S)] ----------
__global__ __launch_bounds__(256) void embed_k(
    const int* __restrict__ ids, const float* __restrict__ wte, float* __restrict__ h)
{
    int row = blockIdx.x;          // b*512 + s
    int s = row & 511;
    int t = threadIdx.x;
    long id = ids[row];
    const float4* w1 = reinterpret_cast<const float4*>(wte + id * 1024);
    const float4* w2 = reinterpret_cast<const float4*>(wte + (long)s * 1024);
    float4 v1 = w1[t], v2 = w2[t];
    float4 o; o.x = v1.x + v2.x; o.y = v1.y + v2.y; o.z = v1.z + v2.z; o.w = v1.w + v2.w;
    reinterpret_cast<float4*>(h + (long)row * 1024)[t] = o;
}

// ---------- LayerNorm over D=1024 ----------
__global__ __launch_bounds__(256) void ln_k(
    const float* __restrict__ in, float* __restrict__ out,
    const float* __restrict__ g, const float* __restrict__ b)
{
    int row = blockIdx.x, t = threadIdx.x;
    float4 v = reinterpret_cast<const float4*>(in + (long)row * 1024)[t];
    float s1 = v.x + v.y + v.z + v.w;
    float s2 = v.x * v.x + v.y * v.y + v.z * v.z + v.w * v.w;
    #pragma unroll
    for (int o = 32; o >= 1; o >>= 1) { s1 += __shfl_xor(s1, o); s2 += __shfl_xor(s2, o); }
    __shared__ float r1[4], r2[4];
    int w = t >> 6;
    if ((t & 63) == 0) { r1[w] = s1; r2[w] = s2; }
    __syncthreads();
    s1 = r1[0] + r1[1] + r1[2] + r1[3];
    s2 = r2[0] + r2[1] + r2[2] + r2[3];
    float mean = s1 * (1.0f / 1024.0f);
    float var  = s2 * (1.0f / 1024.0f) - mean * mean;
    float rstd = rsqrtf(var + 1e-5f);
    float4 gg = reinterpret_cast<const float4*>(g)[t];
    float4 bb = reinterpret_cast<const float4*>(b)[t];
    float4 o;
    o.x = (v.x - mean) * rstd * gg.x + bb.x;
    o.y = (v.y - mean) * rstd * gg.y + bb.y;
    o.z = (v.z - mean) * rstd * gg.z + bb.z;
    o.w = (v.w - mean) * rstd * gg.w + bb.w;
    reinterpret_cast<float4*>(out + (long)row * 1024)[t] = o;
}

// ---------- bf16 MFMA GEMM, C = act(A@W + bias) (+res). A:[M,K] W:[K,N] f32 ----------
// 64x64 tile, 4 waves, BK=32, mfma_f32_16x16x32_bf16
__global__ __launch_bounds__(256) void gemm_nn(
    const float* __restrict__ A, const float* __restrict__ W,
    const float* __restrict__ bias, const float* __restrict__ res,
    float* __restrict__ C, int M, int N, int K, int act)
{
    __shared__ __bf16 As[64][40];   // +8 pad, keeps 16B alignment
    __shared__ __bf16 Bs[64][40];   // stored transposed: Bs[n][k]
    const int t = threadIdx.x;
    const int m0 = blockIdx.x << 6;
    const int n0 = blockIdx.y << 6;
    const int w = t >> 6;
    const int lane = t & 63;
    const int ar  = t >> 2;            // A stage: row 0..63
    const int akk = (t & 3) << 3;      // A stage: k 0/8/16/24
    const int bn  = t & 63;            // B stage: col
    const int bkg = (t >> 6) << 3;     // B stage: k group

    f32x4 acc[4] = {};
    const int frow  = w * 16 + (lane & 15);
    const int fkoff = (lane >> 4) << 3;

    for (int k0 = 0; k0 < K; k0 += 32) {
        const float* ap = A + (long)(m0 + ar) * K + k0 + akk;
        float4 a0 = *reinterpret_cast<const float4*>(ap);
        float4 a1 = *reinterpret_cast<const float4*>(ap + 4);
        bf16x8 av;
        av[0] = (__bf16)a0.x; av[1] = (__bf16)a0.y; av[2] = (__bf16)a0.z; av[3] = (__bf16)a0.w;
        av[4] = (__bf16)a1.x; av[5] = (__bf16)a1.y; av[6] = (__bf16)a1.z; av[7] = (__bf16)a1.w;

        const float* wp = W + (long)(k0 + bkg) * N + n0 + bn;
        bf16x8 bv;
        #pragma unroll
        for (int i = 0; i < 8; i++) bv[i] = (__bf16)wp[(long)i * N];

        __syncthreads();
        *reinterpret_cast<bf16x8*>(&As[ar][akk]) = av;
        *reinterpret_cast<bf16x8*>(&Bs[bn][bkg]) = bv;
        __syncthreads();

        bf16x8 af = *reinterpret_cast<const bf16x8*>(&As[frow][fkoff]);
        #pragma unroll
        for (int j = 0; j < 4; j++) {
            bf16x8 bfr = *reinterpret_cast<const bf16x8*>(&Bs[j * 16 + (lane & 15)][fkoff]);
            acc[j] = __builtin_amdgcn_mfma_f32_16x16x32_bf16(af, bfr, acc[j], 0, 0, 0);
        }
    }

    const int r0r = w * 16 + ((lane >> 4) << 2);
    const int cc  = lane & 15;
    #pragma unroll
    for (int j = 0; j < 4; j++) {
        int cg = n0 + j * 16 + cc;
        #pragma unroll
        for (int r = 0; r < 4; r++) {
            int rg = m0 + r0r + r;
            float v = acc[j][r];
            if (bias) v += bias[cg];
            if (act)  v = gelu_f(v);
            if (res)  v += res[(long)rg * N + cg];
            C[(long)rg * N + cg] = v;
        }
    }
}

// ---------- bf16 MFMA GEMM, C = A @ Wt^T. Wt:[N,K] f32 (LM head, N=50257) ----------
__global__ __launch_bounds__(256) void gemm_nt(
    const float* __restrict__ A, const float* __restrict__ Wt,
    float* __restrict__ C, int M, int N, int K)
{
    __shared__ __bf16 As[64][40];
    __shared__ __bf16 Bs[64][40];
    const int t = threadIdx.x;
    const int m0 = blockIdx.x << 6;
    const int n0 = blockIdx.y << 6;
    const int w = t >> 6;
    const int lane = t & 63;
    const int ar  = t >> 2;
    const int akk = (t & 3) << 3;
    const int bn  = t & 63;
    const int bkg = (t >> 6) << 3;

    f32x4 acc[4] = {};
    const int frow  = w * 16 + (lane & 15);
    const int fkoff = (lane >> 4) << 3;
    const bool bok = (n0 + bn) < N;

    for (int k0 = 0; k0 < K; k0 += 32) {
        const float* ap = A + (long)(m0 + ar) * K + k0 + akk;
        float4 a0 = *reinterpret_cast<const float4*>(ap);
        float4 a1 = *reinterpret_cast<const float4*>(ap + 4);
        bf16x8 av;
        av[0] = (__bf16)a0.x; av[1] = (__bf16)a0.y; av[2] = (__bf16)a0.z; av[3] = (__bf16)a0.w;
        av[4] = (__bf16)a1.x; av[5] = (__bf16)a1.y; av[6] = (__bf16)a1.z; av[7] = (__bf16)a1.w;

        bf16x8 bv;
        if (bok) {
            const float* wp = Wt + (long)(n0 + bn) * K + k0 + bkg;
            float4 b0 = *reinterpret_cast<const float4*>(wp);
            float4 b1 = *reinterpret_cast<const float4*>(wp + 4);
            bv[0] = (__bf16)b0.x; bv[1] = (__bf16)b0.y; bv[2] = (__bf16)b0.z; bv[3] = (__bf16)b0.w;
            bv[4] = (__bf16)b1.x; bv[5] = (__bf16)b1.y; bv[6] = (__bf16)b1.z; bv[7] = (__bf16)b1.w;
        } else {
            #pragma unroll
            for (int i = 0; i < 8; i++) bv[i] = (__bf16)0.f;
        }

        __syncthreads();
        *reinterpret_cast<bf16x8*>(&As[ar][akk]) = av;
        *reinterpret_cast<bf16x8*>(&Bs[bn][bkg]) = bv;
        __syncthreads();

        bf16x8 af = *reinterpret_cast<const bf16x8*>(&As[frow][fkoff]);
        #pragma unroll
        for (int j = 0; j < 4; j++) {
            bf16x8 bfr = *reinterpret_cast<const bf16x8*>(&Bs[j * 16 + (lane & 15)][fkoff]);
            acc[j] = __builtin_amdgcn_mfma_f32_16x16x32_bf16(af, bfr, acc[j], 0, 0, 0);
        }
    }

    const int r0r = w * 16 + ((lane >> 4) << 2);
    const int cc  = lane & 15;
    #pragma unroll
    for (int j = 0; j < 4; j++) {
        int cg = n0 + j * 16 + cc;
        if (cg < N) {
            #pragma unroll
            for (int r = 0; r < 4; r++) {
                int rg = m0 + r0r + r;
                C[(long)rg * N + cg] = acc[j][r];
            }
        }
    }
}

// ---------- attention: one wave per (b, head, query-row) ----------
// keys j=0 -> image token (imgk_l/imgv_l), j>=1 -> qkv row j-1 (k at +D, v at +2D)
__global__ __launch_bounds__(64) void attn_k(
    const float* __restrict__ qkv,
    const float* __restrict__ imgk_l, const float* __restrict__ imgv_l,
    const float* __restrict__ amask, float* __restrict__ out)
{
    const int i  = blockIdx.x;    // 0..511
    const int hh = blockIdx.y;    // 0..15
    const int b  = blockIdx.z;    // 0..1
    const int lane = threadIdx.x;

    __shared__ float qs[64];
    __shared__ float ps[513];

    qs[lane] = qkv[(long)(b * 512 + i) * 3072 + hh * 64 + lane];
    __syncthreads();

    const int nk = i + 2;   // valid keys: j=0..i+1
    float svals[9];
    float lmax = -1e30f;
    int cnt = 0;
    for (int j = lane; j < nk; j += 64) {
        const float* kp = (j == 0)
            ? (imgk_l + b * 1024 + hh * 64)
            : (qkv + (long)(b * 512 + (j - 1)) * 3072 + 1024 + hh * 64);
        float s = 0.f;
        #pragma unroll
        for (int d = 0; d < 64; d++) s += qs[d] * kp[d];
        s *= 0.125f;
        if (j >= 1) s += (1.0f - amask[b * 512 + (j - 1)]) * -10000.0f;
        svals[cnt++] = s;
        lmax = fmaxf(lmax, s);
    }
    #pragma unroll
    for (int o = 32; o >= 1; o >>= 1) lmax = fmaxf(lmax, __shfl_xor(lmax, o));

    float lsum = 0.f;
    cnt = 0;
    for (int j = lane; j < nk; j += 64) {
        float p = __expf(svals[cnt++] - lmax);
        ps[j] = p;
        lsum += p;
    }
    #pragma unroll
    for (int o = 32; o >= 1; o >>= 1) lsum += __shfl_xor(lsum, o);
    __syncthreads();

    float inv = 1.0f / lsum;
    float acc = ps[0] * imgv_l[b * 1024 + hh * 64 + lane];
    const float* vp = qkv + (long)(b * 512) * 3072 + 2048 + hh * 64 + lane;
    for (int j = 1; j < nk; j++) acc += ps[j] * vp[(long)(j - 1) * 3072];
    out[(long)(b * 512 + i) * 1024 + hh * 64 + lane] = acc * inv;
}

// ---------- host orchestration ----------
extern "C" void kernel_launch(void* const* d_in, const int* in_sizes, int n_in,
                              void* d_out, int out_size, void* d_ws, size_t ws_size,
                              hipStream_t stream) {
    (void)in_sizes; (void)n_in; (void)out_size; (void)ws_size;
    const int*   ids   = (const int*)d_in[0];
    const float* amask = (const float*)d_in[1];
    const float* ihs   = (const float*)d_in[2];
    const float* wte   = (const float*)d_in[3];
    const float* ftW1  = (const float*)d_in[4];
    const float* ftb1  = (const float*)d_in[5];
    const float* ftW2  = (const float*)d_in[6];
    const float* ftb2  = (const float*)d_in[7];
    const float* ln1g  = (const float*)d_in[8];
    const float* ln1b  = (const float*)d_in[9];
    const float* Wattn = (const float*)d_in[10];
    const float* battn = (const float*)d_in[11];
    const float* Wuk   = (const float*)d_in[12];
    const float* buk   = (const float*)d_in[13];
    const float* Wuv   = (const float*)d_in[14];
    const float* buv   = (const float*)d_in[15];
    const float* Wproj = (const float*)d_in[16];
    const float* bproj = (const float*)d_in[17];
    const float* ln2g  = (const float*)d_in[18];
    const float* ln2b  = (const float*)d_in[19];
    const float* Wfc   = (const float*)d_in[20];
    const float* bfc   = (const float*)d_in[21];
    const float* Wfc2  = (const float*)d_in[22];
    const float* bfc2  = (const float*)d_in[23];
    const float* lnfg  = (const float*)d_in[24];
    const float* lnfb  = (const float*)d_in[25];
    float* out = (float*)d_out;
    float* ws  = (float*)d_ws;

    float* ftmp  = ws + 0;          // 2048
    float* img   = ws + 2048;       // 2048
    float* imgk  = ws + 4096;       // 12*2*1024
    float* imgv  = ws + 28672;      // 12*2*1024
    float* part  = ws + 53248;      // 12*8*2*1024
    float* h     = ws + 249856;     // 1024*1024
    float* x     = ws + 1298432;    // 1024*1024
    float* qkv   = ws + 2347008;    // 1024*3072
    float* attno = ws + 5492736;    // 1024*1024
    float* ff    = ws + 6541312;    // 1024*4096

    dim3 b256(256);

    // image feature transform: relu(ihs@W1+b1)@W2+b2
    gemv_part<<<dim3(16, 8, 1), b256, 0, stream>>>(ihs, 1024, ftW1, 0, part, 1024, 1024);
    gemv_reduce<<<dim3(8), b256, 0, stream>>>(part, ftb1, 0, ftmp, 1024, 1, 1);
    gemv_part<<<dim3(16, 8, 1), b256, 0, stream>>>(ftmp, 1024, ftW2, 0, part, 1024, 1024);
    gemv_reduce<<<dim3(8), b256, 0, stream>>>(part, ftb2, 0, img, 1024, 1, 0);
    // per-layer image K/V projections, batched over all 12 layers
    gemv_part<<<dim3(16, 8, 12), b256, 0, stream>>>(img, 1024, Wuk, 1024L * 1024, part, 1024, 1024);
    gemv_reduce<<<dim3(96), b256, 0, stream>>>(part, buk, 1024, imgk, 1024, 12, 0);
    gemv_part<<<dim3(16, 8, 12), b256, 0, stream>>>(img, 1024, Wuv, 1024L * 1024, part, 1024, 1024);
    gemv_reduce<<<dim3(96), b256, 0, stream>>>(part, buv, 1024, imgv, 1024, 12, 0);

    embed_k<<<dim3(1024), b256, 0, stream>>>(ids, wte, h);

    for (int l = 0; l < 12; l++) {
        ln_k<<<dim3(1024), b256, 0, stream>>>(h, x, ln1g + l * 1024, ln1b + l * 1024);
        gemm_nn<<<dim3(16, 48), b256, 0, stream>>>(x, Wattn + (long)l * 1024 * 3072,
                                                   battn + l * 3072, nullptr, qkv,
                                                   1024, 3072, 1024, 0);
        attn_k<<<dim3(512, 16, 2), dim3(64), 0, stream>>>(qkv, imgk + l * 2048, imgv + l * 2048,
                                                          amask, attno);
        gemm_nn<<<dim3(16, 16), b256, 0, stream>>>(attno, Wproj + (long)l * 1024 * 1024,
                                                   bproj + l * 1024, h, h,
                                                   1024, 1024, 1024, 0);
        ln_k<<<dim3(1024), b256, 0, stream>>>(h, x, ln2g + l * 1024, ln2b + l * 1024);
        gemm_nn<<<dim3(16, 64), b256, 0, stream>>>(x, Wfc + (long)l * 1024 * 4096,
                                                   bfc + l * 4096, nullptr, ff,
                                                   1024, 4096, 1024, 1);
        gemm_nn<<<dim3(16, 16), b256, 0, stream>>>(ff, Wfc2 + (long)l * 4096 * 1024,
                                                   bfc2 + l * 1024, h, h,
                                                   1024, 1024, 4096, 0);
    }

    ln_k<<<dim3(1024), b256, 0, stream>>>(h, x, lnfg, lnfb);
    gemm_nt<<<dim3(16, 786), b256, 0, stream>>>(x, wte, out, 1024, 50257, 1024);
}

// Round 2
// 2747.117 us; speedup vs baseline: 2.0305x; 2.0305x over previous
//
#include <hip/hip_runtime.h>
#include <cstdint>

// B=2, S=512, D=1024, H=16, HD=64, L=12, V=50257, DFF=4096

typedef __bf16 bf16x8 __attribute__((ext_vector_type(8)));
typedef __bf16 bf16x4 __attribute__((ext_vector_type(4)));
typedef float  f32x4  __attribute__((ext_vector_type(4)));

#define GLDS16(g, l) __builtin_amdgcn_global_load_lds( \
    (const __attribute__((address_space(1))) unsigned int*)(g), \
    (__attribute__((address_space(3))) unsigned int*)(l), 16, 0, 0)

__device__ __forceinline__ float gelu_f(float x) {
    float u = 1.5957691216057308f * (x + 0.044715f * x * x * x);
    float e = __expf(u);
    float t = 1.0f - 2.0f / (e + 1.0f);
    return 0.5f * x * (1.0f + t);
}

// ---------- transpose+convert: W[K][N] f32 -> Wt[N][K] bf16 ----------
__global__ __launch_bounds__(256) void tcvt(
    const float* __restrict__ W, __bf16* __restrict__ Wt, int K, int N)
{
    __shared__ float tile[32][33];
    const int k0 = blockIdx.x * 32, n0 = blockIdx.y * 32;
    const int t = threadIdx.x;
    const int r = t >> 3, c4 = (t & 7) * 4;
    float4 v = *reinterpret_cast<const float4*>(W + (long)(k0 + r) * N + n0 + c4);
    tile[r][c4] = v.x; tile[r][c4 + 1] = v.y; tile[r][c4 + 2] = v.z; tile[r][c4 + 3] = v.w;
    __syncthreads();
    bf16x4 o;
    o[0] = (__bf16)tile[c4][r];
    o[1] = (__bf16)tile[c4 + 1][r];
    o[2] = (__bf16)tile[c4 + 2][r];
    o[3] = (__bf16)tile[c4 + 3][r];
    *reinterpret_cast<bf16x4*>(Wt + (long)(n0 + r) * K + k0 + c4) = o;
}

// ---------- small GEMV path (img projections), deterministic ksplit ----------
__global__ __launch_bounds__(256) void gemv_part(
    const float* __restrict__ x, int xld,
    const float* __restrict__ W, long wzs,
    float* __restrict__ part, int K, int N)
{
    int jb = blockIdx.x, kz = blockIdx.y, z = blockIdx.z;
    int t = threadIdx.x;
    int j = (jb << 6) + (t & 63);
    int g = t >> 6;
    int klen = K / (gridDim.y * 4);
    int kbase = (kz * 4 + g) * klen;
    const float* Wp = W + (long)z * wzs + (long)kbase * N + j;
    const float* x0 = x + kbase;
    const float* x1 = x + xld + kbase;
    float a0 = 0.f, a1 = 0.f;
    for (int k = 0; k < klen; k++) {
        float wv = Wp[(long)k * N];
        a0 += x0[k] * wv;
        a1 += x1[k] * wv;
    }
    __shared__ float r0[4][64], r1[4][64];
    r0[g][t & 63] = a0; r1[g][t & 63] = a1;
    __syncthreads();
    if (t < 64) {
        a0 = r0[0][t] + r0[1][t] + r0[2][t] + r0[3][t];
        a1 = r1[0][t] + r1[1][t] + r1[2][t] + r1[3][t];
        long base = (long)(z * gridDim.y + kz) * 2 * N + (jb << 6) + t;
        part[base]     = a0;
        part[base + N] = a1;
    }
}

__global__ __launch_bounds__(256) void gemv_reduce(
    const float* __restrict__ part, const float* __restrict__ bias, long bzs,
    float* __restrict__ out, int N, int nz, int act)
{
    int idx = blockIdx.x * 256 + threadIdx.x;
    if (idx >= nz * 2 * N) return;
    int j  = idx % N;
    int bz = idx / N;
    int z  = bz >> 1;
    float s = bias[(long)z * bzs + j];
    const float* p = part + ((long)z * 8 * 2 + (bz & 1)) * N + j;
    #pragma unroll
    for (int kz = 0; kz < 8; kz++) s += p[(long)kz * 2 * N];
    if (act) s = fmaxf(s, 0.f);
    out[idx] = s;
}

// ---------- embedding ----------
__global__ __launch_bounds__(256) void embed_k(
    const int* __restrict__ ids, const float* __restrict__ wte, float* __restrict__ h)
{
    int row = blockIdx.x;
    int s = row & 511;
    int t = threadIdx.x;
    long id = ids[row];
    float4 v1 = reinterpret_cast<const float4*>(wte + id * 1024)[t];
    float4 v2 = reinterpret_cast<const float4*>(wte + (long)s * 1024)[t];
    float4 o; o.x = v1.x + v2.x; o.y = v1.y + v2.y; o.z = v1.z + v2.z; o.w = v1.w + v2.w;
    reinterpret_cast<float4*>(h + (long)row * 1024)[t] = o;
}

// ---------- LayerNorm, fp32 in -> bf16 out ----------
__global__ __launch_bounds__(256) void ln_k(
    const float* __restrict__ in, __bf16* __restrict__ out,
    const float* __restrict__ g, const float* __restrict__ b)
{
    int row = blockIdx.x, t = threadIdx.x;
    float4 v = reinterpret_cast<const float4*>(in + (long)row * 1024)[t];
    float s1 = v.x + v.y + v.z + v.w;
    float s2 = v.x * v.x + v.y * v.y + v.z * v.z + v.w * v.w;
    #pragma unroll
    for (int o = 32; o >= 1; o >>= 1) { s1 += __shfl_xor(s1, o); s2 += __shfl_xor(s2, o); }
    __shared__ float r1[4], r2[4];
    int w = t >> 6;
    if ((t & 63) == 0) { r1[w] = s1; r2[w] = s2; }
    __syncthreads();
    s1 = r1[0] + r1[1] + r1[2] + r1[3];
    s2 = r2[0] + r2[1] + r2[2] + r2[3];
    float mean = s1 * (1.0f / 1024.0f);
    float var  = s2 * (1.0f / 1024.0f) - mean * mean;
    float rstd = rsqrtf(var + 1e-5f);
    float4 gg = reinterpret_cast<const float4*>(g)[t];
    float4 bb = reinterpret_cast<const float4*>(b)[t];
    bf16x4 o;
    o[0] = (__bf16)((v.x - mean) * rstd * gg.x + bb.x);
    o[1] = (__bf16)((v.y - mean) * rstd * gg.y + bb.y);
    o[2] = (__bf16)((v.z - mean) * rstd * gg.z + bb.z);
    o[3] = (__bf16)((v.w - mean) * rstd * gg.w + bb.w);
    *reinterpret_cast<bf16x4*>(out + (long)row * 1024 + t * 4) = o;
}

// ---------- bf16 MFMA GEMM (m97 structure). A[M][K] bf16, Bt[N][K] bf16 ----------
// OUTBF16: C is bf16 else fp32. ACT: gelu. RES: add fp32 res.
template<int BM, int BN, int OUTBF16, int ACT, int RES>
__global__ __launch_bounds__(256) void gemm_bb(
    const __bf16* __restrict__ A, const __bf16* __restrict__ Bt,
    const float* __restrict__ bias, const float* __restrict__ res,
    void* __restrict__ C, int N, int K)
{
    constexpr int FM = BM / 32, FN = BN / 32;
    __shared__ __bf16 As[BM * 32];
    __shared__ __bf16 Bs[BN * 32];
    const int t = threadIdx.x;
    const int m0 = blockIdx.x * BM;
    const int n0 = blockIdx.y * BN;
    const int w = t >> 6, lane = t & 63;
    const int lo = lane & 15, hi = lane >> 4;
    const int wr = w >> 1, wc = w & 1;

    f32x4 acc[FM][FN] = {};

    for (int k0 = 0; k0 < K; k0 += 32) {
        __syncthreads();
        #pragma unroll
        for (int i = 0; i < BM / 64; i++) {
            int c = i * 256 + t;
            GLDS16(A + (long)(m0 + (c >> 2)) * K + k0 + ((c & 3) << 3), &As[c * 8]);
        }
        #pragma unroll
        for (int i = 0; i < BN / 64; i++) {
            int c = i * 256 + t;
            GLDS16(Bt + (long)(n0 + (c >> 2)) * K + k0 + ((c & 3) << 3), &Bs[c * 8]);
        }
        __syncthreads();
        bf16x8 afr[FM], bfr[FN];
        #pragma unroll
        for (int mi = 0; mi < FM; mi++)
            afr[mi] = *reinterpret_cast<const bf16x8*>(&As[(wr * (BM / 2) + mi * 16 + lo) * 32 + hi * 8]);
        #pragma unroll
        for (int ni = 0; ni < FN; ni++)
            bfr[ni] = *reinterpret_cast<const bf16x8*>(&Bs[(wc * (BN / 2) + ni * 16 + lo) * 32 + hi * 8]);
        #pragma unroll
        for (int mi = 0; mi < FM; mi++)
            #pragma unroll
            for (int ni = 0; ni < FN; ni++)
                acc[mi][ni] = __builtin_amdgcn_mfma_f32_16x16x32_bf16(afr[mi], bfr[ni], acc[mi][ni], 0, 0, 0);
    }

    #pragma unroll
    for (int mi = 0; mi < FM; mi++)
        #pragma unroll
        for (int ni = 0; ni < FN; ni++) {
            int col = n0 + wc * (BN / 2) + ni * 16 + lo;
            float bv = bias ? bias[col] : 0.f;
            #pragma unroll
            for (int rr = 0; rr < 4; rr++) {
                int row = m0 + wr * (BM / 2) + mi * 16 + hi * 4 + rr;
                float v = acc[mi][ni][rr] + bv;
                if (ACT) v = gelu_f(v);
                if (RES) v += res[(long)row * N + col];
                if (OUTBF16) ((__bf16*)C)[(long)row * N + col] = (__bf16)v;
                else         ((float*)C)[(long)row * N + col] = v;
            }
        }
}

// ---------- LM head: A[M][K] bf16 (glds), Wt[N][K] fp32 (reg-staged), C fp32 ----------
__global__ __launch_bounds__(256) void gemm_lm(
    const __bf16* __restrict__ A, const float* __restrict__ Wt,
    float* __restrict__ C, int N, int K)
{
    __shared__ __bf16 As[128 * 32];
    __shared__ __bf16 Bs[128 * 32];
    const int t = threadIdx.x;
    const int m0 = blockIdx.x * 128;
    const int n0 = blockIdx.y * 128;
    const int w = t >> 6, lane = t & 63;
    const int lo = lane & 15, hi = lane >> 4;
    const int wr = w >> 1, wc = w & 1;

    f32x4 acc[4][4] = {};

    for (int k0 = 0; k0 < K; k0 += 32) {
        __syncthreads();
        #pragma unroll
        for (int i = 0; i < 2; i++) {
            int c = i * 256 + t;
            GLDS16(A + (long)(m0 + (c >> 2)) * K + k0 + ((c & 3) << 3), &As[c * 8]);
        }
        #pragma unroll
        for (int i = 0; i < 2; i++) {
            int c = i * 256 + t;
            int nr = n0 + (c >> 2);
            bf16x8 bv;
            if (nr < N) {
                const float* wp = Wt + (long)nr * K + k0 + ((c & 3) << 3);
                float4 b0 = *reinterpret_cast<const float4*>(wp);
                float4 b1 = *reinterpret_cast<const float4*>(wp + 4);
                bv[0] = (__bf16)b0.x; bv[1] = (__bf16)b0.y; bv[2] = (__bf16)b0.z; bv[3] = (__bf16)b0.w;
                bv[4] = (__bf16)b1.x; bv[5] = (__bf16)b1.y; bv[6] = (__bf16)b1.z; bv[7] = (__bf16)b1.w;
            } else {
                #pragma unroll
                for (int q = 0; q < 8; q++) bv[q] = (__bf16)0.f;
            }
            *reinterpret_cast<bf16x8*>(&Bs[c * 8]) = bv;
        }
        __syncthreads();
        bf16x8 afr[4], bfr[4];
        #pragma unroll
        for (int mi = 0; mi < 4; mi++)
            afr[mi] = *reinterpret_cast<const bf16x8*>(&As[(wr * 64 + mi * 16 + lo) * 32 + hi * 8]);
        #pragma unroll
        for (int ni = 0; ni < 4; ni++)
            bfr[ni] = *reinterpret_cast<const bf16x8*>(&Bs[(wc * 64 + ni * 16 + lo) * 32 + hi * 8]);
        #pragma unroll
        for (int mi = 0; mi < 4; mi++)
            #pragma unroll
            for (int ni = 0; ni < 4; ni++)
                acc[mi][ni] = __builtin_amdgcn_mfma_f32_16x16x32_bf16(afr[mi], bfr[ni], acc[mi][ni], 0, 0, 0);
    }

    #pragma unroll
    for (int mi = 0; mi < 4; mi++)
        #pragma unroll
        for (int ni = 0; ni < 4; ni++) {
            int col = n0 + wc * 64 + ni * 16 + lo;
            if (col < N) {
                #pragma unroll
                for (int rr = 0; rr < 4; rr++) {
                    int row = m0 + wr * 64 + mi * 16 + hi * 4 + rr;
                    C[(long)row * N + col] = acc[mi][ni][rr];
                }
            }
        }
}

// ---------- MFMA flash attention ----------
// qkv [1024][3072] bf16; per-layer imgk/imgv fp32 [2][1024]; out [1024][1024] bf16
__global__ __launch_bounds__(256) void attn_mfma(
    const __bf16* __restrict__ qkv,
    const float* __restrict__ imgk, const float* __restrict__ imgv,
    const float* __restrict__ amask, __bf16* __restrict__ out)
{
    const int qb = blockIdx.x;   // 0..7
    const int h  = blockIdx.y;   // 0..15
    const int b  = blockIdx.z;   // 0..1
    const int t = threadIdx.x, w = t >> 6, lane = t & 63;
    const int lo = lane & 15, hi = lane >> 4;

    __shared__ __bf16 Ks[64][72];
    __shared__ __bf16 Vt[64][72];
    __shared__ __bf16 Ps[4][16][72];
    __shared__ float kimg_s[64];

    // Q fragments (held in regs for whole kernel)
    const __bf16* qrow = qkv + (long)(b * 512 + qb * 64 + w * 16 + lo) * 3072 + h * 64;
    bf16x8 qf0 = *reinterpret_cast<const bf16x8*>(qrow + hi * 8);
    bf16x8 qf1 = *reinterpret_cast<const bf16x8*>(qrow + 32 + hi * 8);

    if (t < 64) kimg_s[t] = imgk[b * 1024 + h * 64 + t];
    __syncthreads();

    // image-token score per q-row (row = lo, replicated over hi)
    float simg = 0.f;
    #pragma unroll
    for (int i = 0; i < 8; i++)
        simg += (float)qf0[i] * kimg_s[hi * 8 + i] + (float)qf1[i] * kimg_s[32 + hi * 8 + i];
    simg += __shfl_xor(simg, 16);
    simg += __shfl_xor(simg, 32);
    simg *= 0.125f;

    float m_run[4], l_run[4];
    f32x4 o_acc[4];
    #pragma unroll
    for (int rr = 0; rr < 4; rr++) {
        m_run[rr] = __shfl(simg, hi * 4 + rr);
        l_run[rr] = 1.0f;
    }
    #pragma unroll
    for (int df = 0; df < 4; df++) {
        float vi = imgv[b * 1024 + h * 64 + df * 16 + lo];
        #pragma unroll
        for (int rr = 0; rr < 4; rr++) o_acc[df][rr] = vi;
    }

    for (int kb = 0; kb <= qb; kb++) {
        __syncthreads();
        // stage K (4 lanes/row, vector writes)
        {
            int r = t >> 2, dg = (t & 3) * 16;
            const __bf16* src = qkv + (long)(b * 512 + kb * 64 + r) * 3072 + 1024 + h * 64 + dg;
            *reinterpret_cast<bf16x8*>(&Ks[r][dg])     = *reinterpret_cast<const bf16x8*>(src);
            *reinterpret_cast<bf16x8*>(&Ks[r][dg + 8]) = *reinterpret_cast<const bf16x8*>(src + 8);
        }
        // stage V transposed (1 lane/row, scalar writes)
        {
            int r = t & 63, dg = (t >> 6) * 16;
            const __bf16* src = qkv + (long)(b * 512 + kb * 64 + r) * 3072 + 2048 + h * 64 + dg;
            bf16x8 v0 = *reinterpret_cast<const bf16x8*>(src);
            bf16x8 v1 = *reinterpret_cast<const bf16x8*>(src + 8);
            #pragma unroll
            for (int i = 0; i < 8; i++) { Vt[dg + i][r] = v0[i]; Vt[dg + 8 + i][r] = v1[i]; }
        }
        __syncthreads();

        // QK^T
        f32x4 sf[4];
        #pragma unroll
        for (int js = 0; js < 4; js++) {
            bf16x8 kf0 = *reinterpret_cast<const bf16x8*>(&Ks[js * 16 + lo][hi * 8]);
            bf16x8 kf1 = *reinterpret_cast<const bf16x8*>(&Ks[js * 16 + lo][32 + hi * 8]);
            f32x4 a = {};
            a = __builtin_amdgcn_mfma_f32_16x16x32_bf16(qf0, kf0, a, 0, 0, 0);
            a = __builtin_amdgcn_mfma_f32_16x16x32_bf16(qf1, kf1, a, 0, 0, 0);
            sf[js] = a;
        }
        // scale + masks
        float s[4][4];
        #pragma unroll
        for (int js = 0; js < 4; js++) {
            int kr = kb * 64 + js * 16 + lo;
            float amv = (1.0f - amask[b * 512 + kr]) * -10000.0f;
            #pragma unroll
            for (int rr = 0; rr < 4; rr++) {
                float sv = sf[js][rr] * 0.125f + amv;
                if (kb == qb) {
                    int qrw = w * 16 + hi * 4 + rr;
                    if (js * 16 + lo > qrw) sv = -10000.0f + amv;
                }
                s[js][rr] = sv;
            }
        }
        // per-row block max
        #pragma unroll
        for (int rr = 0; rr < 4; rr++) {
            float bm = fmaxf(fmaxf(s[0][rr], s[1][rr]), fmaxf(s[2][rr], s[3][rr]));
            #pragma unroll
            for (int off = 1; off < 16; off <<= 1) bm = fmaxf(bm, __shfl_xor(bm, off));
            float m_new = fmaxf(m_run[rr], bm);
            float scale = __expf(m_run[rr] - m_new);
            m_run[rr] = m_new;
            l_run[rr] *= scale;
            #pragma unroll
            for (int df = 0; df < 4; df++) o_acc[df][rr] *= scale;
            float psum = 0.f;
            #pragma unroll
            for (int js = 0; js < 4; js++) {
                float p = __expf(s[js][rr] - m_new);
                psum += p;
                Ps[w][hi * 4 + rr][js * 16 + lo] = (__bf16)p;
            }
            #pragma unroll
            for (int off = 1; off < 16; off <<= 1) psum += __shfl_xor(psum, off);
            l_run[rr] += psum;
        }
        // PV
        #pragma unroll
        for (int jb = 0; jb < 2; jb++) {
            bf16x8 pf = *reinterpret_cast<const bf16x8*>(&Ps[w][lo][jb * 32 + hi * 8]);
            #pragma unroll
            for (int df = 0; df < 4; df++) {
                bf16x8 vf = *reinterpret_cast<const bf16x8*>(&Vt[df * 16 + lo][jb * 32 + hi * 8]);
                o_acc[df] = __builtin_amdgcn_mfma_f32_16x16x32_bf16(pf, vf, o_acc[df], 0, 0, 0);
            }
        }
    }

    float linv[4];
    #pragma unroll
    for (int rr = 0; rr < 4; rr++) linv[rr] = 1.0f / l_run[rr];
    #pragma unroll
    for (int df = 0; df < 4; df++)
        #pragma unroll
        for (int rr = 0; rr < 4; rr++) {
            long row = b * 512 + qb * 64 + w * 16 + hi * 4 + rr;
            out[row * 1024 + h * 64 + df * 16 + lo] = (__bf16)(o_acc[df][rr] * linv[rr]);
        }
}

// ---------- host orchestration ----------
extern "C" void kernel_launch(void* const* d_in, const int* in_sizes, int n_in,
                              void* d_out, int out_size, void* d_ws, size_t ws_size,
                              hipStream_t stream) {
    (void)in_sizes; (void)n_in; (void)out_size; (void)ws_size;
    const int*   ids   = (const int*)d_in[0];
    const float* amask = (const float*)d_in[1];
    const float* ihs   = (const float*)d_in[2];
    const float* wte   = (const float*)d_in[3];
    const float* ftW1  = (const float*)d_in[4];
    const float* ftb1  = (const float*)d_in[5];
    const float* ftW2  = (const float*)d_in[6];
    const float* ftb2  = (const float*)d_in[7];
    const float* ln1g  = (const float*)d_in[8];
    const float* ln1b  = (const float*)d_in[9];
    const float* Wattn = (const float*)d_in[10];
    const float* battn = (const float*)d_in[11];
    const float* Wuk   = (const float*)d_in[12];
    const float* buk   = (const float*)d_in[13];
    const float* Wuv   = (const float*)d_in[14];
    const float* buv   = (const float*)d_in[15];
    const float* Wproj = (const float*)d_in[16];
    const float* bproj = (const float*)d_in[17];
    const float* ln2g  = (const float*)d_in[18];
    const float* ln2b  = (const float*)d_in[19];
    const float* Wfc   = (const float*)d_in[20];
    const float* bfc   = (const float*)d_in[21];
    const float* Wfc2  = (const float*)d_in[22];
    const float* bfc2  = (const float*)d_in[23];
    const float* lnfg  = (const float*)d_in[24];
    const float* lnfb  = (const float*)d_in[25];
    float* out = (float*)d_out;

    char* base = (char*)d_ws;
    float* ftmp  = (float*)(base);                 // 2048 f32
    float* img   = (float*)(base + (1 << 13));     // 2048
    float* imgk  = (float*)(base + (1 << 14));     // 24576
    float* imgv  = (float*)(base + 114688);        // 24576
    float* part  = (float*)(base + 212992);        // 196608
    float* h     = (float*)(base + 1048576);       // 1M f32 (4MB)
    char* p = base + 5 * 1048576;
    __bf16* xb    = (__bf16*)p; p += 2 * 1048576;  // 1M bf16
    __bf16* qkvb  = (__bf16*)p; p += 6 * 1048576;  // 3M
    __bf16* attob = (__bf16*)p; p += 2 * 1048576;  // 1M
    __bf16* ffb   = (__bf16*)p; p += 8 * 1048576;  // 4M
    __bf16* wtA   = (__bf16*)p; p += 6 * 1048576;  // 3M  (3072x1024)
    __bf16* wtP   = (__bf16*)p; p += 2 * 1048576;  // 1M  (1024x1024)
    __bf16* wtF   = (__bf16*)p; p += 8 * 1048576;  // 4M  (4096x1024)
    __bf16* wtF2  = (__bf16*)p; p += 8 * 1048576;  // 4M  (1024x4096)

    dim3 b256(256);

    // image feature transform + per-layer image K/V projections
    gemv_part<<<dim3(16, 8, 1), b256, 0, stream>>>(ihs, 1024, ftW1, 0, part, 1024, 1024);
    gemv_reduce<<<dim3(8), b256, 0, stream>>>(part, ftb1, 0, ftmp, 1024, 1, 1);
    gemv_part<<<dim3(16, 8, 1), b256, 0, stream>>>(ftmp, 1024, ftW2, 0, part, 1024, 1024);
    gemv_reduce<<<dim3(8), b256, 0, stream>>>(part, ftb2, 0, img, 1024, 1, 0);
    gemv_part<<<dim3(16, 8, 12), b256, 0, stream>>>(img, 1024, Wuk, 1024L * 1024, part, 1024, 1024);
    gemv_reduce<<<dim3(96), b256, 0, stream>>>(part, buk, 1024, imgk, 1024, 12, 0);
    gemv_part<<<dim3(16, 8, 12), b256, 0, stream>>>(img, 1024, Wuv, 1024L * 1024, part, 1024, 1024);
    gemv_reduce<<<dim3(96), b256, 0, stream>>>(part, buv, 1024, imgv, 1024, 12, 0);

    embed_k<<<dim3(1024), b256, 0, stream>>>(ids, wte, h);

    for (int l = 0; l < 12; l++) {
        // weight transpose+convert for this layer
        tcvt<<<dim3(32, 96), b256, 0, stream>>>(Wattn + (long)l * 1024 * 3072, wtA, 1024, 3072);
        tcvt<<<dim3(32, 32), b256, 0, stream>>>(Wproj + (long)l * 1024 * 1024, wtP, 1024, 1024);
        tcvt<<<dim3(32, 128), b256, 0, stream>>>(Wfc + (long)l * 1024 * 4096, wtF, 1024, 4096);
        tcvt<<<dim3(128, 32), b256, 0, stream>>>(Wfc2 + (long)l * 4096 * 1024, wtF2, 4096, 1024);

        ln_k<<<dim3(1024), b256, 0, stream>>>(h, xb, ln1g + l * 1024, ln1b + l * 1024);
        gemm_bb<128, 128, 1, 0, 0><<<dim3(8, 24), b256, 0, stream>>>(
            xb, wtA, battn + l * 3072, nullptr, qkvb, 3072, 1024);
        attn_mfma<<<dim3(8, 16, 2), b256, 0, stream>>>(
            qkvb, imgk + l * 2048, imgv + l * 2048, amask, attob);
        gemm_bb<64, 128, 0, 0, 1><<<dim3(16, 8), b256, 0, stream>>>(
            attob, wtP, bproj + l * 1024, h, h, 1024, 1024);
        ln_k<<<dim3(1024), b256, 0, stream>>>(h, xb, ln2g + l * 1024, ln2b + l * 1024);
        gemm_bb<128, 128, 1, 1, 0><<<dim3(8, 32), b256, 0, stream>>>(
            xb, wtF, bfc + l * 4096, nullptr, ffb, 4096, 1024);
        gemm_bb<64, 128, 0, 0, 1><<<dim3(16, 8), b256, 0, stream>>>(
            ffb, wtF2, bfc2 + l * 1024, h, h, 1024, 4096);
    }

    ln_k<<<dim3(1024), b256, 0, stream>>>(h, xb, lnfg, lnfb);
    gemm_lm<<<dim3(8, 393), b256, 0, stream>>>(xb, wte, out, 50257, 1024);
}

// Round 3
// 2064.165 us; speedup vs baseline: 2.7024x; 1.3309x over previous
//
#include <hip/hip_runtime.h>
#include <cstdint>

// B=2, S=512, D=1024, H=16, HD=64, L=12, V=50257, DFF=4096

typedef __bf16 bf16x8 __attribute__((ext_vector_type(8)));
typedef __bf16 bf16x4 __attribute__((ext_vector_type(4)));
typedef float  f32x4  __attribute__((ext_vector_type(4)));

#define GLDS16(g, l) __builtin_amdgcn_global_load_lds( \
    (const __attribute__((address_space(1))) unsigned int*)(g), \
    (__attribute__((address_space(3))) unsigned int*)(l), 16, 0, 0)

__device__ __forceinline__ float gelu_f(float x) {
    float u = 1.5957691216057308f * (x + 0.044715f * x * x * x);
    float e = __expf(u);
    float t = 1.0f - 2.0f / (e + 1.0f);
    return 0.5f * x * (1.0f + t);
}

// ---------- per-layer weight transpose+convert, all 4 mats in one launch ----------
__global__ __launch_bounds__(256) void tcvt_layer(
    const float* __restrict__ Wa, const float* __restrict__ Wp,
    const float* __restrict__ Wf, const float* __restrict__ Wf2,
    __bf16* __restrict__ oa, __bf16* __restrict__ op,
    __bf16* __restrict__ of, __bf16* __restrict__ of2)
{
    int id = blockIdx.x;
    const float* src; __bf16* dst; int K, N, kb, nb;
    if (id < 3072)      { src = Wa;  dst = oa;  K = 1024; N = 3072; kb = id & 31;  nb = id >> 5; }
    else if (id < 4096) { id -= 3072; src = Wp;  dst = op;  K = 1024; N = 1024; kb = id & 31;  nb = id >> 5; }
    else if (id < 8192) { id -= 4096; src = Wf;  dst = of;  K = 1024; N = 4096; kb = id & 31;  nb = id >> 5; }
    else                { id -= 8192; src = Wf2; dst = of2; K = 4096; N = 1024; kb = id & 127; nb = id >> 7; }
    const int k0 = kb * 32, n0 = nb * 32;
    __shared__ float tile[32][33];
    const int t = threadIdx.x;
    const int r = t >> 3, c4 = (t & 7) * 4;
    float4 v = *reinterpret_cast<const float4*>(src + (long)(k0 + r) * N + n0 + c4);
    tile[r][c4] = v.x; tile[r][c4 + 1] = v.y; tile[r][c4 + 2] = v.z; tile[r][c4 + 3] = v.w;
    __syncthreads();
    bf16x4 o;
    o[0] = (__bf16)tile[c4][r];
    o[1] = (__bf16)tile[c4 + 1][r];
    o[2] = (__bf16)tile[c4 + 2][r];
    o[3] = (__bf16)tile[c4 + 3][r];
    *reinterpret_cast<bf16x4*>(dst + (long)(n0 + r) * K + k0 + c4) = o;
}

// ---------- wte fp32 -> bf16 (no transpose; zero-pads rows >= V) ----------
__global__ __launch_bounds__(256) void wcvt(
    const float* __restrict__ wte, __bf16* __restrict__ out, long nvalid)
{
    long e = ((long)blockIdx.x * 256 + threadIdx.x) * 8;
    bf16x8 o;
    if (e < nvalid) {
        float4 a = *reinterpret_cast<const float4*>(wte + e);
        float4 b = *reinterpret_cast<const float4*>(wte + e + 4);
        o[0] = (__bf16)a.x; o[1] = (__bf16)a.y; o[2] = (__bf16)a.z; o[3] = (__bf16)a.w;
        o[4] = (__bf16)b.x; o[5] = (__bf16)b.y; o[6] = (__bf16)b.z; o[7] = (__bf16)b.w;
    } else {
        #pragma unroll
        for (int i = 0; i < 8; i++) o[i] = (__bf16)0.f;
    }
    *reinterpret_cast<bf16x8*>(out + e) = o;
}

// ---------- small GEMV path (img projections), deterministic ksplit ----------
__global__ __launch_bounds__(256) void gemv_part(
    const float* __restrict__ x, int xld,
    const float* __restrict__ W, long wzs,
    float* __restrict__ part, int K, int N)
{
    int jb = blockIdx.x, kz = blockIdx.y, z = blockIdx.z;
    int t = threadIdx.x;
    int j = (jb << 6) + (t & 63);
    int g = t >> 6;
    int klen = K / (gridDim.y * 4);
    int kbase = (kz * 4 + g) * klen;
    const float* Wp = W + (long)z * wzs + (long)kbase * N + j;
    const float* x0 = x + kbase;
    const float* x1 = x + xld + kbase;
    float a0 = 0.f, a1 = 0.f;
    for (int k = 0; k < klen; k++) {
        float wv = Wp[(long)k * N];
        a0 += x0[k] * wv;
        a1 += x1[k] * wv;
    }
    __shared__ float r0[4][64], r1[4][64];
    r0[g][t & 63] = a0; r1[g][t & 63] = a1;
    __syncthreads();
    if (t < 64) {
        a0 = r0[0][t] + r0[1][t] + r0[2][t] + r0[3][t];
        a1 = r1[0][t] + r1[1][t] + r1[2][t] + r1[3][t];
        long base = (long)(z * gridDim.y + kz) * 2 * N + (jb << 6) + t;
        part[base]     = a0;
        part[base + N] = a1;
    }
}

__global__ __launch_bounds__(256) void gemv_reduce(
    const float* __restrict__ part, const float* __restrict__ bias, long bzs,
    float* __restrict__ out, int N, int nz, int act)
{
    int idx = blockIdx.x * 256 + threadIdx.x;
    if (idx >= nz * 2 * N) return;
    int j  = idx % N;
    int bz = idx / N;
    int z  = bz >> 1;
    float s = bias[(long)z * bzs + j];
    const float* p = part + ((long)z * 8 * 2 + (bz & 1)) * N + j;
    #pragma unroll
    for (int kz = 0; kz < 8; kz++) s += p[(long)kz * 2 * N];
    if (act) s = fmaxf(s, 0.f);
    out[idx] = s;
}

// ---------- embedding ----------
__global__ __launch_bounds__(256) void embed_k(
    const int* __restrict__ ids, const float* __restrict__ wte, float* __restrict__ h)
{
    int row = blockIdx.x;
    int s = row & 511;
    int t = threadIdx.x;
    long id = ids[row];
    float4 v1 = reinterpret_cast<const float4*>(wte + id * 1024)[t];
    float4 v2 = reinterpret_cast<const float4*>(wte + (long)s * 1024)[t];
    float4 o; o.x = v1.x + v2.x; o.y = v1.y + v2.y; o.z = v1.z + v2.z; o.w = v1.w + v2.w;
    reinterpret_cast<float4*>(h + (long)row * 1024)[t] = o;
}

// ---------- LayerNorm, fp32 in -> bf16 out ----------
__global__ __launch_bounds__(256) void ln_k(
    const float* __restrict__ in, __bf16* __restrict__ out,
    const float* __restrict__ g, const float* __restrict__ b)
{
    int row = blockIdx.x, t = threadIdx.x;
    float4 v = reinterpret_cast<const float4*>(in + (long)row * 1024)[t];
    float s1 = v.x + v.y + v.z + v.w;
    float s2 = v.x * v.x + v.y * v.y + v.z * v.z + v.w * v.w;
    #pragma unroll
    for (int o = 32; o >= 1; o >>= 1) { s1 += __shfl_xor(s1, o); s2 += __shfl_xor(s2, o); }
    __shared__ float r1[4], r2[4];
    int w = t >> 6;
    if ((t & 63) == 0) { r1[w] = s1; r2[w] = s2; }
    __syncthreads();
    s1 = r1[0] + r1[1] + r1[2] + r1[3];
    s2 = r2[0] + r2[1] + r2[2] + r2[3];
    float mean = s1 * (1.0f / 1024.0f);
    float var  = s2 * (1.0f / 1024.0f) - mean * mean;
    float rstd = rsqrtf(var + 1e-5f);
    float4 gg = reinterpret_cast<const float4*>(g)[t];
    float4 bb = reinterpret_cast<const float4*>(b)[t];
    bf16x4 o;
    o[0] = (__bf16)((v.x - mean) * rstd * gg.x + bb.x);
    o[1] = (__bf16)((v.y - mean) * rstd * gg.y + bb.y);
    o[2] = (__bf16)((v.z - mean) * rstd * gg.z + bb.z);
    o[3] = (__bf16)((v.w - mean) * rstd * gg.w + bb.w);
    *reinterpret_cast<bf16x4*>(out + (long)row * 1024 + t * 4) = o;
}

// ---------- bf16 MFMA GEMM (m97 structure). A[M][K] bf16, Bt[N][K] bf16 ----------
template<int BM, int BN, int OUTBF16, int ACT, int RES, int NBOUND>
__global__ __launch_bounds__(256) void gemm_bb(
    const __bf16* __restrict__ A, const __bf16* __restrict__ Bt,
    const float* __restrict__ bias, const float* __restrict__ res,
    void* __restrict__ C, int N, int K)
{
    constexpr int FM = BM / 32, FN = BN / 32;
    __shared__ __bf16 As[BM * 32];
    __shared__ __bf16 Bs[BN * 32];
    const int t = threadIdx.x;
    const int m0 = blockIdx.x * BM;
    const int n0 = blockIdx.y * BN;
    const int w = t >> 6, lane = t & 63;
    const int lo = lane & 15, hi = lane >> 4;
    const int wr = w >> 1, wc = w & 1;

    f32x4 acc[FM][FN] = {};

    for (int k0 = 0; k0 < K; k0 += 32) {
        __syncthreads();
        #pragma unroll
        for (int i = 0; i < BM / 64; i++) {
            int c = i * 256 + t;
            GLDS16(A + (long)(m0 + (c >> 2)) * K + k0 + ((c & 3) << 3), &As[c * 8]);
        }
        #pragma unroll
        for (int i = 0; i < BN / 64; i++) {
            int c = i * 256 + t;
            GLDS16(Bt + (long)(n0 + (c >> 2)) * K + k0 + ((c & 3) << 3), &Bs[c * 8]);
        }
        __syncthreads();
        bf16x8 afr[FM], bfr[FN];
        #pragma unroll
        for (int mi = 0; mi < FM; mi++)
            afr[mi] = *reinterpret_cast<const bf16x8*>(&As[(wr * (BM / 2) + mi * 16 + lo) * 32 + hi * 8]);
        #pragma unroll
        for (int ni = 0; ni < FN; ni++)
            bfr[ni] = *reinterpret_cast<const bf16x8*>(&Bs[(wc * (BN / 2) + ni * 16 + lo) * 32 + hi * 8]);
        #pragma unroll
        for (int mi = 0; mi < FM; mi++)
            #pragma unroll
            for (int ni = 0; ni < FN; ni++)
                acc[mi][ni] = __builtin_amdgcn_mfma_f32_16x16x32_bf16(afr[mi], bfr[ni], acc[mi][ni], 0, 0, 0);
    }

    #pragma unroll
    for (int mi = 0; mi < FM; mi++)
        #pragma unroll
        for (int ni = 0; ni < FN; ni++) {
            int col = n0 + wc * (BN / 2) + ni * 16 + lo;
            if (NBOUND && col >= N) continue;
            float bv = bias ? bias[col] : 0.f;
            #pragma unroll
            for (int rr = 0; rr < 4; rr++) {
                int row = m0 + wr * (BM / 2) + mi * 16 + hi * 4 + rr;
                float v = acc[mi][ni][rr] + bv;
                if (ACT) v = gelu_f(v);
                if (RES) v += res[(long)row * N + col];
                if (OUTBF16) ((__bf16*)C)[(long)row * N + col] = (__bf16)v;
                else         ((float*)C)[(long)row * N + col] = v;
            }
        }
}

// ---------- LM head fallback: A bf16 (glds), Wt[N][K] fp32 reg-staged ----------
__global__ __launch_bounds__(256) void gemm_lm(
    const __bf16* __restrict__ A, const float* __restrict__ Wt,
    float* __restrict__ C, int N, int K)
{
    __shared__ __bf16 As[128 * 32];
    __shared__ __bf16 Bs[128 * 32];
    const int t = threadIdx.x;
    const int m0 = blockIdx.x * 128;
    const int n0 = blockIdx.y * 128;
    const int w = t >> 6, lane = t & 63;
    const int lo = lane & 15, hi = lane >> 4;
    const int wr = w >> 1, wc = w & 1;

    f32x4 acc[4][4] = {};

    for (int k0 = 0; k0 < K; k0 += 32) {
        __syncthreads();
        #pragma unroll
        for (int i = 0; i < 2; i++) {
            int c = i * 256 + t;
            GLDS16(A + (long)(m0 + (c >> 2)) * K + k0 + ((c & 3) << 3), &As[c * 8]);
        }
        #pragma unroll
        for (int i = 0; i < 2; i++) {
            int c = i * 256 + t;
            int nr = n0 + (c >> 2);
            bf16x8 bv;
            if (nr < N) {
                const float* wp = Wt + (long)nr * K + k0 + ((c & 3) << 3);
                float4 b0 = *reinterpret_cast<const float4*>(wp);
                float4 b1 = *reinterpret_cast<const float4*>(wp + 4);
                bv[0] = (__bf16)b0.x; bv[1] = (__bf16)b0.y; bv[2] = (__bf16)b0.z; bv[3] = (__bf16)b0.w;
                bv[4] = (__bf16)b1.x; bv[5] = (__bf16)b1.y; bv[6] = (__bf16)b1.z; bv[7] = (__bf16)b1.w;
            } else {
                #pragma unroll
                for (int q = 0; q < 8; q++) bv[q] = (__bf16)0.f;
            }
            *reinterpret_cast<bf16x8*>(&Bs[c * 8]) = bv;
        }
        __syncthreads();
        bf16x8 afr[4], bfr[4];
        #pragma unroll
        for (int mi = 0; mi < 4; mi++)
            afr[mi] = *reinterpret_cast<const bf16x8*>(&As[(wr * 64 + mi * 16 + lo) * 32 + hi * 8]);
        #pragma unroll
        for (int ni = 0; ni < 4; ni++)
            bfr[ni] = *reinterpret_cast<const bf16x8*>(&Bs[(wc * 64 + ni * 16 + lo) * 32 + hi * 8]);
        #pragma unroll
        for (int mi = 0; mi < 4; mi++)
            #pragma unroll
            for (int ni = 0; ni < 4; ni++)
                acc[mi][ni] = __builtin_amdgcn_mfma_f32_16x16x32_bf16(afr[mi], bfr[ni], acc[mi][ni], 0, 0, 0);
    }

    #pragma unroll
    for (int mi = 0; mi < 4; mi++)
        #pragma unroll
        for (int ni = 0; ni < 4; ni++) {
            int col = n0 + wc * 64 + ni * 16 + lo;
            if (col < N) {
                #pragma unroll
                for (int rr = 0; rr < 4; rr++) {
                    int row = m0 + wr * 64 + mi * 16 + hi * 4 + rr;
                    C[(long)row * N + col] = acc[mi][ni][rr];
                }
            }
        }
}

// ---------- MFMA flash attention, no-max-tracking (scores analytically bounded) ----------
__global__ __launch_bounds__(256) void attn_mfma(
    const __bf16* __restrict__ qkv,
    const float* __restrict__ imgk, const float* __restrict__ imgv,
    const float* __restrict__ amask, __bf16* __restrict__ out)
{
    const int qb = blockIdx.x;   // 0..7
    const int h  = blockIdx.y;   // 0..15
    const int b  = blockIdx.z;   // 0..1
    const int t = threadIdx.x, w = t >> 6, lane = t & 63;
    const int lo = lane & 15, hi = lane >> 4;

    __shared__ __bf16 Ks[64][72];
    __shared__ __bf16 Vt[64][72];
    __shared__ __bf16 Ps[4][16][72];
    __shared__ float kimg_s[64];
    __shared__ float amv_s[64];

    const __bf16* qrow = qkv + (long)(b * 512 + qb * 64 + w * 16 + lo) * 3072 + h * 64;
    bf16x8 qf0 = *reinterpret_cast<const bf16x8*>(qrow + hi * 8);
    bf16x8 qf1 = *reinterpret_cast<const bf16x8*>(qrow + 32 + hi * 8);

    if (t < 64) kimg_s[t] = imgk[b * 1024 + h * 64 + t];
    __syncthreads();

    // image-token score for q-row = lo (sum over hi groups)
    float simg = 0.f;
    #pragma unroll
    for (int i = 0; i < 8; i++)
        simg += (float)qf0[i] * kimg_s[hi * 8 + i] + (float)qf1[i] * kimg_s[32 + hi * 8 + i];
    simg += __shfl_xor(simg, 16);
    simg += __shfl_xor(simg, 32);
    simg *= 0.125f;

    float pimg[4], l_part[4];
    f32x4 o_acc[4];
    #pragma unroll
    for (int rr = 0; rr < 4; rr++) {
        pimg[rr] = __expf(__shfl(simg, hi * 4 + rr));
        l_part[rr] = 0.f;
    }
    #pragma unroll
    for (int df = 0; df < 4; df++) {
        float vi = imgv[b * 1024 + h * 64 + df * 16 + lo];
        #pragma unroll
        for (int rr = 0; rr < 4; rr++) o_acc[df][rr] = pimg[rr] * vi;
    }

    for (int kb = 0; kb <= qb; kb++) {
        __syncthreads();
        {   // stage K (vector writes, padded rows)
            int r = t >> 2, dg = (t & 3) * 16;
            const __bf16* src = qkv + (long)(b * 512 + kb * 64 + r) * 3072 + 1024 + h * 64 + dg;
            *reinterpret_cast<bf16x8*>(&Ks[r][dg])     = *reinterpret_cast<const bf16x8*>(src);
            *reinterpret_cast<bf16x8*>(&Ks[r][dg + 8]) = *reinterpret_cast<const bf16x8*>(src + 8);
        }
        {   // stage V transposed
            int r = t & 63, dg = (t >> 6) * 16;
            const __bf16* src = qkv + (long)(b * 512 + kb * 64 + r) * 3072 + 2048 + h * 64 + dg;
            bf16x8 v0 = *reinterpret_cast<const bf16x8*>(src);
            bf16x8 v1 = *reinterpret_cast<const bf16x8*>(src + 8);
            #pragma unroll
            for (int i = 0; i < 8; i++) { Vt[dg + i][r] = v0[i]; Vt[dg + 8 + i][r] = v1[i]; }
        }
        if (t < 64) amv_s[t] = (1.0f - amask[b * 512 + kb * 64 + t]) * -10000.0f;
        __syncthreads();

        // QK^T
        f32x4 sf[4];
        #pragma unroll
        for (int js = 0; js < 4; js++) {
            bf16x8 kf0 = *reinterpret_cast<const bf16x8*>(&Ks[js * 16 + lo][hi * 8]);
            bf16x8 kf1 = *reinterpret_cast<const bf16x8*>(&Ks[js * 16 + lo][32 + hi * 8]);
            f32x4 a = {};
            a = __builtin_amdgcn_mfma_f32_16x16x32_bf16(qf0, kf0, a, 0, 0, 0);
            a = __builtin_amdgcn_mfma_f32_16x16x32_bf16(qf1, kf1, a, 0, 0, 0);
            sf[js] = a;
        }
        // p = exp(s) directly; accumulate lane-local l partials
        #pragma unroll
        for (int js = 0; js < 4; js++) {
            float amv = amv_s[js * 16 + lo];
            #pragma unroll
            for (int rr = 0; rr < 4; rr++) {
                float sv = sf[js][rr] * 0.125f + amv;
                if (kb == qb) {
                    int qrw = w * 16 + hi * 4 + rr;
                    if (js * 16 + lo > qrw) sv = -10000.0f + amv;
                }
                float p = __expf(sv);
                l_part[rr] += p;
                Ps[w][hi * 4 + rr][js * 16 + lo] = (__bf16)p;
            }
        }
        // PV
        #pragma unroll
        for (int jb = 0; jb < 2; jb++) {
            bf16x8 pf = *reinterpret_cast<const bf16x8*>(&Ps[w][lo][jb * 32 + hi * 8]);
            #pragma unroll
            for (int df = 0; df < 4; df++) {
                bf16x8 vf = *reinterpret_cast<const bf16x8*>(&Vt[df * 16 + lo][jb * 32 + hi * 8]);
                o_acc[df] = __builtin_amdgcn_mfma_f32_16x16x32_bf16(pf, vf, o_acc[df], 0, 0, 0);
            }
        }
    }

    // single end-of-kernel l reduction (over the 16 lo-lanes)
    float linv[4];
    #pragma unroll
    for (int rr = 0; rr < 4; rr++) {
        float ls = l_part[rr];
        #pragma unroll
        for (int off = 1; off < 16; off <<= 1) ls += __shfl_xor(ls, off);
        linv[rr] = 1.0f / (pimg[rr] + ls);
    }
    #pragma unroll
    for (int df = 0; df < 4; df++)
        #pragma unroll
        for (int rr = 0; rr < 4; rr++) {
            long row = b * 512 + qb * 64 + w * 16 + hi * 4 + rr;
            out[row * 1024 + h * 64 + df * 16 + lo] = (__bf16)(o_acc[df][rr] * linv[rr]);
        }
}

// ---------- host orchestration ----------
extern "C" void kernel_launch(void* const* d_in, const int* in_sizes, int n_in,
                              void* d_out, int out_size, void* d_ws, size_t ws_size,
                              hipStream_t stream) {
    (void)in_sizes; (void)n_in; (void)out_size;
    const int*   ids   = (const int*)d_in[0];
    const float* amask = (const float*)d_in[1];
    const float* ihs   = (const float*)d_in[2];
    const float* wte   = (const float*)d_in[3];
    const float* ftW1  = (const float*)d_in[4];
    const float* ftb1  = (const float*)d_in[5];
    const float* ftW2  = (const float*)d_in[6];
    const float* ftb2  = (const float*)d_in[7];
    const float* ln1g  = (const float*)d_in[8];
    const float* ln1b  = (const float*)d_in[9];
    const float* Wattn = (const float*)d_in[10];
    const float* battn = (const float*)d_in[11];
    const float* Wuk   = (const float*)d_in[12];
    const float* buk   = (const float*)d_in[13];
    const float* Wuv   = (const float*)d_in[14];
    const float* buv   = (const float*)d_in[15];
    const float* Wproj = (const float*)d_in[16];
    const float* bproj = (const float*)d_in[17];
    const float* ln2g  = (const float*)d_in[18];
    const float* ln2b  = (const float*)d_in[19];
    const float* Wfc   = (const float*)d_in[20];
    const float* bfc   = (const float*)d_in[21];
    const float* Wfc2  = (const float*)d_in[22];
    const float* bfc2  = (const float*)d_in[23];
    const float* lnfg  = (const float*)d_in[24];
    const float* lnfb  = (const float*)d_in[25];
    float* out = (float*)d_out;

    const long VP = 50304;  // V padded to multiple of 128
    char* base = (char*)d_ws;
    float* ftmp  = (float*)(base);
    float* img   = (float*)(base + (1 << 13));
    float* imgk  = (float*)(base + (1 << 14));
    float* imgv  = (float*)(base + 114688);
    float* part  = (float*)(base + 212992);
    float* h     = (float*)(base + 1048576);
    char* p = base + 5 * 1048576;
    __bf16* xb    = (__bf16*)p; p += 2 * 1048576;
    __bf16* qkvb  = (__bf16*)p; p += 6 * 1048576;
    __bf16* attob = (__bf16*)p; p += 2 * 1048576;
    __bf16* ffb   = (__bf16*)p; p += 8 * 1048576;
    __bf16* wtA   = (__bf16*)p; p += 6 * 1048576;
    __bf16* wtP   = (__bf16*)p; p += 2 * 1048576;
    __bf16* wtF   = (__bf16*)p; p += 8 * 1048576;
    __bf16* wtF2  = (__bf16*)p; p += 8 * 1048576;
    __bf16* wteb  = (__bf16*)p;
    size_t need = (size_t)(p - base) + (size_t)VP * 1024 * 2;
    const bool big_ws = (ws_size >= need);

    dim3 b256(256);

    gemv_part<<<dim3(16, 8, 1), b256, 0, stream>>>(ihs, 1024, ftW1, 0, part, 1024, 1024);
    gemv_reduce<<<dim3(8), b256, 0, stream>>>(part, ftb1, 0, ftmp, 1024, 1, 1);
    gemv_part<<<dim3(16, 8, 1), b256, 0, stream>>>(ftmp, 1024, ftW2, 0, part, 1024, 1024);
    gemv_reduce<<<dim3(8), b256, 0, stream>>>(part, ftb2, 0, img, 1024, 1, 0);
    gemv_part<<<dim3(16, 8, 12), b256, 0, stream>>>(img, 1024, Wuk, 1024L * 1024, part, 1024, 1024);
    gemv_reduce<<<dim3(96), b256, 0, stream>>>(part, buk, 1024, imgk, 1024, 12, 0);
    gemv_part<<<dim3(16, 8, 12), b256, 0, stream>>>(img, 1024, Wuv, 1024L * 1024, part, 1024, 1024);
    gemv_reduce<<<dim3(96), b256, 0, stream>>>(part, buv, 1024, imgv, 1024, 12, 0);

    embed_k<<<dim3(1024), b256, 0, stream>>>(ids, wte, h);
    if (big_ws)  // convert LM-head weights early (also warms L3)
        wcvt<<<dim3((unsigned)(VP * 1024 / 2048)), b256, 0, stream>>>(wte, wteb, 50257L * 1024);

    for (int l = 0; l < 12; l++) {
        tcvt_layer<<<dim3(12288), b256, 0, stream>>>(
            Wattn + (long)l * 1024 * 3072, Wproj + (long)l * 1024 * 1024,
            Wfc + (long)l * 1024 * 4096, Wfc2 + (long)l * 4096 * 1024,
            wtA, wtP, wtF, wtF2);

        ln_k<<<dim3(1024), b256, 0, stream>>>(h, xb, ln1g + l * 1024, ln1b + l * 1024);
        gemm_bb<64, 64, 1, 0, 0, 0><<<dim3(16, 48), b256, 0, stream>>>(
            xb, wtA, battn + l * 3072, nullptr, qkvb, 3072, 1024);
        attn_mfma<<<dim3(8, 16, 2), b256, 0, stream>>>(
            qkvb, imgk + l * 2048, imgv + l * 2048, amask, attob);
        gemm_bb<64, 64, 0, 0, 1, 0><<<dim3(16, 16), b256, 0, stream>>>(
            attob, wtP, bproj + l * 1024, h, h, 1024, 1024);
        ln_k<<<dim3(1024), b256, 0, stream>>>(h, xb, ln2g + l * 1024, ln2b + l * 1024);
        gemm_bb<64, 64, 1, 1, 0, 0><<<dim3(16, 64), b256, 0, stream>>>(
            xb, wtF, bfc + l * 4096, nullptr, ffb, 4096, 1024);
        gemm_bb<64, 64, 0, 0, 1, 0><<<dim3(16, 16), b256, 0, stream>>>(
            ffb, wtF2, bfc2 + l * 1024, h, h, 1024, 4096);
    }

    ln_k<<<dim3(1024), b256, 0, stream>>>(h, xb, lnfg, lnfb);
    if (big_ws)
        gemm_bb<128, 128, 0, 0, 0, 1><<<dim3(8, 393), b256, 0, stream>>>(
            xb, wteb, nullptr, nullptr, out, 50257, 1024);
    else
        gemm_lm<<<dim3(8, 393), b256, 0, stream>>>(xb, wte, out, 50257, 1024);
}

// Round 4
// 2040.537 us; speedup vs baseline: 2.7336x; 1.0116x over previous
//
#include <hip/hip_runtime.h>
#include <cstdint>

// B=2, S=512, D=1024, H=16, HD=64, L=12, V=50257, DFF=4096

typedef __bf16 bf16x8 __attribute__((ext_vector_type(8)));
typedef __bf16 bf16x4 __attribute__((ext_vector_type(4)));
typedef float  f32x4  __attribute__((ext_vector_type(4)));

#define GLDS16(g, l) __builtin_amdgcn_global_load_lds( \
    (const __attribute__((address_space(1))) unsigned int*)(g), \
    (__attribute__((address_space(3))) unsigned int*)(l), 16, 0, 0)

__device__ __forceinline__ float gelu_f(float x) {
    float u = 1.5957691216057308f * (x + 0.044715f * x * x * x);
    float e = __expf(u);
    float t = 1.0f - 2.0f / (e + 1.0f);
    return 0.5f * x * (1.0f + t);
}

// ---------- per-layer weight transpose+convert, all 4 mats in one launch ----------
__global__ __launch_bounds__(256) void tcvt_layer(
    const float* __restrict__ Wa, const float* __restrict__ Wp,
    const float* __restrict__ Wf, const float* __restrict__ Wf2,
    __bf16* __restrict__ oa, __bf16* __restrict__ op,
    __bf16* __restrict__ of, __bf16* __restrict__ of2)
{
    int id = blockIdx.x;
    const float* src; __bf16* dst; int K, N, kb, nb;
    if (id < 3072)      { src = Wa;  dst = oa;  K = 1024; N = 3072; kb = id & 31;  nb = id >> 5; }
    else if (id < 4096) { id -= 3072; src = Wp;  dst = op;  K = 1024; N = 1024; kb = id & 31;  nb = id >> 5; }
    else if (id < 8192) { id -= 4096; src = Wf;  dst = of;  K = 1024; N = 4096; kb = id & 31;  nb = id >> 5; }
    else                { id -= 8192; src = Wf2; dst = of2; K = 4096; N = 1024; kb = id & 127; nb = id >> 7; }
    const int k0 = kb * 32, n0 = nb * 32;
    __shared__ float tile[32][33];
    const int t = threadIdx.x;
    const int r = t >> 3, c4 = (t & 7) * 4;
    float4 v = *reinterpret_cast<const float4*>(src + (long)(k0 + r) * N + n0 + c4);
    tile[r][c4] = v.x; tile[r][c4 + 1] = v.y; tile[r][c4 + 2] = v.z; tile[r][c4 + 3] = v.w;
    __syncthreads();
    bf16x4 o;
    o[0] = (__bf16)tile[c4][r];
    o[1] = (__bf16)tile[c4 + 1][r];
    o[2] = (__bf16)tile[c4 + 2][r];
    o[3] = (__bf16)tile[c4 + 3][r];
    *reinterpret_cast<bf16x4*>(dst + (long)(n0 + r) * K + k0 + c4) = o;
}

// ---------- wte fp32 -> bf16 (zero-pads rows >= V) ----------
__global__ __launch_bounds__(256) void wcvt(
    const float* __restrict__ wte, __bf16* __restrict__ out, long nvalid)
{
    long e = ((long)blockIdx.x * 256 + threadIdx.x) * 8;
    bf16x8 o;
    if (e < nvalid) {
        float4 a = *reinterpret_cast<const float4*>(wte + e);
        float4 b = *reinterpret_cast<const float4*>(wte + e + 4);
        o[0] = (__bf16)a.x; o[1] = (__bf16)a.y; o[2] = (__bf16)a.z; o[3] = (__bf16)a.w;
        o[4] = (__bf16)b.x; o[5] = (__bf16)b.y; o[6] = (__bf16)b.z; o[7] = (__bf16)b.w;
    } else {
        #pragma unroll
        for (int i = 0; i < 8; i++) o[i] = (__bf16)0.f;
    }
    *reinterpret_cast<bf16x8*>(out + e) = o;
}

// ---------- small GEMV path (img projections), deterministic ksplit ----------
__global__ __launch_bounds__(256) void gemv_part(
    const float* __restrict__ x, int xld,
    const float* __restrict__ W, long wzs,
    float* __restrict__ part, int K, int N)
{
    int jb = blockIdx.x, kz = blockIdx.y, z = blockIdx.z;
    int t = threadIdx.x;
    int j = (jb << 6) + (t & 63);
    int g = t >> 6;
    int klen = K / (gridDim.y * 4);
    int kbase = (kz * 4 + g) * klen;
    const float* Wp = W + (long)z * wzs + (long)kbase * N + j;
    const float* x0 = x + kbase;
    const float* x1 = x + xld + kbase;
    float a0 = 0.f, a1 = 0.f;
    for (int k = 0; k < klen; k++) {
        float wv = Wp[(long)k * N];
        a0 += x0[k] * wv;
        a1 += x1[k] * wv;
    }
    __shared__ float r0[4][64], r1[4][64];
    r0[g][t & 63] = a0; r1[g][t & 63] = a1;
    __syncthreads();
    if (t < 64) {
        a0 = r0[0][t] + r0[1][t] + r0[2][t] + r0[3][t];
        a1 = r1[0][t] + r1[1][t] + r1[2][t] + r1[3][t];
        long base = (long)(z * gridDim.y + kz) * 2 * N + (jb << 6) + t;
        part[base]     = a0;
        part[base + N] = a1;
    }
}

__global__ __launch_bounds__(256) void gemv_reduce(
    const float* __restrict__ part, const float* __restrict__ bias, long bzs,
    float* __restrict__ out, int N, int nz, int act)
{
    int idx = blockIdx.x * 256 + threadIdx.x;
    if (idx >= nz * 2 * N) return;
    int j  = idx % N;
    int bz = idx / N;
    int z  = bz >> 1;
    float s = bias[(long)z * bzs + j];
    const float* p = part + ((long)z * 8 * 2 + (bz & 1)) * N + j;
    #pragma unroll
    for (int kz = 0; kz < 8; kz++) s += p[(long)kz * 2 * N];
    if (act) s = fmaxf(s, 0.f);
    out[idx] = s;
}

// ---------- embedding ----------
__global__ __launch_bounds__(256) void embed_k(
    const int* __restrict__ ids, const float* __restrict__ wte, float* __restrict__ h)
{
    int row = blockIdx.x;
    int s = row & 511;
    int t = threadIdx.x;
    long id = ids[row];
    float4 v1 = reinterpret_cast<const float4*>(wte + id * 1024)[t];
    float4 v2 = reinterpret_cast<const float4*>(wte + (long)s * 1024)[t];
    float4 o; o.x = v1.x + v2.x; o.y = v1.y + v2.y; o.z = v1.z + v2.z; o.w = v1.w + v2.w;
    reinterpret_cast<float4*>(h + (long)row * 1024)[t] = o;
}

// ---------- LayerNorm, fp32 in -> bf16 out ----------
__global__ __launch_bounds__(256) void ln_k(
    const float* __restrict__ in, __bf16* __restrict__ out,
    const float* __restrict__ g, const float* __restrict__ b)
{
    int row = blockIdx.x, t = threadIdx.x;
    float4 v = reinterpret_cast<const float4*>(in + (long)row * 1024)[t];
    float s1 = v.x + v.y + v.z + v.w;
    float s2 = v.x * v.x + v.y * v.y + v.z * v.z + v.w * v.w;
    #pragma unroll
    for (int o = 32; o >= 1; o >>= 1) { s1 += __shfl_xor(s1, o); s2 += __shfl_xor(s2, o); }
    __shared__ float r1[4], r2[4];
    int w = t >> 6;
    if ((t & 63) == 0) { r1[w] = s1; r2[w] = s2; }
    __syncthreads();
    s1 = r1[0] + r1[1] + r1[2] + r1[3];
    s2 = r2[0] + r2[1] + r2[2] + r2[3];
    float mean = s1 * (1.0f / 1024.0f);
    float var  = s2 * (1.0f / 1024.0f) - mean * mean;
    float rstd = rsqrtf(var + 1e-5f);
    float4 gg = reinterpret_cast<const float4*>(g)[t];
    float4 bb = reinterpret_cast<const float4*>(b)[t];
    bf16x4 o;
    o[0] = (__bf16)((v.x - mean) * rstd * gg.x + bb.x);
    o[1] = (__bf16)((v.y - mean) * rstd * gg.y + bb.y);
    o[2] = (__bf16)((v.z - mean) * rstd * gg.z + bb.z);
    o[3] = (__bf16)((v.w - mean) * rstd * gg.w + bb.w);
    *reinterpret_cast<bf16x4*>(out + (long)row * 1024 + t * 4) = o;
}

// ---------- fused: h += bias + sum(parts); write h; out = LN(h) ----------
__global__ __launch_bounds__(256) void lnadd_k(
    float* __restrict__ h, const float* __restrict__ part,
    const float* __restrict__ bias,
    const float* __restrict__ g, const float* __restrict__ b,
    __bf16* __restrict__ out)
{
    int row = blockIdx.x, t = threadIdx.x;
    long off = (long)row * 1024 + t * 4;
    float4 v = *reinterpret_cast<const float4*>(h + off);
    #pragma unroll
    for (int sp = 0; sp < 4; sp++) {
        float4 pv = *reinterpret_cast<const float4*>(part + sp * 1048576L + off);
        v.x += pv.x; v.y += pv.y; v.z += pv.z; v.w += pv.w;
    }
    float4 bi = reinterpret_cast<const float4*>(bias)[t];
    v.x += bi.x; v.y += bi.y; v.z += bi.z; v.w += bi.w;
    *reinterpret_cast<float4*>(h + off) = v;

    float s1 = v.x + v.y + v.z + v.w;
    float s2 = v.x * v.x + v.y * v.y + v.z * v.z + v.w * v.w;
    #pragma unroll
    for (int o = 32; o >= 1; o >>= 1) { s1 += __shfl_xor(s1, o); s2 += __shfl_xor(s2, o); }
    __shared__ float r1[4], r2[4];
    int w = t >> 6;
    if ((t & 63) == 0) { r1[w] = s1; r2[w] = s2; }
    __syncthreads();
    s1 = r1[0] + r1[1] + r1[2] + r1[3];
    s2 = r2[0] + r2[1] + r2[2] + r2[3];
    float mean = s1 * (1.0f / 1024.0f);
    float var  = s2 * (1.0f / 1024.0f) - mean * mean;
    float rstd = rsqrtf(var + 1e-5f);
    float4 gg = reinterpret_cast<const float4*>(g)[t];
    float4 bb = reinterpret_cast<const float4*>(b)[t];
    bf16x4 o;
    o[0] = (__bf16)((v.x - mean) * rstd * gg.x + bb.x);
    o[1] = (__bf16)((v.y - mean) * rstd * gg.y + bb.y);
    o[2] = (__bf16)((v.z - mean) * rstd * gg.z + bb.z);
    o[3] = (__bf16)((v.w - mean) * rstd * gg.w + bb.w);
    *reinterpret_cast<bf16x4*>(out + off) = o;
}

// ---------- 128x128 bf16 MFMA GEMM, 1D grid + XCD swizzle + optional K-split ----------
// A[M][K] bf16, Bt[rows][K] bf16. PARTIAL: write fp32 partial at C + sp*M*N.
template<int OUTBF16, int ACT, int NBOUND, int PARTIAL>
__global__ __launch_bounds__(256) void gemm_s(
    const __bf16* __restrict__ A, const __bf16* __restrict__ Bt,
    const float* __restrict__ bias, void* __restrict__ C,
    int N, int K, int GM, int GN, int NS)
{
    // bijective XCD swizzle (m204): XCD = bid%8 gets a contiguous work chunk,
    // work decodes m-fastest so same-B-panel blocks share one XCD's L2.
    const int total = GM * GN * NS;
    const int q = total >> 3, r = total & 7;
    const int x = blockIdx.x & 7, j = blockIdx.x >> 3;
    const int w0 = (x < r) ? x * (q + 1) + j : r * (q + 1) + (x - r) * q + j;
    const int sp = w0 / (GM * GN);
    const int rem = w0 - sp * (GM * GN);
    const int m0 = (rem % GM) * 128;
    const int n0 = (rem / GM) * 128;

    __shared__ __bf16 As[128 * 32];
    __shared__ __bf16 Bs[128 * 32];
    const int t = threadIdx.x;
    const int wv = t >> 6, lane = t & 63;
    const int lo = lane & 15, hi = lane >> 4;
    const int wr = wv >> 1, wc = wv & 1;

    f32x4 acc[4][4] = {};

    const int Ksp = K / NS;
    const int kbeg = sp * Ksp, kend = kbeg + Ksp;
    for (int k0 = kbeg; k0 < kend; k0 += 32) {
        __syncthreads();
        #pragma unroll
        for (int i = 0; i < 2; i++) {
            int c = i * 256 + t;
            GLDS16(A + (long)(m0 + (c >> 2)) * K + k0 + ((c & 3) << 3), &As[c * 8]);
        }
        #pragma unroll
        for (int i = 0; i < 2; i++) {
            int c = i * 256 + t;
            GLDS16(Bt + (long)(n0 + (c >> 2)) * K + k0 + ((c & 3) << 3), &Bs[c * 8]);
        }
        __syncthreads();
        bf16x8 afr[4], bfr[4];
        #pragma unroll
        for (int mi = 0; mi < 4; mi++)
            afr[mi] = *reinterpret_cast<const bf16x8*>(&As[(wr * 64 + mi * 16 + lo) * 32 + hi * 8]);
        #pragma unroll
        for (int ni = 0; ni < 4; ni++)
            bfr[ni] = *reinterpret_cast<const bf16x8*>(&Bs[(wc * 64 + ni * 16 + lo) * 32 + hi * 8]);
        #pragma unroll
        for (int mi = 0; mi < 4; mi++)
            #pragma unroll
            for (int ni = 0; ni < 4; ni++)
                acc[mi][ni] = __builtin_amdgcn_mfma_f32_16x16x32_bf16(afr[mi], bfr[ni], acc[mi][ni], 0, 0, 0);
    }

    const long coff = PARTIAL ? (long)sp * GM * 128 * N : 0;
    #pragma unroll
    for (int mi = 0; mi < 4; mi++)
        #pragma unroll
        for (int ni = 0; ni < 4; ni++) {
            int col = n0 + wc * 64 + ni * 16 + lo;
            if (NBOUND && col >= N) continue;
            float bv = (!PARTIAL && bias) ? bias[col] : 0.f;
            #pragma unroll
            for (int rr = 0; rr < 4; rr++) {
                int row = m0 + wr * 64 + mi * 16 + hi * 4 + rr;
                float v = acc[mi][ni][rr] + bv;
                if (ACT) v = gelu_f(v);
                if (OUTBF16) ((__bf16*)C)[(long)row * N + col] = (__bf16)v;
                else         ((float*)C)[coff + (long)row * N + col] = v;
            }
        }
}

// ---------- 64x64 GEMM (proj / fallback fc2): residual epilogue ----------
template<int OUTBF16, int ACT, int RES>
__global__ __launch_bounds__(256) void gemm_bb(
    const __bf16* __restrict__ A, const __bf16* __restrict__ Bt,
    const float* __restrict__ bias, const float* __restrict__ res,
    void* __restrict__ C, int N, int K)
{
    __shared__ __bf16 As[64 * 32];
    __shared__ __bf16 Bs[64 * 32];
    const int t = threadIdx.x;
    const int m0 = blockIdx.x * 64;
    const int n0 = blockIdx.y * 64;
    const int w = t >> 6, lane = t & 63;
    const int lo = lane & 15, hi = lane >> 4;
    const int wr = w >> 1, wc = w & 1;

    f32x4 acc[2][2] = {};

    for (int k0 = 0; k0 < K; k0 += 32) {
        __syncthreads();
        {
            int c = t;
            GLDS16(A + (long)(m0 + (c >> 2)) * K + k0 + ((c & 3) << 3), &As[c * 8]);
            GLDS16(Bt + (long)(n0 + (c >> 2)) * K + k0 + ((c & 3) << 3), &Bs[c * 8]);
        }
        __syncthreads();
        bf16x8 afr[2], bfr[2];
        #pragma unroll
        for (int mi = 0; mi < 2; mi++)
            afr[mi] = *reinterpret_cast<const bf16x8*>(&As[(wr * 32 + mi * 16 + lo) * 32 + hi * 8]);
        #pragma unroll
        for (int ni = 0; ni < 2; ni++)
            bfr[ni] = *reinterpret_cast<const bf16x8*>(&Bs[(wc * 32 + ni * 16 + lo) * 32 + hi * 8]);
        #pragma unroll
        for (int mi = 0; mi < 2; mi++)
            #pragma unroll
            for (int ni = 0; ni < 2; ni++)
                acc[mi][ni] = __builtin_amdgcn_mfma_f32_16x16x32_bf16(afr[mi], bfr[ni], acc[mi][ni], 0, 0, 0);
    }

    #pragma unroll
    for (int mi = 0; mi < 2; mi++)
        #pragma unroll
        for (int ni = 0; ni < 2; ni++) {
            int col = n0 + wc * 32 + ni * 16 + lo;
            float bv = bias ? bias[col] : 0.f;
            #pragma unroll
            for (int rr = 0; rr < 4; rr++) {
                int row = m0 + wr * 32 + mi * 16 + hi * 4 + rr;
                float v = acc[mi][ni][rr] + bv;
                if (ACT) v = gelu_f(v);
                if (RES) v += res[(long)row * N + col];
                if (OUTBF16) ((__bf16*)C)[(long)row * N + col] = (__bf16)v;
                else         ((float*)C)[(long)row * N + col] = v;
            }
        }
}

// ---------- LM head fallback: A bf16 (glds), Wt[N][K] fp32 reg-staged ----------
__global__ __launch_bounds__(256) void gemm_lm(
    const __bf16* __restrict__ A, const float* __restrict__ Wt,
    float* __restrict__ C, int N, int K)
{
    __shared__ __bf16 As[128 * 32];
    __shared__ __bf16 Bs[128 * 32];
    const int t = threadIdx.x;
    const int m0 = blockIdx.x * 128;
    const int n0 = blockIdx.y * 128;
    const int w = t >> 6, lane = t & 63;
    const int lo = lane & 15, hi = lane >> 4;
    const int wr = w >> 1, wc = w & 1;

    f32x4 acc[4][4] = {};

    for (int k0 = 0; k0 < K; k0 += 32) {
        __syncthreads();
        #pragma unroll
        for (int i = 0; i < 2; i++) {
            int c = i * 256 + t;
            GLDS16(A + (long)(m0 + (c >> 2)) * K + k0 + ((c & 3) << 3), &As[c * 8]);
        }
        #pragma unroll
        for (int i = 0; i < 2; i++) {
            int c = i * 256 + t;
            int nr = n0 + (c >> 2);
            bf16x8 bv;
            if (nr < N) {
                const float* wp = Wt + (long)nr * K + k0 + ((c & 3) << 3);
                float4 b0 = *reinterpret_cast<const float4*>(wp);
                float4 b1 = *reinterpret_cast<const float4*>(wp + 4);
                bv[0] = (__bf16)b0.x; bv[1] = (__bf16)b0.y; bv[2] = (__bf16)b0.z; bv[3] = (__bf16)b0.w;
                bv[4] = (__bf16)b1.x; bv[5] = (__bf16)b1.y; bv[6] = (__bf16)b1.z; bv[7] = (__bf16)b1.w;
            } else {
                #pragma unroll
                for (int qq = 0; qq < 8; qq++) bv[qq] = (__bf16)0.f;
            }
            *reinterpret_cast<bf16x8*>(&Bs[c * 8]) = bv;
        }
        __syncthreads();
        bf16x8 afr[4], bfr[4];
        #pragma unroll
        for (int mi = 0; mi < 4; mi++)
            afr[mi] = *reinterpret_cast<const bf16x8*>(&As[(wr * 64 + mi * 16 + lo) * 32 + hi * 8]);
        #pragma unroll
        for (int ni = 0; ni < 4; ni++)
            bfr[ni] = *reinterpret_cast<const bf16x8*>(&Bs[(wc * 64 + ni * 16 + lo) * 32 + hi * 8]);
        #pragma unroll
        for (int mi = 0; mi < 4; mi++)
            #pragma unroll
            for (int ni = 0; ni < 4; ni++)
                acc[mi][ni] = __builtin_amdgcn_mfma_f32_16x16x32_bf16(afr[mi], bfr[ni], acc[mi][ni], 0, 0, 0);
    }

    #pragma unroll
    for (int mi = 0; mi < 4; mi++)
        #pragma unroll
        for (int ni = 0; ni < 4; ni++) {
            int col = n0 + wc * 64 + ni * 16 + lo;
            if (col < N) {
                #pragma unroll
                for (int rr = 0; rr < 4; rr++) {
                    int row = m0 + wr * 64 + mi * 16 + hi * 4 + rr;
                    C[(long)row * N + col] = acc[mi][ni][rr];
                }
            }
        }
}

// ---------- MFMA flash attention, no-max-tracking (scores analytically bounded) ----------
__global__ __launch_bounds__(256) void attn_mfma(
    const __bf16* __restrict__ qkv,
    const float* __restrict__ imgk, const float* __restrict__ imgv,
    const float* __restrict__ amask, __bf16* __restrict__ out)
{
    const int qb = blockIdx.x;
    const int h  = blockIdx.y;
    const int b  = blockIdx.z;
    const int t = threadIdx.x, w = t >> 6, lane = t & 63;
    const int lo = lane & 15, hi = lane >> 4;

    __shared__ __bf16 Ks[64][72];
    __shared__ __bf16 Vt[64][72];
    __shared__ __bf16 Ps[4][16][72];
    __shared__ float kimg_s[64];
    __shared__ float amv_s[64];

    const __bf16* qrow = qkv + (long)(b * 512 + qb * 64 + w * 16 + lo) * 3072 + h * 64;
    bf16x8 qf0 = *reinterpret_cast<const bf16x8*>(qrow + hi * 8);
    bf16x8 qf1 = *reinterpret_cast<const bf16x8*>(qrow + 32 + hi * 8);

    if (t < 64) kimg_s[t] = imgk[b * 1024 + h * 64 + t];
    __syncthreads();

    float simg = 0.f;
    #pragma unroll
    for (int i = 0; i < 8; i++)
        simg += (float)qf0[i] * kimg_s[hi * 8 + i] + (float)qf1[i] * kimg_s[32 + hi * 8 + i];
    simg += __shfl_xor(simg, 16);
    simg += __shfl_xor(simg, 32);
    simg *= 0.125f;

    float pimg[4], l_part[4];
    f32x4 o_acc[4];
    #pragma unroll
    for (int rr = 0; rr < 4; rr++) {
        pimg[rr] = __expf(__shfl(simg, hi * 4 + rr));
        l_part[rr] = 0.f;
    }
    #pragma unroll
    for (int df = 0; df < 4; df++) {
        float vi = imgv[b * 1024 + h * 64 + df * 16 + lo];
        #pragma unroll
        for (int rr = 0; rr < 4; rr++) o_acc[df][rr] = pimg[rr] * vi;
    }

    for (int kb = 0; kb <= qb; kb++) {
        __syncthreads();
        {
            int r = t >> 2, dg = (t & 3) * 16;
            const __bf16* src = qkv + (long)(b * 512 + kb * 64 + r) * 3072 + 1024 + h * 64 + dg;
            *reinterpret_cast<bf16x8*>(&Ks[r][dg])     = *reinterpret_cast<const bf16x8*>(src);
            *reinterpret_cast<bf16x8*>(&Ks[r][dg + 8]) = *reinterpret_cast<const bf16x8*>(src + 8);
        }
        {
            int r = t & 63, dg = (t >> 6) * 16;
            const __bf16* src = qkv + (long)(b * 512 + kb * 64 + r) * 3072 + 2048 + h * 64 + dg;
            bf16x8 v0 = *reinterpret_cast<const bf16x8*>(src);
            bf16x8 v1 = *reinterpret_cast<const bf16x8*>(src + 8);
            #pragma unroll
            for (int i = 0; i < 8; i++) { Vt[dg + i][r] = v0[i]; Vt[dg + 8 + i][r] = v1[i]; }
        }
        if (t < 64) amv_s[t] = (1.0f - amask[b * 512 + kb * 64 + t]) * -10000.0f;
        __syncthreads();

        f32x4 sf[4];
        #pragma unroll
        for (int js = 0; js < 4; js++) {
            bf16x8 kf0 = *reinterpret_cast<const bf16x8*>(&Ks[js * 16 + lo][hi * 8]);
            bf16x8 kf1 = *reinterpret_cast<const bf16x8*>(&Ks[js * 16 + lo][32 + hi * 8]);
            f32x4 a = {};
            a = __builtin_amdgcn_mfma_f32_16x16x32_bf16(qf0, kf0, a, 0, 0, 0);
            a = __builtin_amdgcn_mfma_f32_16x16x32_bf16(qf1, kf1, a, 0, 0, 0);
            sf[js] = a;
        }
        #pragma unroll
        for (int js = 0; js < 4; js++) {
            float amv = amv_s[js * 16 + lo];
            #pragma unroll
            for (int rr = 0; rr < 4; rr++) {
                float sv = sf[js][rr] * 0.125f + amv;
                if (kb == qb) {
                    int qrw = w * 16 + hi * 4 + rr;
                    if (js * 16 + lo > qrw) sv = -10000.0f + amv;
                }
                float p = __expf(sv);
                l_part[rr] += p;
                Ps[w][hi * 4 + rr][js * 16 + lo] = (__bf16)p;
            }
        }
        #pragma unroll
        for (int jb = 0; jb < 2; jb++) {
            bf16x8 pf = *reinterpret_cast<const bf16x8*>(&Ps[w][lo][jb * 32 + hi * 8]);
            #pragma unroll
            for (int df = 0; df < 4; df++) {
                bf16x8 vf = *reinterpret_cast<const bf16x8*>(&Vt[df * 16 + lo][jb * 32 + hi * 8]);
                o_acc[df] = __builtin_amdgcn_mfma_f32_16x16x32_bf16(pf, vf, o_acc[df], 0, 0, 0);
            }
        }
    }

    float linv[4];
    #pragma unroll
    for (int rr = 0; rr < 4; rr++) {
        float ls = l_part[rr];
        #pragma unroll
        for (int off = 1; off < 16; off <<= 1) ls += __shfl_xor(ls, off);
        linv[rr] = 1.0f / (pimg[rr] + ls);
    }
    #pragma unroll
    for (int df = 0; df < 4; df++)
        #pragma unroll
        for (int rr = 0; rr < 4; rr++) {
            long row = b * 512 + qb * 64 + w * 16 + hi * 4 + rr;
            out[row * 1024 + h * 64 + df * 16 + lo] = (__bf16)(o_acc[df][rr] * linv[rr]);
        }
}

// ---------- host orchestration ----------
extern "C" void kernel_launch(void* const* d_in, const int* in_sizes, int n_in,
                              void* d_out, int out_size, void* d_ws, size_t ws_size,
                              hipStream_t stream) {
    (void)in_sizes; (void)n_in; (void)out_size;
    const int*   ids   = (const int*)d_in[0];
    const float* amask = (const float*)d_in[1];
    const float* ihs   = (const float*)d_in[2];
    const float* wte   = (const float*)d_in[3];
    const float* ftW1  = (const float*)d_in[4];
    const float* ftb1  = (const float*)d_in[5];
    const float* ftW2  = (const float*)d_in[6];
    const float* ftb2  = (const float*)d_in[7];
    const float* ln1g  = (const float*)d_in[8];
    const float* ln1b  = (const float*)d_in[9];
    const float* Wattn = (const float*)d_in[10];
    const float* battn = (const float*)d_in[11];
    const float* Wuk   = (const float*)d_in[12];
    const float* buk   = (const float*)d_in[13];
    const float* Wuv   = (const float*)d_in[14];
    const float* buv   = (const float*)d_in[15];
    const float* Wproj = (const float*)d_in[16];
    const float* bproj = (const float*)d_in[17];
    const float* ln2g  = (const float*)d_in[18];
    const float* ln2b  = (const float*)d_in[19];
    const float* Wfc   = (const float*)d_in[20];
    const float* bfc   = (const float*)d_in[21];
    const float* Wfc2  = (const float*)d_in[22];
    const float* bfc2  = (const float*)d_in[23];
    const float* lnfg  = (const float*)d_in[24];
    const float* lnfb  = (const float*)d_in[25];
    float* out = (float*)d_out;

    const long VP = 50304;
    char* base = (char*)d_ws;
    float* ftmp  = (float*)(base);
    float* img   = (float*)(base + (1 << 13));
    float* imgk  = (float*)(base + (1 << 14));
    float* imgv  = (float*)(base + 114688);
    float* part  = (float*)(base + 212992);
    float* h     = (float*)(base + 1048576);
    char* p = base + 5 * 1048576;
    __bf16* xb    = (__bf16*)p; p += 2 * 1048576;
    __bf16* qkvb  = (__bf16*)p; p += 6 * 1048576;
    __bf16* attob = (__bf16*)p; p += 2 * 1048576;
    __bf16* ffb   = (__bf16*)p; p += 8 * 1048576;
    __bf16* wtA   = (__bf16*)p; p += 6 * 1048576;
    __bf16* wtP   = (__bf16*)p; p += 2 * 1048576;
    __bf16* wtF   = (__bf16*)p; p += 8 * 1048576;
    __bf16* wtF2  = (__bf16*)p; p += 8 * 1048576;
    __bf16* wteb  = (__bf16*)p;
    size_t need1 = (size_t)(p - base) + (size_t)VP * 1024 * 2;
    float* part_fc2 = (float*)(base + need1);
    size_t need2 = need1 + 4 * 1048576 * sizeof(float);
    const bool big_ws  = (ws_size >= need1);
    const bool big_ws2 = (ws_size >= need2);

    dim3 b256(256);

    gemv_part<<<dim3(16, 8, 1), b256, 0, stream>>>(ihs, 1024, ftW1, 0, part, 1024, 1024);
    gemv_reduce<<<dim3(8), b256, 0, stream>>>(part, ftb1, 0, ftmp, 1024, 1, 1);
    gemv_part<<<dim3(16, 8, 1), b256, 0, stream>>>(ftmp, 1024, ftW2, 0, part, 1024, 1024);
    gemv_reduce<<<dim3(8), b256, 0, stream>>>(part, ftb2, 0, img, 1024, 1, 0);
    gemv_part<<<dim3(16, 8, 12), b256, 0, stream>>>(img, 1024, Wuk, 1024L * 1024, part, 1024, 1024);
    gemv_reduce<<<dim3(96), b256, 0, stream>>>(part, buk, 1024, imgk, 1024, 12, 0);
    gemv_part<<<dim3(16, 8, 12), b256, 0, stream>>>(img, 1024, Wuv, 1024L * 1024, part, 1024, 1024);
    gemv_reduce<<<dim3(96), b256, 0, stream>>>(part, buv, 1024, imgv, 1024, 12, 0);

    embed_k<<<dim3(1024), b256, 0, stream>>>(ids, wte, h);
    ln_k<<<dim3(1024), b256, 0, stream>>>(h, xb, ln1g, ln1b);   // ln1 of layer 0

    for (int l = 0; l < 12; l++) {
        tcvt_layer<<<dim3(12288), b256, 0, stream>>>(
            Wattn + (long)l * 1024 * 3072, Wproj + (long)l * 1024 * 1024,
            Wfc + (long)l * 1024 * 4096, Wfc2 + (long)l * 4096 * 1024,
            wtA, wtP, wtF, wtF2);

        // qkv: 128x128, 192 blocks, XCD-swizzled
        gemm_s<1, 0, 0, 0><<<dim3(192), b256, 0, stream>>>(
            xb, wtA, battn + l * 3072, qkvb, 3072, 1024, 8, 24, 1);
        attn_mfma<<<dim3(8, 16, 2), b256, 0, stream>>>(
            qkvb, imgk + l * 2048, imgv + l * 2048, amask, attob);
        gemm_bb<0, 0, 1><<<dim3(16, 16), b256, 0, stream>>>(
            attob, wtP, bproj + l * 1024, h, h, 1024, 1024);
        ln_k<<<dim3(1024), b256, 0, stream>>>(h, xb, ln2g + l * 1024, ln2b + l * 1024);
        gemm_s<1, 1, 0, 0><<<dim3(256), b256, 0, stream>>>(
            xb, wtF, bfc + l * 4096, ffb, 4096, 1024, 8, 32, 1);

        const float* ng = (l < 11) ? (ln1g + (l + 1) * 1024) : lnfg;
        const float* nb = (l < 11) ? (ln1b + (l + 1) * 1024) : lnfb;
        if (big_ws2) {
            // fc2 as ksplit-4 partials + fused add/LN
            gemm_s<0, 0, 0, 1><<<dim3(256), b256, 0, stream>>>(
                ffb, wtF2, nullptr, part_fc2, 1024, 4096, 8, 8, 4);
            lnadd_k<<<dim3(1024), b256, 0, stream>>>(h, part_fc2, bfc2 + l * 1024, ng, nb, xb);
        } else {
            gemm_bb<0, 0, 1><<<dim3(16, 16), b256, 0, stream>>>(
                ffb, wtF2, bfc2 + l * 1024, h, h, 1024, 4096);
            ln_k<<<dim3(1024), b256, 0, stream>>>(h, xb, ng, nb);
        }
    }

    // xb now holds lnf(h); convert wte late so it's L3-warm for the LM head
    if (big_ws) {
        wcvt<<<dim3((unsigned)(VP * 1024 / 2048)), b256, 0, stream>>>(wte, wteb, 50257L * 1024);
        gemm_s<0, 0, 1, 0><<<dim3(3144), b256, 0, stream>>>(
            xb, wteb, nullptr, out, 50257, 1024, 8, 393, 1);
    } else {
        gemm_lm<<<dim3(8, 393), b256, 0, stream>>>(xb, wte, out, 50257, 1024);
    }
}

// Round 5
// 1933.297 us; speedup vs baseline: 2.8853x; 1.0555x over previous
//
#include <hip/hip_runtime.h>
#include <cstdint>

// B=2, S=512, D=1024, H=16, HD=64, L=12, V=50257, DFF=4096

typedef __bf16 bf16x8 __attribute__((ext_vector_type(8)));
typedef __bf16 bf16x4 __attribute__((ext_vector_type(4)));
typedef float  f32x4  __attribute__((ext_vector_type(4)));

#define GLDS16(g, l) __builtin_amdgcn_global_load_lds( \
    (const __attribute__((address_space(1))) unsigned int*)(g), \
    (__attribute__((address_space(3))) unsigned int*)(l), 16, 0, 0)

#define SCHED_FENCE() __builtin_amdgcn_sched_barrier(0)

__device__ __forceinline__ float gelu_f(float x) {
    float u = 1.5957691216057308f * (x + 0.044715f * x * x * x);
    float e = __expf(u);
    float t = 1.0f - 2.0f / (e + 1.0f);
    return 0.5f * x * (1.0f + t);
}

// ---------- per-layer weight transpose+convert, all 4 mats in one launch ----------
__global__ __launch_bounds__(256) void tcvt_layer(
    const float* __restrict__ Wa, const float* __restrict__ Wp,
    const float* __restrict__ Wf, const float* __restrict__ Wf2,
    __bf16* __restrict__ oa, __bf16* __restrict__ op,
    __bf16* __restrict__ of, __bf16* __restrict__ of2)
{
    int id = blockIdx.x;
    const float* src; __bf16* dst; int K, N, kb, nb;
    if (id < 3072)      { src = Wa;  dst = oa;  K = 1024; N = 3072; kb = id & 31;  nb = id >> 5; }
    else if (id < 4096) { id -= 3072; src = Wp;  dst = op;  K = 1024; N = 1024; kb = id & 31;  nb = id >> 5; }
    else if (id < 8192) { id -= 4096; src = Wf;  dst = of;  K = 1024; N = 4096; kb = id & 31;  nb = id >> 5; }
    else                { id -= 8192; src = Wf2; dst = of2; K = 4096; N = 1024; kb = id & 127; nb = id >> 7; }
    const int k0 = kb * 32, n0 = nb * 32;
    __shared__ float tile[32][33];
    const int t = threadIdx.x;
    const int r = t >> 3, c4 = (t & 7) * 4;
    float4 v = *reinterpret_cast<const float4*>(src + (long)(k0 + r) * N + n0 + c4);
    tile[r][c4] = v.x; tile[r][c4 + 1] = v.y; tile[r][c4 + 2] = v.z; tile[r][c4 + 3] = v.w;
    __syncthreads();
    bf16x4 o;
    o[0] = (__bf16)tile[c4][r];
    o[1] = (__bf16)tile[c4 + 1][r];
    o[2] = (__bf16)tile[c4 + 2][r];
    o[3] = (__bf16)tile[c4 + 3][r];
    *reinterpret_cast<bf16x4*>(dst + (long)(n0 + r) * K + k0 + c4) = o;
}

// ---------- wte fp32 -> bf16 (zero-pads rows >= V) ----------
__global__ __launch_bounds__(256) void wcvt(
    const float* __restrict__ wte, __bf16* __restrict__ out, long nvalid)
{
    long e = ((long)blockIdx.x * 256 + threadIdx.x) * 8;
    bf16x8 o;
    if (e < nvalid) {
        float4 a = *reinterpret_cast<const float4*>(wte + e);
        float4 b = *reinterpret_cast<const float4*>(wte + e + 4);
        o[0] = (__bf16)a.x; o[1] = (__bf16)a.y; o[2] = (__bf16)a.z; o[3] = (__bf16)a.w;
        o[4] = (__bf16)b.x; o[5] = (__bf16)b.y; o[6] = (__bf16)b.z; o[7] = (__bf16)b.w;
    } else {
        #pragma unroll
        for (int i = 0; i < 8; i++) o[i] = (__bf16)0.f;
    }
    *reinterpret_cast<bf16x8*>(out + e) = o;
}

// ---------- small GEMV path (img projections), deterministic ksplit ----------
__global__ __launch_bounds__(256) void gemv_part(
    const float* __restrict__ x, int xld,
    const float* __restrict__ W, long wzs,
    float* __restrict__ part, int K, int N)
{
    int jb = blockIdx.x, kz = blockIdx.y, z = blockIdx.z;
    int t = threadIdx.x;
    int j = (jb << 6) + (t & 63);
    int g = t >> 6;
    int klen = K / (gridDim.y * 4);
    int kbase = (kz * 4 + g) * klen;
    const float* Wp = W + (long)z * wzs + (long)kbase * N + j;
    const float* x0 = x + kbase;
    const float* x1 = x + xld + kbase;
    float a0 = 0.f, a1 = 0.f;
    for (int k = 0; k < klen; k++) {
        float wv = Wp[(long)k * N];
        a0 += x0[k] * wv;
        a1 += x1[k] * wv;
    }
    __shared__ float r0[4][64], r1[4][64];
    r0[g][t & 63] = a0; r1[g][t & 63] = a1;
    __syncthreads();
    if (t < 64) {
        a0 = r0[0][t] + r0[1][t] + r0[2][t] + r0[3][t];
        a1 = r1[0][t] + r1[1][t] + r1[2][t] + r1[3][t];
        long base = (long)(z * gridDim.y + kz) * 2 * N + (jb << 6) + t;
        part[base]     = a0;
        part[base + N] = a1;
    }
}

__global__ __launch_bounds__(256) void gemv_reduce(
    const float* __restrict__ part, const float* __restrict__ bias, long bzs,
    float* __restrict__ out, int N, int nz, int act)
{
    int idx = blockIdx.x * 256 + threadIdx.x;
    if (idx >= nz * 2 * N) return;
    int j  = idx % N;
    int bz = idx / N;
    int z  = bz >> 1;
    float s = bias[(long)z * bzs + j];
    const float* p = part + ((long)z * 8 * 2 + (bz & 1)) * N + j;
    #pragma unroll
    for (int kz = 0; kz < 8; kz++) s += p[(long)kz * 2 * N];
    if (act) s = fmaxf(s, 0.f);
    out[idx] = s;
}

// ---------- embedding ----------
__global__ __launch_bounds__(256) void embed_k(
    const int* __restrict__ ids, const float* __restrict__ wte, float* __restrict__ h)
{
    int row = blockIdx.x;
    int s = row & 511;
    int t = threadIdx.x;
    long id = ids[row];
    float4 v1 = reinterpret_cast<const float4*>(wte + id * 1024)[t];
    float4 v2 = reinterpret_cast<const float4*>(wte + (long)s * 1024)[t];
    float4 o; o.x = v1.x + v2.x; o.y = v1.y + v2.y; o.z = v1.z + v2.z; o.w = v1.w + v2.w;
    reinterpret_cast<float4*>(h + (long)row * 1024)[t] = o;
}

// ---------- LayerNorm, fp32 in -> bf16 out ----------
__global__ __launch_bounds__(256) void ln_k(
    const float* __restrict__ in, __bf16* __restrict__ out,
    const float* __restrict__ g, const float* __restrict__ b)
{
    int row = blockIdx.x, t = threadIdx.x;
    float4 v = reinterpret_cast<const float4*>(in + (long)row * 1024)[t];
    float s1 = v.x + v.y + v.z + v.w;
    float s2 = v.x * v.x + v.y * v.y + v.z * v.z + v.w * v.w;
    #pragma unroll
    for (int o = 32; o >= 1; o >>= 1) { s1 += __shfl_xor(s1, o); s2 += __shfl_xor(s2, o); }
    __shared__ float r1[4], r2[4];
    int w = t >> 6;
    if ((t & 63) == 0) { r1[w] = s1; r2[w] = s2; }
    __syncthreads();
    s1 = r1[0] + r1[1] + r1[2] + r1[3];
    s2 = r2[0] + r2[1] + r2[2] + r2[3];
    float mean = s1 * (1.0f / 1024.0f);
    float var  = s2 * (1.0f / 1024.0f) - mean * mean;
    float rstd = rsqrtf(var + 1e-5f);
    float4 gg = reinterpret_cast<const float4*>(g)[t];
    float4 bb = reinterpret_cast<const float4*>(b)[t];
    bf16x4 o;
    o[0] = (__bf16)((v.x - mean) * rstd * gg.x + bb.x);
    o[1] = (__bf16)((v.y - mean) * rstd * gg.y + bb.y);
    o[2] = (__bf16)((v.z - mean) * rstd * gg.z + bb.z);
    o[3] = (__bf16)((v.w - mean) * rstd * gg.w + bb.w);
    *reinterpret_cast<bf16x4*>(out + (long)row * 1024 + t * 4) = o;
}

// ---------- fused: h += bias + sum(parts); write h; out = LN(h) ----------
__global__ __launch_bounds__(256) void lnadd_k(
    float* __restrict__ h, const float* __restrict__ part,
    const float* __restrict__ bias,
    const float* __restrict__ g, const float* __restrict__ b,
    __bf16* __restrict__ out)
{
    int row = blockIdx.x, t = threadIdx.x;
    long off = (long)row * 1024 + t * 4;
    float4 v = *reinterpret_cast<const float4*>(h + off);
    #pragma unroll
    for (int sp = 0; sp < 4; sp++) {
        float4 pv = *reinterpret_cast<const float4*>(part + sp * 1048576L + off);
        v.x += pv.x; v.y += pv.y; v.z += pv.z; v.w += pv.w;
    }
    float4 bi = reinterpret_cast<const float4*>(bias)[t];
    v.x += bi.x; v.y += bi.y; v.z += bi.z; v.w += bi.w;
    *reinterpret_cast<float4*>(h + off) = v;

    float s1 = v.x + v.y + v.z + v.w;
    float s2 = v.x * v.x + v.y * v.y + v.z * v.z + v.w * v.w;
    #pragma unroll
    for (int o = 32; o >= 1; o >>= 1) { s1 += __shfl_xor(s1, o); s2 += __shfl_xor(s2, o); }
    __shared__ float r1[4], r2[4];
    int w = t >> 6;
    if ((t & 63) == 0) { r1[w] = s1; r2[w] = s2; }
    __syncthreads();
    s1 = r1[0] + r1[1] + r1[2] + r1[3];
    s2 = r2[0] + r2[1] + r2[2] + r2[3];
    float mean = s1 * (1.0f / 1024.0f);
    float var  = s2 * (1.0f / 1024.0f) - mean * mean;
    float rstd = rsqrtf(var + 1e-5f);
    float4 gg = reinterpret_cast<const float4*>(g)[t];
    float4 bb = reinterpret_cast<const float4*>(b)[t];
    bf16x4 o;
    o[0] = (__bf16)((v.x - mean) * rstd * gg.x + bb.x);
    o[1] = (__bf16)((v.y - mean) * rstd * gg.y + bb.y);
    o[2] = (__bf16)((v.z - mean) * rstd * gg.z + bb.z);
    o[3] = (__bf16)((v.w - mean) * rstd * gg.w + bb.w);
    *reinterpret_cast<bf16x4*>(out + off) = o;
}

// ---------- 128x128 bf16 GEMM, 2-phase counted-vmcnt pipeline + XCD swizzle ----------
// A[M][K] bf16, Bt[rows][K] bf16. PARTIAL: write fp32 partial at C + sp*M*N.
template<int OUTBF16, int ACT, int NBOUND, int PARTIAL>
__global__ __launch_bounds__(256) void gemm_s(
    const __bf16* __restrict__ A, const __bf16* __restrict__ Bt,
    const float* __restrict__ bias, void* __restrict__ C,
    int N, int K, int GM, int GN, int NS)
{
    const int total = GM * GN * NS;
    const int q = total >> 3, r = total & 7;
    const int x = blockIdx.x & 7, jj = blockIdx.x >> 3;
    const int w0 = (x < r) ? x * (q + 1) + jj : r * (q + 1) + (x - r) * q + jj;
    const int sp = w0 / (GM * GN);
    const int rem = w0 - sp * (GM * GN);
    const int m0 = (rem % GM) * 128;
    const int n0 = (rem / GM) * 128;

    __shared__ __bf16 As[2][128 * 32];
    __shared__ __bf16 Bs[2][128 * 32];
    const int t = threadIdx.x;
    const int wv = t >> 6, lane = t & 63;
    const int lo = lane & 15, hi = lane >> 4;
    const int wr = wv >> 1, wc = wv & 1;

    f32x4 acc[4][4] = {};

    const int Ksp = K / NS;
    const int kbeg = sp * Ksp;
    const int T = Ksp >> 5;

    // per-iter stage: 2 glds for A + 2 for B (16B/lane each)
    const int sr = t >> 2;                 // row 0..63 (round adds +64)
    const int sk = (t & 3) << 3;           // k-offset 0/8/16/24
    #define STAGE_S(bf, kk) do { \
        GLDS16(A + (long)(m0 + sr)      * K + (kk) + sk, &As[bf][(sr)      * 32 + sk]); \
        GLDS16(A + (long)(m0 + 64 + sr) * K + (kk) + sk, &As[bf][(64 + sr) * 32 + sk]); \
        GLDS16(Bt + (long)(n0 + sr)      * K + (kk) + sk, &Bs[bf][(sr)      * 32 + sk]); \
        GLDS16(Bt + (long)(n0 + 64 + sr) * K + (kk) + sk, &Bs[bf][(64 + sr) * 32 + sk]); \
    } while (0)

    STAGE_S(0, kbeg);
    int cur = 0;
    for (int it = 0; it < T; it++) {
        if (it + 1 < T) {
            STAGE_S(cur ^ 1, kbeg + (it + 1) * 32);
            asm volatile("s_waitcnt vmcnt(4)" ::: "memory");
        } else {
            asm volatile("s_waitcnt vmcnt(0)" ::: "memory");
        }
        SCHED_FENCE();
        __builtin_amdgcn_s_barrier();
        SCHED_FENCE();

        bf16x8 afr[4], bfr[4];
        #pragma unroll
        for (int mi = 0; mi < 4; mi++)
            afr[mi] = *reinterpret_cast<const bf16x8*>(&As[cur][(wr * 64 + mi * 16 + lo) * 32 + hi * 8]);
        #pragma unroll
        for (int ni = 0; ni < 4; ni++)
            bfr[ni] = *reinterpret_cast<const bf16x8*>(&Bs[cur][(wc * 64 + ni * 16 + lo) * 32 + hi * 8]);
        #pragma unroll
        for (int mi = 0; mi < 4; mi++)
            #pragma unroll
            for (int ni = 0; ni < 4; ni++)
                acc[mi][ni] = __builtin_amdgcn_mfma_f32_16x16x32_bf16(afr[mi], bfr[ni], acc[mi][ni], 0, 0, 0);

        SCHED_FENCE();
        __builtin_amdgcn_s_barrier();
        SCHED_FENCE();
        cur ^= 1;
    }
    #undef STAGE_S

    const long coff = PARTIAL ? (long)sp * GM * 128 * N : 0;
    #pragma unroll
    for (int mi = 0; mi < 4; mi++)
        #pragma unroll
        for (int ni = 0; ni < 4; ni++) {
            int col = n0 + wc * 64 + ni * 16 + lo;
            if (NBOUND && col >= N) continue;
            float bv = (!PARTIAL && bias) ? bias[col] : 0.f;
            #pragma unroll
            for (int rr = 0; rr < 4; rr++) {
                int row = m0 + wr * 64 + mi * 16 + hi * 4 + rr;
                float v = acc[mi][ni][rr] + bv;
                if (ACT) v = gelu_f(v);
                if (OUTBF16) ((__bf16*)C)[(long)row * N + col] = (__bf16)v;
                else         ((float*)C)[coff + (long)row * N + col] = v;
            }
        }
}

// ---------- 64x64 GEMM (proj): 2-phase pipeline, residual epilogue ----------
template<int OUTBF16, int ACT, int RES>
__global__ __launch_bounds__(256) void gemm_bb(
    const __bf16* __restrict__ A, const __bf16* __restrict__ Bt,
    const float* __restrict__ bias, const float* __restrict__ res,
    void* __restrict__ C, int N, int K)
{
    __shared__ __bf16 As[2][64 * 32];
    __shared__ __bf16 Bs[2][64 * 32];
    const int t = threadIdx.x;
    const int m0 = blockIdx.x * 64;
    const int n0 = blockIdx.y * 64;
    const int w = t >> 6, lane = t & 63;
    const int lo = lane & 15, hi = lane >> 4;
    const int wr = w >> 1, wc = w & 1;

    f32x4 acc[2][2] = {};
    const int sr = t >> 2;
    const int sk = (t & 3) << 3;
    #define STAGE_B(bf, kk) do { \
        GLDS16(A  + (long)(m0 + sr) * K + (kk) + sk, &As[bf][(sr) * 32 + sk]); \
        GLDS16(Bt + (long)(n0 + sr) * K + (kk) + sk, &Bs[bf][(sr) * 32 + sk]); \
    } while (0)

    const int T = K >> 5;
    STAGE_B(0, 0);
    int cur = 0;
    for (int it = 0; it < T; it++) {
        if (it + 1 < T) {
            STAGE_B(cur ^ 1, (it + 1) * 32);
            asm volatile("s_waitcnt vmcnt(2)" ::: "memory");
        } else {
            asm volatile("s_waitcnt vmcnt(0)" ::: "memory");
        }
        SCHED_FENCE();
        __builtin_amdgcn_s_barrier();
        SCHED_FENCE();

        bf16x8 afr[2], bfr[2];
        #pragma unroll
        for (int mi = 0; mi < 2; mi++)
            afr[mi] = *reinterpret_cast<const bf16x8*>(&As[cur][(wr * 32 + mi * 16 + lo) * 32 + hi * 8]);
        #pragma unroll
        for (int ni = 0; ni < 2; ni++)
            bfr[ni] = *reinterpret_cast<const bf16x8*>(&Bs[cur][(wc * 32 + ni * 16 + lo) * 32 + hi * 8]);
        #pragma unroll
        for (int mi = 0; mi < 2; mi++)
            #pragma unroll
            for (int ni = 0; ni < 2; ni++)
                acc[mi][ni] = __builtin_amdgcn_mfma_f32_16x16x32_bf16(afr[mi], bfr[ni], acc[mi][ni], 0, 0, 0);

        SCHED_FENCE();
        __builtin_amdgcn_s_barrier();
        SCHED_FENCE();
        cur ^= 1;
    }
    #undef STAGE_B

    #pragma unroll
    for (int mi = 0; mi < 2; mi++)
        #pragma unroll
        for (int ni = 0; ni < 2; ni++) {
            int col = n0 + wc * 32 + ni * 16 + lo;
            float bv = bias ? bias[col] : 0.f;
            #pragma unroll
            for (int rr = 0; rr < 4; rr++) {
                int row = m0 + wr * 32 + mi * 16 + hi * 4 + rr;
                float v = acc[mi][ni][rr] + bv;
                if (ACT) v = gelu_f(v);
                if (RES) v += res[(long)row * N + col];
                if (OUTBF16) ((__bf16*)C)[(long)row * N + col] = (__bf16)v;
                else         ((float*)C)[(long)row * N + col] = v;
            }
        }
}

// ---------- LM head fallback: A bf16 (glds), Wt[N][K] fp32 reg-staged ----------
__global__ __launch_bounds__(256) void gemm_lm(
    const __bf16* __restrict__ A, const float* __restrict__ Wt,
    float* __restrict__ C, int N, int K)
{
    __shared__ __bf16 As[128 * 32];
    __shared__ __bf16 Bs[128 * 32];
    const int t = threadIdx.x;
    const int m0 = blockIdx.x * 128;
    const int n0 = blockIdx.y * 128;
    const int w = t >> 6, lane = t & 63;
    const int lo = lane & 15, hi = lane >> 4;
    const int wr = w >> 1, wc = w & 1;

    f32x4 acc[4][4] = {};

    for (int k0 = 0; k0 < K; k0 += 32) {
        __syncthreads();
        #pragma unroll
        for (int i = 0; i < 2; i++) {
            int c = i * 256 + t;
            GLDS16(A + (long)(m0 + (c >> 2)) * K + k0 + ((c & 3) << 3), &As[c * 8]);
        }
        #pragma unroll
        for (int i = 0; i < 2; i++) {
            int c = i * 256 + t;
            int nr = n0 + (c >> 2);
            bf16x8 bv;
            if (nr < N) {
                const float* wp = Wt + (long)nr * K + k0 + ((c & 3) << 3);
                float4 b0 = *reinterpret_cast<const float4*>(wp);
                float4 b1 = *reinterpret_cast<const float4*>(wp + 4);
                bv[0] = (__bf16)b0.x; bv[1] = (__bf16)b0.y; bv[2] = (__bf16)b0.z; bv[3] = (__bf16)b0.w;
                bv[4] = (__bf16)b1.x; bv[5] = (__bf16)b1.y; bv[6] = (__bf16)b1.z; bv[7] = (__bf16)b1.w;
            } else {
                #pragma unroll
                for (int qq = 0; qq < 8; qq++) bv[qq] = (__bf16)0.f;
            }
            *reinterpret_cast<bf16x8*>(&Bs[c * 8]) = bv;
        }
        __syncthreads();
        bf16x8 afr[4], bfr[4];
        #pragma unroll
        for (int mi = 0; mi < 4; mi++)
            afr[mi] = *reinterpret_cast<const bf16x8*>(&As[(wr * 64 + mi * 16 + lo) * 32 + hi * 8]);
        #pragma unroll
        for (int ni = 0; ni < 4; ni++)
            bfr[ni] = *reinterpret_cast<const bf16x8*>(&Bs[(wc * 64 + ni * 16 + lo) * 32 + hi * 8]);
        #pragma unroll
        for (int mi = 0; mi < 4; mi++)
            #pragma unroll
            for (int ni = 0; ni < 4; ni++)
                acc[mi][ni] = __builtin_amdgcn_mfma_f32_16x16x32_bf16(afr[mi], bfr[ni], acc[mi][ni], 0, 0, 0);
    }

    #pragma unroll
    for (int mi = 0; mi < 4; mi++)
        #pragma unroll
        for (int ni = 0; ni < 4; ni++) {
            int col = n0 + wc * 64 + ni * 16 + lo;
            if (col < N) {
                #pragma unroll
                for (int rr = 0; rr < 4; rr++) {
                    int row = m0 + wr * 64 + mi * 16 + hi * 4 + rr;
                    C[(long)row * N + col] = acc[mi][ni][rr];
                }
            }
        }
}

// ---------- MFMA flash attention, no-max-tracking + T14 reg-prefetch ----------
__global__ __launch_bounds__(256) void attn_mfma(
    const __bf16* __restrict__ qkv,
    const float* __restrict__ imgk, const float* __restrict__ imgv,
    const float* __restrict__ amask, __bf16* __restrict__ out)
{
    const int qb = blockIdx.x;
    const int h  = blockIdx.y;
    const int b  = blockIdx.z;
    const int t = threadIdx.x, w = t >> 6, lane = t & 63;
    const int lo = lane & 15, hi = lane >> 4;

    __shared__ __bf16 Ks[64][72];
    __shared__ __bf16 Vt[64][72];
    __shared__ __bf16 Ps[4][16][72];
    __shared__ float kimg_s[64];
    __shared__ float amv_s[64];

    const int kr8 = t >> 2, kd8 = (t & 3) * 16;   // K-stage coords
    const int vr8 = t & 63, vd8 = (t >> 6) * 16;  // V-stage coords

    const __bf16* qrow = qkv + (long)(b * 512 + qb * 64 + w * 16 + lo) * 3072 + h * 64;
    bf16x8 qf0 = *reinterpret_cast<const bf16x8*>(qrow + hi * 8);
    bf16x8 qf1 = *reinterpret_cast<const bf16x8*>(qrow + 32 + hi * 8);

    if (t < 64) kimg_s[t] = imgk[b * 1024 + h * 64 + t];
    __syncthreads();

    float simg = 0.f;
    #pragma unroll
    for (int i = 0; i < 8; i++)
        simg += (float)qf0[i] * kimg_s[hi * 8 + i] + (float)qf1[i] * kimg_s[32 + hi * 8 + i];
    simg += __shfl_xor(simg, 16);
    simg += __shfl_xor(simg, 32);
    simg *= 0.125f;

    float pimg[4], l_part[4];
    f32x4 o_acc[4];
    #pragma unroll
    for (int rr = 0; rr < 4; rr++) {
        pimg[rr] = __expf(__shfl(simg, hi * 4 + rr));
        l_part[rr] = 0.f;
    }
    #pragma unroll
    for (int df = 0; df < 4; df++) {
        float vi = imgv[b * 1024 + h * 64 + df * 16 + lo];
        #pragma unroll
        for (int rr = 0; rr < 4; rr++) o_acc[df][rr] = pimg[rr] * vi;
    }

    // prefetch tile 0 into regs
    bf16x8 ck0, ck1, cv0, cv1;
    {
        const __bf16* ks = qkv + (long)(b * 512 + kr8) * 3072 + 1024 + h * 64 + kd8;
        ck0 = *reinterpret_cast<const bf16x8*>(ks);
        ck1 = *reinterpret_cast<const bf16x8*>(ks + 8);
        const __bf16* vs = qkv + (long)(b * 512 + vr8) * 3072 + 2048 + h * 64 + vd8;
        cv0 = *reinterpret_cast<const bf16x8*>(vs);
        cv1 = *reinterpret_cast<const bf16x8*>(vs + 8);
    }

    for (int kb = 0; kb <= qb; kb++) {
        // issue next tile's loads early (T14: latency hides under this tile's compute)
        bf16x8 nk0, nk1, nv0, nv1;
        const bool more = (kb < qb);
        if (more) {
            const __bf16* ks = qkv + (long)(b * 512 + (kb + 1) * 64 + kr8) * 3072 + 1024 + h * 64 + kd8;
            nk0 = *reinterpret_cast<const bf16x8*>(ks);
            nk1 = *reinterpret_cast<const bf16x8*>(ks + 8);
            const __bf16* vs = qkv + (long)(b * 512 + (kb + 1) * 64 + vr8) * 3072 + 2048 + h * 64 + vd8;
            nv0 = *reinterpret_cast<const bf16x8*>(vs);
            nv1 = *reinterpret_cast<const bf16x8*>(vs + 8);
        }
        __syncthreads();   // prior iter done reading Ks/Vt
        *reinterpret_cast<bf16x8*>(&Ks[kr8][kd8])     = ck0;
        *reinterpret_cast<bf16x8*>(&Ks[kr8][kd8 + 8]) = ck1;
        #pragma unroll
        for (int i = 0; i < 8; i++) { Vt[vd8 + i][vr8] = cv0[i]; Vt[vd8 + 8 + i][vr8] = cv1[i]; }
        if (t < 64) amv_s[t] = (1.0f - amask[b * 512 + kb * 64 + t]) * -10000.0f;
        __syncthreads();

        f32x4 sf[4];
        #pragma unroll
        for (int js = 0; js < 4; js++) {
            bf16x8 kf0 = *reinterpret_cast<const bf16x8*>(&Ks[js * 16 + lo][hi * 8]);
            bf16x8 kf1 = *reinterpret_cast<const bf16x8*>(&Ks[js * 16 + lo][32 + hi * 8]);
            f32x4 a = {};
            a = __builtin_amdgcn_mfma_f32_16x16x32_bf16(qf0, kf0, a, 0, 0, 0);
            a = __builtin_amdgcn_mfma_f32_16x16x32_bf16(qf1, kf1, a, 0, 0, 0);
            sf[js] = a;
        }
        #pragma unroll
        for (int js = 0; js < 4; js++) {
            float amv = amv_s[js * 16 + lo];
            #pragma unroll
            for (int rr = 0; rr < 4; rr++) {
                float sv = sf[js][rr] * 0.125f + amv;
                if (kb == qb) {
                    int qrw = w * 16 + hi * 4 + rr;
                    if (js * 16 + lo > qrw) sv = -10000.0f + amv;
                }
                float p = __expf(sv);
                l_part[rr] += p;
                Ps[w][hi * 4 + rr][js * 16 + lo] = (__bf16)p;
            }
        }
        #pragma unroll
        for (int jb = 0; jb < 2; jb++) {
            bf16x8 pf = *reinterpret_cast<const bf16x8*>(&Ps[w][lo][jb * 32 + hi * 8]);
            #pragma unroll
            for (int df = 0; df < 4; df++) {
                bf16x8 vf = *reinterpret_cast<const bf16x8*>(&Vt[df * 16 + lo][jb * 32 + hi * 8]);
                o_acc[df] = __builtin_amdgcn_mfma_f32_16x16x32_bf16(pf, vf, o_acc[df], 0, 0, 0);
            }
        }
        if (more) { ck0 = nk0; ck1 = nk1; cv0 = nv0; cv1 = nv1; }
    }

    float linv[4];
    #pragma unroll
    for (int rr = 0; rr < 4; rr++) {
        float ls = l_part[rr];
        #pragma unroll
        for (int off = 1; off < 16; off <<= 1) ls += __shfl_xor(ls, off);
        linv[rr] = 1.0f / (pimg[rr] + ls);
    }
    #pragma unroll
    for (int df = 0; df < 4; df++)
        #pragma unroll
        for (int rr = 0; rr < 4; rr++) {
            long row = b * 512 + qb * 64 + w * 16 + hi * 4 + rr;
            out[row * 1024 + h * 64 + df * 16 + lo] = (__bf16)(o_acc[df][rr] * linv[rr]);
        }
}

// ---------- host orchestration ----------
extern "C" void kernel_launch(void* const* d_in, const int* in_sizes, int n_in,
                              void* d_out, int out_size, void* d_ws, size_t ws_size,
                              hipStream_t stream) {
    (void)in_sizes; (void)n_in; (void)out_size;
    const int*   ids   = (const int*)d_in[0];
    const float* amask = (const float*)d_in[1];
    const float* ihs   = (const float*)d_in[2];
    const float* wte   = (const float*)d_in[3];
    const float* ftW1  = (const float*)d_in[4];
    const float* ftb1  = (const float*)d_in[5];
    const float* ftW2  = (const float*)d_in[6];
    const float* ftb2  = (const float*)d_in[7];
    const float* ln1g  = (const float*)d_in[8];
    const float* ln1b  = (const float*)d_in[9];
    const float* Wattn = (const float*)d_in[10];
    const float* battn = (const float*)d_in[11];
    const float* Wuk   = (const float*)d_in[12];
    const float* buk   = (const float*)d_in[13];
    const float* Wuv   = (const float*)d_in[14];
    const float* buv   = (const float*)d_in[15];
    const float* Wproj = (const float*)d_in[16];
    const float* bproj = (const float*)d_in[17];
    const float* ln2g  = (const float*)d_in[18];
    const float* ln2b  = (const float*)d_in[19];
    const float* Wfc   = (const float*)d_in[20];
    const float* bfc   = (const float*)d_in[21];
    const float* Wfc2  = (const float*)d_in[22];
    const float* bfc2  = (const float*)d_in[23];
    const float* lnfg  = (const float*)d_in[24];
    const float* lnfb  = (const float*)d_in[25];
    float* out = (float*)d_out;

    const long VP = 50304;
    char* base = (char*)d_ws;
    float* ftmp  = (float*)(base);
    float* img   = (float*)(base + (1 << 13));
    float* imgk  = (float*)(base + (1 << 14));
    float* imgv  = (float*)(base + 114688);
    float* part  = (float*)(base + 212992);
    float* h     = (float*)(base + 1048576);
    char* p = base + 5 * 1048576;
    __bf16* xb    = (__bf16*)p; p += 2 * 1048576;
    __bf16* qkvb  = (__bf16*)p; p += 6 * 1048576;
    __bf16* attob = (__bf16*)p; p += 2 * 1048576;
    __bf16* ffb   = (__bf16*)p; p += 8 * 1048576;
    __bf16* wtA   = (__bf16*)p; p += 6 * 1048576;
    __bf16* wtP   = (__bf16*)p; p += 2 * 1048576;
    __bf16* wtF   = (__bf16*)p; p += 8 * 1048576;
    __bf16* wtF2  = (__bf16*)p; p += 8 * 1048576;
    __bf16* wteb  = (__bf16*)p;
    size_t need1 = (size_t)(p - base) + (size_t)VP * 1024 * 2;
    float* part_fc2 = (float*)(base + need1);
    size_t need2 = need1 + 4 * 1048576 * sizeof(float);
    const bool big_ws  = (ws_size >= need1);
    const bool big_ws2 = (ws_size >= need2);

    dim3 b256(256);

    gemv_part<<<dim3(16, 8, 1), b256, 0, stream>>>(ihs, 1024, ftW1, 0, part, 1024, 1024);
    gemv_reduce<<<dim3(8), b256, 0, stream>>>(part, ftb1, 0, ftmp, 1024, 1, 1);
    gemv_part<<<dim3(16, 8, 1), b256, 0, stream>>>(ftmp, 1024, ftW2, 0, part, 1024, 1024);
    gemv_reduce<<<dim3(8), b256, 0, stream>>>(part, ftb2, 0, img, 1024, 1, 0);
    gemv_part<<<dim3(16, 8, 12), b256, 0, stream>>>(img, 1024, Wuk, 1024L * 1024, part, 1024, 1024);
    gemv_reduce<<<dim3(96), b256, 0, stream>>>(part, buk, 1024, imgk, 1024, 12, 0);
    gemv_part<<<dim3(16, 8, 12), b256, 0, stream>>>(img, 1024, Wuv, 1024L * 1024, part, 1024, 1024);
    gemv_reduce<<<dim3(96), b256, 0, stream>>>(part, buv, 1024, imgv, 1024, 12, 0);

    embed_k<<<dim3(1024), b256, 0, stream>>>(ids, wte, h);
    ln_k<<<dim3(1024), b256, 0, stream>>>(h, xb, ln1g, ln1b);   // ln1 of layer 0

    for (int l = 0; l < 12; l++) {
        tcvt_layer<<<dim3(12288), b256, 0, stream>>>(
            Wattn + (long)l * 1024 * 3072, Wproj + (long)l * 1024 * 1024,
            Wfc + (long)l * 1024 * 4096, Wfc2 + (long)l * 4096 * 1024,
            wtA, wtP, wtF, wtF2);

        gemm_s<1, 0, 0, 0><<<dim3(192), b256, 0, stream>>>(
            xb, wtA, battn + l * 3072, qkvb, 3072, 1024, 8, 24, 1);
        attn_mfma<<<dim3(8, 16, 2), b256, 0, stream>>>(
            qkvb, imgk + l * 2048, imgv + l * 2048, amask, attob);
        gemm_bb<0, 0, 1><<<dim3(16, 16), b256, 0, stream>>>(
            attob, wtP, bproj + l * 1024, h, h, 1024, 1024);
        ln_k<<<dim3(1024), b256, 0, stream>>>(h, xb, ln2g + l * 1024, ln2b + l * 1024);
        gemm_s<1, 1, 0, 0><<<dim3(256), b256, 0, stream>>>(
            xb, wtF, bfc + l * 4096, ffb, 4096, 1024, 8, 32, 1);

        const float* ng = (l < 11) ? (ln1g + (l + 1) * 1024) : lnfg;
        const float* nb = (l < 11) ? (ln1b + (l + 1) * 1024) : lnfb;
        if (big_ws2) {
            gemm_s<0, 0, 0, 1><<<dim3(256), b256, 0, stream>>>(
                ffb, wtF2, nullptr, part_fc2, 1024, 4096, 8, 8, 4);
            lnadd_k<<<dim3(1024), b256, 0, stream>>>(h, part_fc2, bfc2 + l * 1024, ng, nb, xb);
        } else {
            gemm_bb<0, 0, 1><<<dim3(16, 16), b256, 0, stream>>>(
                ffb, wtF2, bfc2 + l * 1024, h, h, 1024, 4096);
            ln_k<<<dim3(1024), b256, 0, stream>>>(h, xb, ng, nb);
        }
    }

    // xb now holds lnf(h); convert wte late so it's L3-warm for the LM head
    if (big_ws) {
        wcvt<<<dim3((unsigned)(VP * 1024 / 2048)), b256, 0, stream>>>(wte, wteb, 50257L * 1024);
        gemm_s<0, 0, 1, 0><<<dim3(3144), b256, 0, stream>>>(
            xb, wteb, nullptr, out, 50257, 1024, 8, 393, 1);
    } else {
        gemm_lm<<<dim3(8, 393), b256, 0, stream>>>(xb, wte, out, 50257, 1024);
    }
}

// Round 6
// 1593.040 us; speedup vs baseline: 3.5016x; 1.2136x over previous
//
#include <hip/hip_runtime.h>
#include <cstdint>

// B=2, S=512, D=1024, H=16, HD=64, L=12, V=50257, DFF=4096

typedef __bf16 bf16x8 __attribute__((ext_vector_type(8)));
typedef __bf16 bf16x4 __attribute__((ext_vector_type(4)));
typedef float  f32x4  __attribute__((ext_vector_type(4)));

#define GLDS16(g, l) __builtin_amdgcn_global_load_lds( \
    (const __attribute__((address_space(1))) unsigned int*)(g), \
    (__attribute__((address_space(3))) unsigned int*)(l), 16, 0, 0)

#define SCHED_FENCE() __builtin_amdgcn_sched_barrier(0)

__device__ __forceinline__ float gelu_f(float x) {
    float u = 1.5957691216057308f * (x + 0.044715f * x * x * x);
    float e = __expf(u);
    float t = 1.0f - 2.0f / (e + 1.0f);
    return 0.5f * x * (1.0f + t);
}

// swizzled fragment offset in a [rows][64] bf16 LDS tile:
// elem = row*64 + ((kh*32 + hi*8) ^ ((row&7)<<3))   [T2 XOR, matches stage perm]
__device__ __forceinline__ int fragoff(int row, int kh, int hi) {
    return row * 64 + ((kh * 32 + hi * 8) ^ ((row & 7) << 3));
}

// ---------- per-layer weight transpose+convert ----------
__global__ __launch_bounds__(256) void tcvt_layer(
    const float* __restrict__ Wa, const float* __restrict__ Wp,
    const float* __restrict__ Wf, const float* __restrict__ Wf2,
    __bf16* __restrict__ oa, __bf16* __restrict__ op,
    __bf16* __restrict__ of, __bf16* __restrict__ of2)
{
    int id = blockIdx.x;
    const float* src; __bf16* dst; int K, N, kb, nb;
    if (id < 3072)      { src = Wa;  dst = oa;  K = 1024; N = 3072; kb = id & 31;  nb = id >> 5; }
    else if (id < 4096) { id -= 3072; src = Wp;  dst = op;  K = 1024; N = 1024; kb = id & 31;  nb = id >> 5; }
    else if (id < 8192) { id -= 4096; src = Wf;  dst = of;  K = 1024; N = 4096; kb = id & 31;  nb = id >> 5; }
    else                { id -= 8192; src = Wf2; dst = of2; K = 4096; N = 1024; kb = id & 127; nb = id >> 7; }
    const int k0 = kb * 32, n0 = nb * 32;
    __shared__ float tile[32][33];
    const int t = threadIdx.x;
    const int r = t >> 3, c4 = (t & 7) * 4;
    float4 v = *reinterpret_cast<const float4*>(src + (long)(k0 + r) * N + n0 + c4);
    tile[r][c4] = v.x; tile[r][c4 + 1] = v.y; tile[r][c4 + 2] = v.z; tile[r][c4 + 3] = v.w;
    __syncthreads();
    bf16x4 o;
    o[0] = (__bf16)tile[c4][r];
    o[1] = (__bf16)tile[c4 + 1][r];
    o[2] = (__bf16)tile[c4 + 2][r];
    o[3] = (__bf16)tile[c4 + 3][r];
    *reinterpret_cast<bf16x4*>(dst + (long)(n0 + r) * K + k0 + c4) = o;
}

// ---------- wte fp32 -> bf16 (zero-pads rows >= V) ----------
__global__ __launch_bounds__(256) void wcvt(
    const float* __restrict__ wte, __bf16* __restrict__ out, long nvalid)
{
    long e = ((long)blockIdx.x * 256 + threadIdx.x) * 8;
    bf16x8 o;
    if (e < nvalid) {
        float4 a = *reinterpret_cast<const float4*>(wte + e);
        float4 b = *reinterpret_cast<const float4*>(wte + e + 4);
        o[0] = (__bf16)a.x; o[1] = (__bf16)a.y; o[2] = (__bf16)a.z; o[3] = (__bf16)a.w;
        o[4] = (__bf16)b.x; o[5] = (__bf16)b.y; o[6] = (__bf16)b.z; o[7] = (__bf16)b.w;
    } else {
        #pragma unroll
        for (int i = 0; i < 8; i++) o[i] = (__bf16)0.f;
    }
    *reinterpret_cast<bf16x8*>(out + e) = o;
}

// ---------- small GEMV path (img feature transform), ksplit-8 ----------
__global__ __launch_bounds__(256) void gemv_part(
    const float* __restrict__ x, int xld,
    const float* __restrict__ W, long wzs,
    float* __restrict__ part, int K, int N)
{
    int jb = blockIdx.x, kz = blockIdx.y, z = blockIdx.z;
    int t = threadIdx.x;
    int j = (jb << 6) + (t & 63);
    int g = t >> 6;
    int klen = K / (gridDim.y * 4);
    int kbase = (kz * 4 + g) * klen;
    const float* Wp = W + (long)z * wzs + (long)kbase * N + j;
    const float* x0 = x + kbase;
    const float* x1 = x + xld + kbase;
    float a0 = 0.f, a1 = 0.f;
    for (int k = 0; k < klen; k++) {
        float wv = Wp[(long)k * N];
        a0 += x0[k] * wv;
        a1 += x1[k] * wv;
    }
    __shared__ float r0[4][64], r1[4][64];
    r0[g][t & 63] = a0; r1[g][t & 63] = a1;
    __syncthreads();
    if (t < 64) {
        a0 = r0[0][t] + r0[1][t] + r0[2][t] + r0[3][t];
        a1 = r1[0][t] + r1[1][t] + r1[2][t] + r1[3][t];
        long base = (long)(z * gridDim.y + kz) * 2 * N + (jb << 6) + t;
        part[base]     = a0;
        part[base + N] = a1;
    }
}

__global__ __launch_bounds__(256) void gemv_reduce(
    const float* __restrict__ part, const float* __restrict__ bias, long bzs,
    float* __restrict__ out, int N, int nz, int act)
{
    int idx = blockIdx.x * 256 + threadIdx.x;
    if (idx >= nz * 2 * N) return;
    int j  = idx % N;
    int bz = idx / N;
    int z  = bz >> 1;
    float s = bias[(long)z * bzs + j];
    const float* p = part + ((long)z * 8 * 2 + (bz & 1)) * N + j;
    #pragma unroll
    for (int kz = 0; kz < 8; kz++) s += p[(long)kz * 2 * N];
    if (act) s = fmaxf(s, 0.f);
    out[idx] = s;
}

// ---------- batched img K/V projections: z<12 -> Wuk[z], else Wuv[z-12]; ksplit-4 ----------
__global__ __launch_bounds__(256) void gemv_kv_part(
    const float* __restrict__ img,
    const float* __restrict__ Wuk, const float* __restrict__ Wuv,
    float* __restrict__ part)
{
    int jb = blockIdx.x, kz = blockIdx.y, z = blockIdx.z;
    int t = threadIdx.x;
    int j = (jb << 6) + (t & 63);
    int g = t >> 6;
    int kbase = (kz * 4 + g) * 64;
    const float* W = (z < 12) ? (Wuk + (long)z * 1048576) : (Wuv + (long)(z - 12) * 1048576);
    const float* Wp = W + (long)kbase * 1024 + j;
    const float* x0 = img + kbase;
    const float* x1 = img + 1024 + kbase;
    float a0 = 0.f, a1 = 0.f;
    for (int k = 0; k < 64; k++) {
        float wv = Wp[(long)k * 1024];
        a0 += x0[k] * wv;
        a1 += x1[k] * wv;
    }
    __shared__ float r0[4][64], r1[4][64];
    r0[g][t & 63] = a0; r1[g][t & 63] = a1;
    __syncthreads();
    if (t < 64) {
        a0 = r0[0][t] + r0[1][t] + r0[2][t] + r0[3][t];
        a1 = r1[0][t] + r1[1][t] + r1[2][t] + r1[3][t];
        long base = (long)(z * 4 + kz) * 2 * 1024 + (jb << 6) + t;
        part[base]        = a0;
        part[base + 1024] = a1;
    }
}

__global__ __launch_bounds__(256) void gemv_kv_reduce(
    const float* __restrict__ part,
    const float* __restrict__ buk, const float* __restrict__ buv,
    float* __restrict__ imgk, float* __restrict__ imgv)
{
    int idx = blockIdx.x * 256 + threadIdx.x;   // over 24*2*1024
    int z = idx >> 11;
    int bsel = (idx >> 10) & 1;
    int j = idx & 1023;
    float s = (z < 12) ? buk[z * 1024 + j] : buv[(z - 12) * 1024 + j];
    const float* p = part + ((long)z * 4 * 2 + bsel) * 1024 + j;
    #pragma unroll
    for (int kz = 0; kz < 4; kz++) s += p[(long)kz * 2 * 1024];
    if (z < 12) imgk[z * 2048 + bsel * 1024 + j] = s;
    else        imgv[(z - 12) * 2048 + bsel * 1024 + j] = s;
}

// ---------- fused embedding + LN (layer-0 ln1) ----------
__global__ __launch_bounds__(256) void embed_ln(
    const int* __restrict__ ids, const float* __restrict__ wte,
    float* __restrict__ h, __bf16* __restrict__ xb,
    const float* __restrict__ g, const float* __restrict__ b)
{
    int row = blockIdx.x;
    int s = row & 511;
    int t = threadIdx.x;
    long id = ids[row];
    float4 v1 = reinterpret_cast<const float4*>(wte + id * 1024)[t];
    float4 v2 = reinterpret_cast<const float4*>(wte + (long)s * 1024)[t];
    float4 v; v.x = v1.x + v2.x; v.y = v1.y + v2.y; v.z = v1.z + v2.z; v.w = v1.w + v2.w;
    reinterpret_cast<float4*>(h + (long)row * 1024)[t] = v;

    float s1 = v.x + v.y + v.z + v.w;
    float s2 = v.x * v.x + v.y * v.y + v.z * v.z + v.w * v.w;
    #pragma unroll
    for (int o = 32; o >= 1; o >>= 1) { s1 += __shfl_xor(s1, o); s2 += __shfl_xor(s2, o); }
    __shared__ float r1[4], r2[4];
    int w = t >> 6;
    if ((t & 63) == 0) { r1[w] = s1; r2[w] = s2; }
    __syncthreads();
    s1 = r1[0] + r1[1] + r1[2] + r1[3];
    s2 = r2[0] + r2[1] + r2[2] + r2[3];
    float mean = s1 * (1.0f / 1024.0f);
    float var  = s2 * (1.0f / 1024.0f) - mean * mean;
    float rstd = rsqrtf(var + 1e-5f);
    float4 gg = reinterpret_cast<const float4*>(g)[t];
    float4 bb = reinterpret_cast<const float4*>(b)[t];
    bf16x4 o;
    o[0] = (__bf16)((v.x - mean) * rstd * gg.x + bb.x);
    o[1] = (__bf16)((v.y - mean) * rstd * gg.y + bb.y);
    o[2] = (__bf16)((v.z - mean) * rstd * gg.z + bb.z);
    o[3] = (__bf16)((v.w - mean) * rstd * gg.w + bb.w);
    *reinterpret_cast<bf16x4*>(xb + (long)row * 1024 + t * 4) = o;
}

// ---------- LayerNorm (fallback path only) ----------
__global__ __launch_bounds__(256) void ln_k(
    const float* __restrict__ in, __bf16* __restrict__ out,
    const float* __restrict__ g, const float* __restrict__ b)
{
    int row = blockIdx.x, t = threadIdx.x;
    float4 v = reinterpret_cast<const float4*>(in + (long)row * 1024)[t];
    float s1 = v.x + v.y + v.z + v.w;
    float s2 = v.x * v.x + v.y * v.y + v.z * v.z + v.w * v.w;
    #pragma unroll
    for (int o = 32; o >= 1; o >>= 1) { s1 += __shfl_xor(s1, o); s2 += __shfl_xor(s2, o); }
    __shared__ float r1[4], r2[4];
    int w = t >> 6;
    if ((t & 63) == 0) { r1[w] = s1; r2[w] = s2; }
    __syncthreads();
    s1 = r1[0] + r1[1] + r1[2] + r1[3];
    s2 = r2[0] + r2[1] + r2[2] + r2[3];
    float mean = s1 * (1.0f / 1024.0f);
    float var  = s2 * (1.0f / 1024.0f) - mean * mean;
    float rstd = rsqrtf(var + 1e-5f);
    float4 gg = reinterpret_cast<const float4*>(g)[t];
    float4 bb = reinterpret_cast<const float4*>(b)[t];
    bf16x4 o;
    o[0] = (__bf16)((v.x - mean) * rstd * gg.x + bb.x);
    o[1] = (__bf16)((v.y - mean) * rstd * gg.y + bb.y);
    o[2] = (__bf16)((v.z - mean) * rstd * gg.z + bb.z);
    o[3] = (__bf16)((v.w - mean) * rstd * gg.w + bb.w);
    *reinterpret_cast<bf16x4*>(out + (long)row * 1024 + t * 4) = o;
}

// ---------- fused: h += bias + sum(NP parts); out = LN(h) ----------
template<int NP>
__global__ __launch_bounds__(256) void lnadd_k(
    float* __restrict__ h, const float* __restrict__ part,
    const float* __restrict__ bias,
    const float* __restrict__ g, const float* __restrict__ b,
    __bf16* __restrict__ out)
{
    int row = blockIdx.x, t = threadIdx.x;
    long off = (long)row * 1024 + t * 4;
    float4 v = *reinterpret_cast<const float4*>(h + off);
    #pragma unroll
    for (int sp = 0; sp < NP; sp++) {
        float4 pv = *reinterpret_cast<const float4*>(part + sp * 1048576L + off);
        v.x += pv.x; v.y += pv.y; v.z += pv.z; v.w += pv.w;
    }
    float4 bi = reinterpret_cast<const float4*>(bias)[t];
    v.x += bi.x; v.y += bi.y; v.z += bi.z; v.w += bi.w;
    *reinterpret_cast<float4*>(h + off) = v;

    float s1 = v.x + v.y + v.z + v.w;
    float s2 = v.x * v.x + v.y * v.y + v.z * v.z + v.w * v.w;
    #pragma unroll
    for (int o = 32; o >= 1; o >>= 1) { s1 += __shfl_xor(s1, o); s2 += __shfl_xor(s2, o); }
    __shared__ float r1[4], r2[4];
    int w = t >> 6;
    if ((t & 63) == 0) { r1[w] = s1; r2[w] = s2; }
    __syncthreads();
    s1 = r1[0] + r1[1] + r1[2] + r1[3];
    s2 = r2[0] + r2[1] + r2[2] + r2[3];
    float mean = s1 * (1.0f / 1024.0f);
    float var  = s2 * (1.0f / 1024.0f) - mean * mean;
    float rstd = rsqrtf(var + 1e-5f);
    float4 gg = reinterpret_cast<const float4*>(g)[t];
    float4 bb = reinterpret_cast<const float4*>(b)[t];
    bf16x4 o;
    o[0] = (__bf16)((v.x - mean) * rstd * gg.x + bb.x);
    o[1] = (__bf16)((v.y - mean) * rstd * gg.y + bb.y);
    o[2] = (__bf16)((v.z - mean) * rstd * gg.z + bb.z);
    o[3] = (__bf16)((v.w - mean) * rstd * gg.w + bb.w);
    *reinterpret_cast<bf16x4*>(out + off) = o;
}

// ---------- 128x128 GEMM, BK=64, T2-swizzled LDS, counted-vmcnt 2-phase ----------
// A[M][K] bf16, Bt[rows][K] bf16 (rows padded >= n-extent). XCD-swizzled 1D grid.
template<int OUTBF16, int ACT, int NBOUND, int PARTIAL>
__global__ __launch_bounds__(256) void gemm128(
    const __bf16* __restrict__ A, const __bf16* __restrict__ Bt,
    const float* __restrict__ bias, void* __restrict__ C,
    int N, int K, int GM, int GN, int NS)
{
    const int total = GM * GN * NS;
    const int q = total >> 3, r = total & 7;
    const int x = blockIdx.x & 7, jj = blockIdx.x >> 3;
    const int w0 = (x < r) ? x * (q + 1) + jj : r * (q + 1) + (x - r) * q + jj;
    const int sp = w0 / (GM * GN);
    const int rem = w0 - sp * (GM * GN);
    const int m0 = (rem % GM) * 128;
    const int n0 = (rem / GM) * 128;

    __shared__ __bf16 As[2][128 * 64];
    __shared__ __bf16 Bs[2][128 * 64];
    const int t = threadIdx.x;
    const int wv = t >> 6, lane = t & 63;
    const int lo = lane & 15, hi = lane >> 4;
    const int wr = wv >> 1, wc = wv & 1;

    f32x4 acc[4][4] = {};

    // stage geometry: load i -> row = i*32 + (t>>3); global k pre-permuted by row&7
    const int srow = t >> 3;
    const int skx  = (((t & 7) ^ (srow & 7)) << 3);
    const int sldst = t * 8;   // elem offset within a 32-row stripe (4096 B = 2048 elems)
    #define ST128(bf, kk) do { \
        _Pragma("unroll") \
        for (int i = 0; i < 4; i++) \
            GLDS16(A + (long)(m0 + i * 32 + srow) * K + (kk) + skx, &As[bf][i * 2048 + sldst]); \
        _Pragma("unroll") \
        for (int i = 0; i < 4; i++) \
            GLDS16(Bt + (long)(n0 + i * 32 + srow) * K + (kk) + skx, &Bs[bf][i * 2048 + sldst]); \
    } while (0)

    const int Ksp = K / NS;
    const int kbeg = sp * Ksp;
    const int T = Ksp >> 6;

    ST128(0, kbeg);
    int cur = 0;
    for (int it = 0; it < T; it++) {
        if (it + 1 < T) {
            ST128(cur ^ 1, kbeg + (it + 1) * 64);
            asm volatile("s_waitcnt vmcnt(8)" ::: "memory");
        } else {
            asm volatile("s_waitcnt vmcnt(0)" ::: "memory");
        }
        SCHED_FENCE();
        __builtin_amdgcn_s_barrier();
        SCHED_FENCE();

        #pragma unroll
        for (int kh = 0; kh < 2; kh++) {
            bf16x8 afr[4], bfr[4];
            #pragma unroll
            for (int mi = 0; mi < 4; mi++)
                afr[mi] = *reinterpret_cast<const bf16x8*>(&As[cur][fragoff(wr * 64 + mi * 16 + lo, kh, hi)]);
            #pragma unroll
            for (int ni = 0; ni < 4; ni++)
                bfr[ni] = *reinterpret_cast<const bf16x8*>(&Bs[cur][fragoff(wc * 64 + ni * 16 + lo, kh, hi)]);
            #pragma unroll
            for (int mi = 0; mi < 4; mi++)
                #pragma unroll
                for (int ni = 0; ni < 4; ni++)
                    acc[mi][ni] = __builtin_amdgcn_mfma_f32_16x16x32_bf16(afr[mi], bfr[ni], acc[mi][ni], 0, 0, 0);
        }

        SCHED_FENCE();
        __builtin_amdgcn_s_barrier();
        SCHED_FENCE();
        cur ^= 1;
    }
    #undef ST128

    const long coff = PARTIAL ? (long)sp * GM * 128 * N : 0;
    #pragma unroll
    for (int mi = 0; mi < 4; mi++)
        #pragma unroll
        for (int ni = 0; ni < 4; ni++) {
            int col = n0 + wc * 64 + ni * 16 + lo;
            if (NBOUND && col >= N) continue;
            float bv = (!PARTIAL && bias) ? bias[col] : 0.f;
            #pragma unroll
            for (int rr = 0; rr < 4; rr++) {
                int row = m0 + wr * 64 + mi * 16 + hi * 4 + rr;
                float v = acc[mi][ni][rr] + bv;
                if (ACT) v = gelu_f(v);
                if (OUTBF16) ((__bf16*)C)[(long)row * N + col] = (__bf16)v;
                else         ((float*)C)[coff + (long)row * N + col] = v;
            }
        }
}

// ---------- 64xBN GEMM, BK=64, swizzled, counted-vmcnt 2-phase ----------
template<int BN, int OUTBF16, int ACT, int PARTIAL>
__global__ __launch_bounds__(256) void gemm64(
    const __bf16* __restrict__ A, const __bf16* __restrict__ Bt,
    const float* __restrict__ bias, void* __restrict__ C,
    int N, int K, int GM, int GN, int NS)
{
    constexpr int NB = BN / 32;           // B loads per thread
    const int total = GM * GN * NS;
    const int q = total >> 3, r = total & 7;
    const int x = blockIdx.x & 7, jj = blockIdx.x >> 3;
    const int w0 = (x < r) ? x * (q + 1) + jj : r * (q + 1) + (x - r) * q + jj;
    const int sp = w0 / (GM * GN);
    const int rem = w0 - sp * (GM * GN);
    const int m0 = (rem % GM) * 64;
    const int n0 = (rem / GM) * BN;

    __shared__ __bf16 As[2][64 * 64];
    __shared__ __bf16 Bs[2][BN * 64];
    const int t = threadIdx.x;
    const int wv = t >> 6, lane = t & 63;
    const int lo = lane & 15, hi = lane >> 4;
    const int wr = wv >> 1, wc = wv & 1;

    f32x4 acc[2][NB] = {};

    const int srow = t >> 3;
    const int skx  = (((t & 7) ^ (srow & 7)) << 3);
    const int sldst = t * 8;
    #define ST64(bf, kk) do { \
        _Pragma("unroll") \
        for (int i = 0; i < 2; i++) \
            GLDS16(A + (long)(m0 + i * 32 + srow) * K + (kk) + skx, &As[bf][i * 2048 + sldst]); \
        _Pragma("unroll") \
        for (int i = 0; i < NB; i++) \
            GLDS16(Bt + (long)(n0 + i * 32 + srow) * K + (kk) + skx, &Bs[bf][i * 2048 + sldst]); \
    } while (0)

    const int Ksp = K / NS;
    const int kbeg = sp * Ksp;
    const int T = Ksp >> 6;

    ST64(0, kbeg);
    int cur = 0;
    for (int it = 0; it < T; it++) {
        if (it + 1 < T) {
            ST64(cur ^ 1, kbeg + (it + 1) * 64);
            if constexpr (NB == 4) asm volatile("s_waitcnt vmcnt(6)" ::: "memory");
            else                   asm volatile("s_waitcnt vmcnt(4)" ::: "memory");
        } else {
            asm volatile("s_waitcnt vmcnt(0)" ::: "memory");
        }
        SCHED_FENCE();
        __builtin_amdgcn_s_barrier();
        SCHED_FENCE();

        #pragma unroll
        for (int kh = 0; kh < 2; kh++) {
            bf16x8 afr[2], bfr[NB];
            #pragma unroll
            for (int mi = 0; mi < 2; mi++)
                afr[mi] = *reinterpret_cast<const bf16x8*>(&As[cur][fragoff(wr * 32 + mi * 16 + lo, kh, hi)]);
            #pragma unroll
            for (int ni = 0; ni < NB; ni++)
                bfr[ni] = *reinterpret_cast<const bf16x8*>(&Bs[cur][fragoff(wc * (BN / 2) + ni * 16 + lo, kh, hi)]);
            #pragma unroll
            for (int mi = 0; mi < 2; mi++)
                #pragma unroll
                for (int ni = 0; ni < NB; ni++)
                    acc[mi][ni] = __builtin_amdgcn_mfma_f32_16x16x32_bf16(afr[mi], bfr[ni], acc[mi][ni], 0, 0, 0);
        }

        SCHED_FENCE();
        __builtin_amdgcn_s_barrier();
        SCHED_FENCE();
        cur ^= 1;
    }
    #undef ST64

    const long coff = PARTIAL ? (long)sp * GM * 64 * N : 0;
    #pragma unroll
    for (int mi = 0; mi < 2; mi++)
        #pragma unroll
        for (int ni = 0; ni < NB; ni++) {
            int col = n0 + wc * (BN / 2) + ni * 16 + lo;
            float bv = (!PARTIAL && bias) ? bias[col] : 0.f;
            #pragma unroll
            for (int rr = 0; rr < 4; rr++) {
                int row = m0 + wr * 32 + mi * 16 + hi * 4 + rr;
                float v = acc[mi][ni][rr] + bv;
                if (ACT) v = gelu_f(v);
                if (OUTBF16) ((__bf16*)C)[(long)row * N + col] = (__bf16)v;
                else         ((float*)C)[coff + (long)row * N + col] = v;
            }
        }
}

// ---------- fallback 64x64 GEMM (BK=32, old style) ----------
template<int OUTBF16, int ACT, int RES>
__global__ __launch_bounds__(256) void gemm_bb(
    const __bf16* __restrict__ A, const __bf16* __restrict__ Bt,
    const float* __restrict__ bias, const float* __restrict__ res,
    void* __restrict__ C, int N, int K)
{
    __shared__ __bf16 As[64 * 32];
    __shared__ __bf16 Bs[64 * 32];
    const int t = threadIdx.x;
    const int m0 = blockIdx.x * 64;
    const int n0 = blockIdx.y * 64;
    const int w = t >> 6, lane = t & 63;
    const int lo = lane & 15, hi = lane >> 4;
    const int wr = w >> 1, wc = w & 1;

    f32x4 acc[2][2] = {};

    for (int k0 = 0; k0 < K; k0 += 32) {
        __syncthreads();
        GLDS16(A  + (long)(m0 + (t >> 2)) * K + k0 + ((t & 3) << 3), &As[t * 8]);
        GLDS16(Bt + (long)(n0 + (t >> 2)) * K + k0 + ((t & 3) << 3), &Bs[t * 8]);
        __syncthreads();
        bf16x8 afr[2], bfr[2];
        #pragma unroll
        for (int mi = 0; mi < 2; mi++)
            afr[mi] = *reinterpret_cast<const bf16x8*>(&As[(wr * 32 + mi * 16 + lo) * 32 + hi * 8]);
        #pragma unroll
        for (int ni = 0; ni < 2; ni++)
            bfr[ni] = *reinterpret_cast<const bf16x8*>(&Bs[(wc * 32 + ni * 16 + lo) * 32 + hi * 8]);
        #pragma unroll
        for (int mi = 0; mi < 2; mi++)
            #pragma unroll
            for (int ni = 0; ni < 2; ni++)
                acc[mi][ni] = __builtin_amdgcn_mfma_f32_16x16x32_bf16(afr[mi], bfr[ni], acc[mi][ni], 0, 0, 0);
    }

    #pragma unroll
    for (int mi = 0; mi < 2; mi++)
        #pragma unroll
        for (int ni = 0; ni < 2; ni++) {
            int col = n0 + wc * 32 + ni * 16 + lo;
            float bv = bias ? bias[col] : 0.f;
            #pragma unroll
            for (int rr = 0; rr < 4; rr++) {
                int row = m0 + wr * 32 + mi * 16 + hi * 4 + rr;
                float v = acc[mi][ni][rr] + bv;
                if (ACT) v = gelu_f(v);
                if (RES) v += res[(long)row * N + col];
                if (OUTBF16) ((__bf16*)C)[(long)row * N + col] = (__bf16)v;
                else         ((float*)C)[(long)row * N + col] = v;
            }
        }
}

// ---------- LM head fallback: A bf16 (glds), Wt[N][K] fp32 reg-staged ----------
__global__ __launch_bounds__(256) void gemm_lm(
    const __bf16* __restrict__ A, const float* __restrict__ Wt,
    float* __restrict__ C, int N, int K)
{
    __shared__ __bf16 As[128 * 32];
    __shared__ __bf16 Bs[128 * 32];
    const int t = threadIdx.x;
    const int m0 = blockIdx.x * 128;
    const int n0 = blockIdx.y * 128;
    const int w = t >> 6, lane = t & 63;
    const int lo = lane & 15, hi = lane >> 4;
    const int wr = w >> 1, wc = w & 1;

    f32x4 acc[4][4] = {};

    for (int k0 = 0; k0 < K; k0 += 32) {
        __syncthreads();
        #pragma unroll
        for (int i = 0; i < 2; i++) {
            int c = i * 256 + t;
            GLDS16(A + (long)(m0 + (c >> 2)) * K + k0 + ((c & 3) << 3), &As[c * 8]);
        }
        #pragma unroll
        for (int i = 0; i < 2; i++) {
            int c = i * 256 + t;
            int nr = n0 + (c >> 2);
            bf16x8 bv;
            if (nr < N) {
                const float* wp = Wt + (long)nr * K + k0 + ((c & 3) << 3);
                float4 b0 = *reinterpret_cast<const float4*>(wp);
                float4 b1 = *reinterpret_cast<const float4*>(wp + 4);
                bv[0] = (__bf16)b0.x; bv[1] = (__bf16)b0.y; bv[2] = (__bf16)b0.z; bv[3] = (__bf16)b0.w;
                bv[4] = (__bf16)b1.x; bv[5] = (__bf16)b1.y; bv[6] = (__bf16)b1.z; bv[7] = (__bf16)b1.w;
            } else {
                #pragma unroll
                for (int qq = 0; qq < 8; qq++) bv[qq] = (__bf16)0.f;
            }
            *reinterpret_cast<bf16x8*>(&Bs[c * 8]) = bv;
        }
        __syncthreads();
        bf16x8 afr[4], bfr[4];
        #pragma unroll
        for (int mi = 0; mi < 4; mi++)
            afr[mi] = *reinterpret_cast<const bf16x8*>(&As[(wr * 64 + mi * 16 + lo) * 32 + hi * 8]);
        #pragma unroll
        for (int ni = 0; ni < 4; ni++)
            bfr[ni] = *reinterpret_cast<const bf16x8*>(&Bs[(wc * 64 + ni * 16 + lo) * 32 + hi * 8]);
        #pragma unroll
        for (int mi = 0; mi < 4; mi++)
            #pragma unroll
            for (int ni = 0; ni < 4; ni++)
                acc[mi][ni] = __builtin_amdgcn_mfma_f32_16x16x32_bf16(afr[mi], bfr[ni], acc[mi][ni], 0, 0, 0);
    }

    #pragma unroll
    for (int mi = 0; mi < 4; mi++)
        #pragma unroll
        for (int ni = 0; ni < 4; ni++) {
            int col = n0 + wc * 64 + ni * 16 + lo;
            if (col < N) {
                #pragma unroll
                for (int rr = 0; rr < 4; rr++) {
                    int row = m0 + wr * 64 + mi * 16 + hi * 4 + rr;
                    C[(long)row * N + col] = acc[mi][ni][rr];
                }
            }
        }
}

// ---------- MFMA flash attention, no-max-tracking + reg-prefetch ----------
__global__ __launch_bounds__(256) void attn_mfma(
    const __bf16* __restrict__ qkv,
    const float* __restrict__ imgk, const float* __restrict__ imgv,
    const float* __restrict__ amask, __bf16* __restrict__ out)
{
    const int qb = blockIdx.x;
    const int h  = blockIdx.y;
    const int b  = blockIdx.z;
    const int t = threadIdx.x, w = t >> 6, lane = t & 63;
    const int lo = lane & 15, hi = lane >> 4;

    __shared__ __bf16 Ks[64][72];
    __shared__ __bf16 Vt[64][72];
    __shared__ __bf16 Ps[4][16][72];
    __shared__ float kimg_s[64];
    __shared__ float amv_s[64];

    const int kr8 = t >> 2, kd8 = (t & 3) * 16;
    const int vr8 = t & 63, vd8 = (t >> 6) * 16;

    const __bf16* qrow = qkv + (long)(b * 512 + qb * 64 + w * 16 + lo) * 3072 + h * 64;
    bf16x8 qf0 = *reinterpret_cast<const bf16x8*>(qrow + hi * 8);
    bf16x8 qf1 = *reinterpret_cast<const bf16x8*>(qrow + 32 + hi * 8);

    if (t < 64) kimg_s[t] = imgk[b * 1024 + h * 64 + t];
    __syncthreads();

    float simg = 0.f;
    #pragma unroll
    for (int i = 0; i < 8; i++)
        simg += (float)qf0[i] * kimg_s[hi * 8 + i] + (float)qf1[i] * kimg_s[32 + hi * 8 + i];
    simg += __shfl_xor(simg, 16);
    simg += __shfl_xor(simg, 32);
    simg *= 0.125f;

    float pimg[4], l_part[4];
    f32x4 o_acc[4];
    #pragma unroll
    for (int rr = 0; rr < 4; rr++) {
        pimg[rr] = __expf(__shfl(simg, hi * 4 + rr));
        l_part[rr] = 0.f;
    }
    #pragma unroll
    for (int df = 0; df < 4; df++) {
        float vi = imgv[b * 1024 + h * 64 + df * 16 + lo];
        #pragma unroll
        for (int rr = 0; rr < 4; rr++) o_acc[df][rr] = pimg[rr] * vi;
    }

    bf16x8 ck0, ck1, cv0, cv1;
    {
        const __bf16* ks = qkv + (long)(b * 512 + kr8) * 3072 + 1024 + h * 64 + kd8;
        ck0 = *reinterpret_cast<const bf16x8*>(ks);
        ck1 = *reinterpret_cast<const bf16x8*>(ks + 8);
        const __bf16* vs = qkv + (long)(b * 512 + vr8) * 3072 + 2048 + h * 64 + vd8;
        cv0 = *reinterpret_cast<const bf16x8*>(vs);
        cv1 = *reinterpret_cast<const bf16x8*>(vs + 8);
    }

    for (int kb = 0; kb <= qb; kb++) {
        bf16x8 nk0, nk1, nv0, nv1;
        const bool more = (kb < qb);
        if (more) {
            const __bf16* ks = qkv + (long)(b * 512 + (kb + 1) * 64 + kr8) * 3072 + 1024 + h * 64 + kd8;
            nk0 = *reinterpret_cast<const bf16x8*>(ks);
            nk1 = *reinterpret_cast<const bf16x8*>(ks + 8);
            const __bf16* vs = qkv + (long)(b * 512 + (kb + 1) * 64 + vr8) * 3072 + 2048 + h * 64 + vd8;
            nv0 = *reinterpret_cast<const bf16x8*>(vs);
            nv1 = *reinterpret_cast<const bf16x8*>(vs + 8);
        }
        __syncthreads();
        *reinterpret_cast<bf16x8*>(&Ks[kr8][kd8])     = ck0;
        *reinterpret_cast<bf16x8*>(&Ks[kr8][kd8 + 8]) = ck1;
        #pragma unroll
        for (int i = 0; i < 8; i++) { Vt[vd8 + i][vr8] = cv0[i]; Vt[vd8 + 8 + i][vr8] = cv1[i]; }
        if (t < 64) amv_s[t] = (1.0f - amask[b * 512 + kb * 64 + t]) * -10000.0f;
        __syncthreads();

        f32x4 sf[4];
        #pragma unroll
        for (int js = 0; js < 4; js++) {
            bf16x8 kf0 = *reinterpret_cast<const bf16x8*>(&Ks[js * 16 + lo][hi * 8]);
            bf16x8 kf1 = *reinterpret_cast<const bf16x8*>(&Ks[js * 16 + lo][32 + hi * 8]);
            f32x4 a = {};
            a = __builtin_amdgcn_mfma_f32_16x16x32_bf16(qf0, kf0, a, 0, 0, 0);
            a = __builtin_amdgcn_mfma_f32_16x16x32_bf16(qf1, kf1, a, 0, 0, 0);
            sf[js] = a;
        }
        #pragma unroll
        for (int js = 0; js < 4; js++) {
            float amv = amv_s[js * 16 + lo];
            #pragma unroll
            for (int rr = 0; rr < 4; rr++) {
                float sv = sf[js][rr] * 0.125f + amv;
                if (kb == qb) {
                    int qrw = w * 16 + hi * 4 + rr;
                    if (js * 16 + lo > qrw) sv = -10000.0f + amv;
                }
                float p = __expf(sv);
                l_part[rr] += p;
                Ps[w][hi * 4 + rr][js * 16 + lo] = (__bf16)p;
            }
        }
        #pragma unroll
        for (int jb = 0; jb < 2; jb++) {
            bf16x8 pf = *reinterpret_cast<const bf16x8*>(&Ps[w][lo][jb * 32 + hi * 8]);
            #pragma unroll
            for (int df = 0; df < 4; df++) {
                bf16x8 vf = *reinterpret_cast<const bf16x8*>(&Vt[df * 16 + lo][jb * 32 + hi * 8]);
                o_acc[df] = __builtin_amdgcn_mfma_f32_16x16x32_bf16(pf, vf, o_acc[df], 0, 0, 0);
            }
        }
        if (more) { ck0 = nk0; ck1 = nk1; cv0 = nv0; cv1 = nv1; }
    }

    float linv[4];
    #pragma unroll
    for (int rr = 0; rr < 4; rr++) {
        float ls = l_part[rr];
        #pragma unroll
        for (int off = 1; off < 16; off <<= 1) ls += __shfl_xor(ls, off);
        linv[rr] = 1.0f / (pimg[rr] + ls);
    }
    #pragma unroll
    for (int df = 0; df < 4; df++)
        #pragma unroll
        for (int rr = 0; rr < 4; rr++) {
            long row = b * 512 + qb * 64 + w * 16 + hi * 4 + rr;
            out[row * 1024 + h * 64 + df * 16 + lo] = (__bf16)(o_acc[df][rr] * linv[rr]);
        }
}

// ---------- host orchestration ----------
extern "C" void kernel_launch(void* const* d_in, const int* in_sizes, int n_in,
                              void* d_out, int out_size, void* d_ws, size_t ws_size,
                              hipStream_t stream) {
    (void)in_sizes; (void)n_in; (void)out_size;
    const int*   ids   = (const int*)d_in[0];
    const float* amask = (const float*)d_in[1];
    const float* ihs   = (const float*)d_in[2];
    const float* wte   = (const float*)d_in[3];
    const float* ftW1  = (const float*)d_in[4];
    const float* ftb1  = (const float*)d_in[5];
    const float* ftW2  = (const float*)d_in[6];
    const float* ftb2  = (const float*)d_in[7];
    const float* ln1g  = (const float*)d_in[8];
    const float* ln1b  = (const float*)d_in[9];
    const float* Wattn = (const float*)d_in[10];
    const float* battn = (const float*)d_in[11];
    const float* Wuk   = (const float*)d_in[12];
    const float* buk   = (const float*)d_in[13];
    const float* Wuv   = (const float*)d_in[14];
    const float* buv   = (const float*)d_in[15];
    const float* Wproj = (const float*)d_in[16];
    const float* bproj = (const float*)d_in[17];
    const float* ln2g  = (const float*)d_in[18];
    const float* ln2b  = (const float*)d_in[19];
    const float* Wfc   = (const float*)d_in[20];
    const float* bfc   = (const float*)d_in[21];
    const float* Wfc2  = (const float*)d_in[22];
    const float* bfc2  = (const float*)d_in[23];
    const float* lnfg  = (const float*)d_in[24];
    const float* lnfb  = (const float*)d_in[25];
    float* out = (float*)d_out;

    const long VP = 50304;
    char* base = (char*)d_ws;
    float* ftmp  = (float*)(base);
    float* img   = (float*)(base + (1 << 13));
    float* imgk  = (float*)(base + (1 << 14));
    float* imgv  = (float*)(base + 114688);
    float* part  = (float*)(base + 212992);     // 208896 f32 capacity; kv uses 196608
    float* h     = (float*)(base + 1048576);
    char* p = base + 5 * 1048576;
    __bf16* xb    = (__bf16*)p; p += 2 * 1048576;
    __bf16* qkvb  = (__bf16*)p; p += 6 * 1048576;
    __bf16* attob = (__bf16*)p; p += 2 * 1048576;
    __bf16* ffb   = (__bf16*)p; p += 8 * 1048576;
    __bf16* wtA   = (__bf16*)p; p += 6 * 1048576;
    __bf16* wtP   = (__bf16*)p; p += 2 * 1048576;
    __bf16* wtF   = (__bf16*)p; p += 8 * 1048576;
    __bf16* wtF2  = (__bf16*)p; p += 8 * 1048576;
    __bf16* wteb  = (__bf16*)p;
    size_t need1 = (size_t)(p - base) + (size_t)VP * 1024 * 2;
    float* part_g = (float*)(base + need1);     // 4 fp32 partial buffers of 1M floats
    size_t need2 = need1 + 4 * 1048576 * sizeof(float);
    const bool big_ws  = (ws_size >= need1);
    const bool big_ws2 = (ws_size >= need2);

    dim3 b256(256);

    // image feature transform (ksplit-8) + batched K/V projections (ksplit-4)
    gemv_part<<<dim3(16, 8, 1), b256, 0, stream>>>(ihs, 1024, ftW1, 0, part, 1024, 1024);
    gemv_reduce<<<dim3(8), b256, 0, stream>>>(part, ftb1, 0, ftmp, 1024, 1, 1);
    gemv_part<<<dim3(16, 8, 1), b256, 0, stream>>>(ftmp, 1024, ftW2, 0, part, 1024, 1024);
    gemv_reduce<<<dim3(8), b256, 0, stream>>>(part, ftb2, 0, img, 1024, 1, 0);
    gemv_kv_part<<<dim3(16, 4, 24), b256, 0, stream>>>(img, Wuk, Wuv, part);
    gemv_kv_reduce<<<dim3(192), b256, 0, stream>>>(part, buk, buv, imgk, imgv);

    embed_ln<<<dim3(1024), b256, 0, stream>>>(ids, wte, h, xb, ln1g, ln1b);

    for (int l = 0; l < 12; l++) {
        tcvt_layer<<<dim3(12288), b256, 0, stream>>>(
            Wattn + (long)l * 1024 * 3072, Wproj + (long)l * 1024 * 1024,
            Wfc + (long)l * 1024 * 4096, Wfc2 + (long)l * 4096 * 1024,
            wtA, wtP, wtF, wtF2);

        // qkv: 64x128 tiles, 384 blocks
        gemm64<128, 1, 0, 0><<<dim3(384), b256, 0, stream>>>(
            xb, wtA, battn + l * 3072, qkvb, 3072, 1024, 16, 24, 1);
        attn_mfma<<<dim3(8, 16, 2), b256, 0, stream>>>(
            qkvb, imgk + l * 2048, imgv + l * 2048, amask, attob);

        const float* ng = (l < 11) ? (ln1g + (l + 1) * 1024) : lnfg;
        const float* nb = (l < 11) ? (ln1b + (l + 1) * 1024) : lnfb;
        if (big_ws2) {
            // proj: 64x64 ksplit-2 partial (512 blocks) + fused residual/bias/ln2
            gemm64<64, 0, 0, 1><<<dim3(512), b256, 0, stream>>>(
                attob, wtP, nullptr, part_g, 1024, 1024, 16, 16, 2);
            lnadd_k<2><<<dim3(1024), b256, 0, stream>>>(
                h, part_g, bproj + l * 1024, ln2g + l * 1024, ln2b + l * 1024, xb);
            // fc: 64x128 (512 blocks), gelu, bf16 out
            gemm64<128, 1, 1, 0><<<dim3(512), b256, 0, stream>>>(
                xb, wtF, bfc + l * 4096, ffb, 4096, 1024, 16, 32, 1);
            // fc2: 64x128 ksplit-4 partial (512 blocks) + fused residual/bias/next-ln
            gemm64<128, 0, 0, 1><<<dim3(512), b256, 0, stream>>>(
                ffb, wtF2, nullptr, part_g, 1024, 4096, 16, 8, 4);
            lnadd_k<4><<<dim3(1024), b256, 0, stream>>>(
                h, part_g, bfc2 + l * 1024, ng, nb, xb);
        } else {
            gemm_bb<0, 0, 1><<<dim3(16, 16), b256, 0, stream>>>(
                attob, wtP, bproj + l * 1024, h, h, 1024, 1024);
            ln_k<<<dim3(1024), b256, 0, stream>>>(h, xb, ln2g + l * 1024, ln2b + l * 1024);
            gemm64<128, 1, 1, 0><<<dim3(512), b256, 0, stream>>>(
                xb, wtF, bfc + l * 4096, ffb, 4096, 1024, 16, 32, 1);
            gemm_bb<0, 0, 1><<<dim3(16, 16), b256, 0, stream>>>(
                ffb, wtF2, bfc2 + l * 1024, h, h, 1024, 4096);
            ln_k<<<dim3(1024), b256, 0, stream>>>(h, xb, ng, nb);
        }
    }

    // xb holds lnf(h); convert wte late so bf16 panels are L3-warm for the LM GEMM
    if (big_ws) {
        wcvt<<<dim3((unsigned)(VP * 1024 / 2048)), b256, 0, stream>>>(wte, wteb, 50257L * 1024);
        gemm128<0, 0, 1, 0><<<dim3(3144), b256, 0, stream>>>(
            xb, wteb, nullptr, out, 50257, 1024, 8, 393, 1);
    } else {
        gemm_lm<<<dim3(8, 393), b256, 0, stream>>>(xb, wte, out, 50257, 1024);
    }
}

// Round 7
// 1474.173 us; speedup vs baseline: 3.7839x; 1.0806x over previous
//
#include <hip/hip_runtime.h>
#include <cstdint>

// B=2, S=512, D=1024, H=16, HD=64, L=12, V=50257, DFF=4096

typedef __bf16 bf16x8 __attribute__((ext_vector_type(8)));
typedef __bf16 bf16x4 __attribute__((ext_vector_type(4)));
typedef float  f32x4  __attribute__((ext_vector_type(4)));

#define GLDS16(g, l) __builtin_amdgcn_global_load_lds( \
    (const __attribute__((address_space(1))) unsigned int*)(g), \
    (__attribute__((address_space(3))) unsigned int*)(l), 16, 0, 0)

#define SCHED_FENCE() __builtin_amdgcn_sched_barrier(0)

__device__ __forceinline__ float gelu_f(float x) {
    float u = 1.5957691216057308f * (x + 0.044715f * x * x * x);
    float e = __expf(u);
    float t = 1.0f - 2.0f / (e + 1.0f);
    return 0.5f * x * (1.0f + t);
}

// swizzled fragment offset in a [rows][64] bf16 LDS tile (T2 XOR, pairs with staging perm)
__device__ __forceinline__ int fragoff(int row, int kh, int hi) {
    return row * 64 + ((kh * 32 + hi * 8) ^ ((row & 7) << 3));
}

// ---------- weight transpose+convert body: 64x64 f32 tile -> bf16 [N][K] ----------
// id < 768: Wattn (K1024,N3072); <1024: Wproj; <2048: Wfc (K1024,N4096); else Wfc2 (K4096,N1024)
__device__ __forceinline__ void tcvt_body(
    int id, const float* __restrict__ Wa, const float* __restrict__ Wp,
    const float* __restrict__ Wf, const float* __restrict__ Wf2,
    __bf16* __restrict__ oa, __bf16* __restrict__ op,
    __bf16* __restrict__ of, __bf16* __restrict__ of2, float* tile)
{
    const float* src; __bf16* dst; int K, N, kb, nb;
    if (id < 768)       { src = Wa;  dst = oa;  K = 1024; N = 3072; kb = id & 15; nb = id >> 4; }
    else if (id < 1024) { id -= 768;  src = Wp;  dst = op;  K = 1024; N = 1024; kb = id & 15; nb = id >> 4; }
    else if (id < 2048) { id -= 1024; src = Wf;  dst = of;  K = 1024; N = 4096; kb = id & 15; nb = id >> 4; }
    else                { id -= 2048; src = Wf2; dst = of2; K = 4096; N = 1024; kb = id & 63; nb = id >> 6; }
    const int k0 = kb * 64, n0 = nb * 64;
    const int t = threadIdx.x;
    #pragma unroll
    for (int i = 0; i < 4; i++) {
        int r = i * 16 + (t >> 4), c = (t & 15) * 4;
        float4 v = *reinterpret_cast<const float4*>(src + (long)(k0 + r) * N + n0 + c);
        tile[r * 65 + c] = v.x; tile[r * 65 + c + 1] = v.y;
        tile[r * 65 + c + 2] = v.z; tile[r * 65 + c + 3] = v.w;
    }
    __syncthreads();
    const int nrow = t >> 2, kc = (t & 3) * 16;
    bf16x8 o0, o1;
    #pragma unroll
    for (int i = 0; i < 8; i++) {
        o0[i] = (__bf16)tile[(kc + i) * 65 + nrow];
        o1[i] = (__bf16)tile[(kc + 8 + i) * 65 + nrow];
    }
    *reinterpret_cast<bf16x8*>(dst + (long)(n0 + nrow) * K + k0 + kc)     = o0;
    *reinterpret_cast<bf16x8*>(dst + (long)(n0 + nrow) * K + k0 + kc + 8) = o1;
}

// ---------- wte fp32 -> bf16 body (8192 elems/block, zero-pads past nvalid) ----------
__device__ __forceinline__ void wcvt_body(
    int id, const float* __restrict__ wte, __bf16* __restrict__ out, long nvalid)
{
    long base = (long)id * 8192 + threadIdx.x * 8;
    #pragma unroll
    for (int i = 0; i < 4; i++) {
        long e = base + (long)i * 2048;
        bf16x8 o;
        if (e < nvalid) {
            float4 a = *reinterpret_cast<const float4*>(wte + e);
            float4 b = *reinterpret_cast<const float4*>(wte + e + 4);
            o[0] = (__bf16)a.x; o[1] = (__bf16)a.y; o[2] = (__bf16)a.z; o[3] = (__bf16)a.w;
            o[4] = (__bf16)b.x; o[5] = (__bf16)b.y; o[6] = (__bf16)b.z; o[7] = (__bf16)b.w;
        } else {
            #pragma unroll
            for (int q = 0; q < 8; q++) o[q] = (__bf16)0.f;
        }
        *reinterpret_cast<bf16x8*>(out + e) = o;
    }
}

__global__ __launch_bounds__(256) void tcvt_std(
    const float* __restrict__ Wa, const float* __restrict__ Wp,
    const float* __restrict__ Wf, const float* __restrict__ Wf2,
    __bf16* __restrict__ oa, __bf16* __restrict__ op,
    __bf16* __restrict__ of, __bf16* __restrict__ of2)
{
    __shared__ float tile[64 * 65];
    tcvt_body(blockIdx.x, Wa, Wp, Wf, Wf2, oa, op, of, of2, tile);
}

__global__ __launch_bounds__(256) void wcvt_std(
    const float* __restrict__ wte, __bf16* __restrict__ out, long nvalid)
{
    wcvt_body(blockIdx.x, wte, out, nvalid);
}

// ---------- small GEMV path (img feature transform), ksplit-8 ----------
__global__ __launch_bounds__(256) void gemv_part(
    const float* __restrict__ x, int xld,
    const float* __restrict__ W, long wzs,
    float* __restrict__ part, int K, int N)
{
    int jb = blockIdx.x, kz = blockIdx.y, z = blockIdx.z;
    int t = threadIdx.x;
    int j = (jb << 6) + (t & 63);
    int g = t >> 6;
    int klen = K / (gridDim.y * 4);
    int kbase = (kz * 4 + g) * klen;
    const float* Wp = W + (long)z * wzs + (long)kbase * N + j;
    const float* x0 = x + kbase;
    const float* x1 = x + xld + kbase;
    float a0 = 0.f, a1 = 0.f;
    for (int k = 0; k < klen; k++) {
        float wv = Wp[(long)k * N];
        a0 += x0[k] * wv;
        a1 += x1[k] * wv;
    }
    __shared__ float r0[4][64], r1[4][64];
    r0[g][t & 63] = a0; r1[g][t & 63] = a1;
    __syncthreads();
    if (t < 64) {
        a0 = r0[0][t] + r0[1][t] + r0[2][t] + r0[3][t];
        a1 = r1[0][t] + r1[1][t] + r1[2][t] + r1[3][t];
        long base = (long)(z * gridDim.y + kz) * 2 * N + (jb << 6) + t;
        part[base]     = a0;
        part[base + N] = a1;
    }
}

__global__ __launch_bounds__(256) void gemv_reduce(
    const float* __restrict__ part, const float* __restrict__ bias, long bzs,
    float* __restrict__ out, int N, int nz, int act)
{
    int idx = blockIdx.x * 256 + threadIdx.x;
    if (idx >= nz * 2 * N) return;
    int j  = idx % N;
    int bz = idx / N;
    int z  = bz >> 1;
    float s = bias[(long)z * bzs + j];
    const float* p = part + ((long)z * 8 * 2 + (bz & 1)) * N + j;
    #pragma unroll
    for (int kz = 0; kz < 8; kz++) s += p[(long)kz * 2 * N];
    if (act) s = fmaxf(s, 0.f);
    out[idx] = s;
}

// ---------- batched img K/V projections ----------
__global__ __launch_bounds__(256) void gemv_kv_part(
    const float* __restrict__ img,
    const float* __restrict__ Wuk, const float* __restrict__ Wuv,
    float* __restrict__ part)
{
    int jb = blockIdx.x, kz = blockIdx.y, z = blockIdx.z;
    int t = threadIdx.x;
    int j = (jb << 6) + (t & 63);
    int g = t >> 6;
    int kbase = (kz * 4 + g) * 64;
    const float* W = (z < 12) ? (Wuk + (long)z * 1048576) : (Wuv + (long)(z - 12) * 1048576);
    const float* Wp = W + (long)kbase * 1024 + j;
    const float* x0 = img + kbase;
    const float* x1 = img + 1024 + kbase;
    float a0 = 0.f, a1 = 0.f;
    for (int k = 0; k < 64; k++) {
        float wv = Wp[(long)k * 1024];
        a0 += x0[k] * wv;
        a1 += x1[k] * wv;
    }
    __shared__ float r0[4][64], r1[4][64];
    r0[g][t & 63] = a0; r1[g][t & 63] = a1;
    __syncthreads();
    if (t < 64) {
        a0 = r0[0][t] + r0[1][t] + r0[2][t] + r0[3][t];
        a1 = r1[0][t] + r1[1][t] + r1[2][t] + r1[3][t];
        long base = (long)(z * 4 + kz) * 2 * 1024 + (jb << 6) + t;
        part[base]        = a0;
        part[base + 1024] = a1;
    }
}

__global__ __launch_bounds__(256) void gemv_kv_reduce(
    const float* __restrict__ part,
    const float* __restrict__ buk, const float* __restrict__ buv,
    float* __restrict__ imgk, float* __restrict__ imgv)
{
    int idx = blockIdx.x * 256 + threadIdx.x;
    int z = idx >> 11;
    int bsel = (idx >> 10) & 1;
    int j = idx & 1023;
    float s = (z < 12) ? buk[z * 1024 + j] : buv[(z - 12) * 1024 + j];
    const float* p = part + ((long)z * 4 * 2 + bsel) * 1024 + j;
    #pragma unroll
    for (int kz = 0; kz < 4; kz++) s += p[(long)kz * 2 * 1024];
    if (z < 12) imgk[z * 2048 + bsel * 1024 + j] = s;
    else        imgv[(z - 12) * 2048 + bsel * 1024 + j] = s;
}

// ---------- fused embedding + LN (layer-0 ln1) ----------
__global__ __launch_bounds__(256) void embed_ln(
    const int* __restrict__ ids, const float* __restrict__ wte,
    float* __restrict__ h, __bf16* __restrict__ xb,
    const float* __restrict__ g, const float* __restrict__ b)
{
    int row = blockIdx.x;
    int s = row & 511;
    int t = threadIdx.x;
    long id = ids[row];
    float4 v1 = reinterpret_cast<const float4*>(wte + id * 1024)[t];
    float4 v2 = reinterpret_cast<const float4*>(wte + (long)s * 1024)[t];
    float4 v; v.x = v1.x + v2.x; v.y = v1.y + v2.y; v.z = v1.z + v2.z; v.w = v1.w + v2.w;
    reinterpret_cast<float4*>(h + (long)row * 1024)[t] = v;

    float s1 = v.x + v.y + v.z + v.w;
    float s2 = v.x * v.x + v.y * v.y + v.z * v.z + v.w * v.w;
    #pragma unroll
    for (int o = 32; o >= 1; o >>= 1) { s1 += __shfl_xor(s1, o); s2 += __shfl_xor(s2, o); }
    __shared__ float r1[4], r2[4];
    int w = t >> 6;
    if ((t & 63) == 0) { r1[w] = s1; r2[w] = s2; }
    __syncthreads();
    s1 = r1[0] + r1[1] + r1[2] + r1[3];
    s2 = r2[0] + r2[1] + r2[2] + r2[3];
    float mean = s1 * (1.0f / 1024.0f);
    float var  = s2 * (1.0f / 1024.0f) - mean * mean;
    float rstd = rsqrtf(var + 1e-5f);
    float4 gg = reinterpret_cast<const float4*>(g)[t];
    float4 bb = reinterpret_cast<const float4*>(b)[t];
    bf16x4 o;
    o[0] = (__bf16)((v.x - mean) * rstd * gg.x + bb.x);
    o[1] = (__bf16)((v.y - mean) * rstd * gg.y + bb.y);
    o[2] = (__bf16)((v.z - mean) * rstd * gg.z + bb.z);
    o[3] = (__bf16)((v.w - mean) * rstd * gg.w + bb.w);
    *reinterpret_cast<bf16x4*>(xb + (long)row * 1024 + t * 4) = o;
}

// ---------- LayerNorm (fallback path) ----------
__global__ __launch_bounds__(256) void ln_k(
    const float* __restrict__ in, __bf16* __restrict__ out,
    const float* __restrict__ g, const float* __restrict__ b)
{
    int row = blockIdx.x, t = threadIdx.x;
    float4 v = reinterpret_cast<const float4*>(in + (long)row * 1024)[t];
    float s1 = v.x + v.y + v.z + v.w;
    float s2 = v.x * v.x + v.y * v.y + v.z * v.z + v.w * v.w;
    #pragma unroll
    for (int o = 32; o >= 1; o >>= 1) { s1 += __shfl_xor(s1, o); s2 += __shfl_xor(s2, o); }
    __shared__ float r1[4], r2[4];
    int w = t >> 6;
    if ((t & 63) == 0) { r1[w] = s1; r2[w] = s2; }
    __syncthreads();
    s1 = r1[0] + r1[1] + r1[2] + r1[3];
    s2 = r2[0] + r2[1] + r2[2] + r2[3];
    float mean = s1 * (1.0f / 1024.0f);
    float var  = s2 * (1.0f / 1024.0f) - mean * mean;
    float rstd = rsqrtf(var + 1e-5f);
    float4 gg = reinterpret_cast<const float4*>(g)[t];
    float4 bb = reinterpret_cast<const float4*>(b)[t];
    bf16x4 o;
    o[0] = (__bf16)((v.x - mean) * rstd * gg.x + bb.x);
    o[1] = (__bf16)((v.y - mean) * rstd * gg.y + bb.y);
    o[2] = (__bf16)((v.z - mean) * rstd * gg.z + bb.z);
    o[3] = (__bf16)((v.w - mean) * rstd * gg.w + bb.w);
    *reinterpret_cast<bf16x4*>(out + (long)row * 1024 + t * 4) = o;
}

// ---------- fused: h += bias + sum(NP parts); out = LN(h) ----------
template<int NP>
__global__ __launch_bounds__(256) void lnadd_k(
    float* __restrict__ h, const float* __restrict__ part,
    const float* __restrict__ bias,
    const float* __restrict__ g, const float* __restrict__ b,
    __bf16* __restrict__ out)
{
    int row = blockIdx.x, t = threadIdx.x;
    long off = (long)row * 1024 + t * 4;
    float4 v = *reinterpret_cast<const float4*>(h + off);
    #pragma unroll
    for (int sp = 0; sp < NP; sp++) {
        float4 pv = *reinterpret_cast<const float4*>(part + sp * 1048576L + off);
        v.x += pv.x; v.y += pv.y; v.z += pv.z; v.w += pv.w;
    }
    float4 bi = reinterpret_cast<const float4*>(bias)[t];
    v.x += bi.x; v.y += bi.y; v.z += bi.z; v.w += bi.w;
    *reinterpret_cast<float4*>(h + off) = v;

    float s1 = v.x + v.y + v.z + v.w;
    float s2 = v.x * v.x + v.y * v.y + v.z * v.z + v.w * v.w;
    #pragma unroll
    for (int o = 32; o >= 1; o >>= 1) { s1 += __shfl_xor(s1, o); s2 += __shfl_xor(s2, o); }
    __shared__ float r1[4], r2[4];
    int w = t >> 6;
    if ((t & 63) == 0) { r1[w] = s1; r2[w] = s2; }
    __syncthreads();
    s1 = r1[0] + r1[1] + r1[2] + r1[3];
    s2 = r2[0] + r2[1] + r2[2] + r2[3];
    float mean = s1 * (1.0f / 1024.0f);
    float var  = s2 * (1.0f / 1024.0f) - mean * mean;
    float rstd = rsqrtf(var + 1e-5f);
    float4 gg = reinterpret_cast<const float4*>(g)[t];
    float4 bb = reinterpret_cast<const float4*>(b)[t];
    bf16x4 o;
    o[0] = (__bf16)((v.x - mean) * rstd * gg.x + bb.x);
    o[1] = (__bf16)((v.y - mean) * rstd * gg.y + bb.y);
    o[2] = (__bf16)((v.z - mean) * rstd * gg.z + bb.z);
    o[3] = (__bf16)((v.w - mean) * rstd * gg.w + bb.w);
    *reinterpret_cast<bf16x4*>(out + off) = o;
}

// ---------- 256x256 GEMM (LM head), BK=64, T2 swizzle, counted-vmcnt 2-phase ----------
// 512 threads, 8 waves (2 M x 4 N), per-wave 128x64 output, 128 KB LDS.
__global__ __launch_bounds__(512) void gemm256(
    const __bf16* __restrict__ A, const __bf16* __restrict__ Bt,
    float* __restrict__ C, int N, int K, int GM, int GN)
{
    const int total = GM * GN;
    const int q = total >> 3, r = total & 7;
    const int x = blockIdx.x & 7, jj = blockIdx.x >> 3;
    const int w0 = (x < r) ? x * (q + 1) + jj : r * (q + 1) + (x - r) * q + jj;
    const int m0 = (w0 % GM) * 256;
    const int n0 = (w0 / GM) * 256;

    __shared__ __bf16 As[2][256 * 64];
    __shared__ __bf16 Bs[2][256 * 64];
    const int t = threadIdx.x;
    const int wid = t >> 6, lane = t & 63;
    const int lo = lane & 15, hi = lane >> 4;
    const int wr = wid >> 2, wc = wid & 3;

    f32x4 acc[8][4] = {};

    const int srow = t >> 3;                      // 0..63
    const int skx  = (((t & 7) ^ (srow & 7)) << 3);
    const int sldst = t * 8;                      // within a 64-row stripe (4096 elems)
    #define ST256(bf, kk) do { \
        _Pragma("unroll") \
        for (int i = 0; i < 4; i++) \
            GLDS16(A + (long)(m0 + i * 64 + srow) * K + (kk) + skx, &As[bf][i * 4096 + sldst]); \
        _Pragma("unroll") \
        for (int i = 0; i < 4; i++) \
            GLDS16(Bt + (long)(n0 + i * 64 + srow) * K + (kk) + skx, &Bs[bf][i * 4096 + sldst]); \
    } while (0)

    const int T = K >> 6;
    ST256(0, 0);
    int cur = 0;
    for (int it = 0; it < T; it++) {
        if (it + 1 < T) {
            ST256(cur ^ 1, (it + 1) * 64);
            asm volatile("s_waitcnt vmcnt(8)" ::: "memory");
        } else {
            asm volatile("s_waitcnt vmcnt(0)" ::: "memory");
        }
        SCHED_FENCE();
        __builtin_amdgcn_s_barrier();
        SCHED_FENCE();

        #pragma unroll
        for (int kh = 0; kh < 2; kh++) {
            bf16x8 afr[8], bfr[4];
            #pragma unroll
            for (int mi = 0; mi < 8; mi++)
                afr[mi] = *reinterpret_cast<const bf16x8*>(&As[cur][fragoff(wr * 128 + mi * 16 + lo, kh, hi)]);
            #pragma unroll
            for (int ni = 0; ni < 4; ni++)
                bfr[ni] = *reinterpret_cast<const bf16x8*>(&Bs[cur][fragoff(wc * 64 + ni * 16 + lo, kh, hi)]);
            #pragma unroll
            for (int mi = 0; mi < 8; mi++)
                #pragma unroll
                for (int ni = 0; ni < 4; ni++)
                    acc[mi][ni] = __builtin_amdgcn_mfma_f32_16x16x32_bf16(afr[mi], bfr[ni], acc[mi][ni], 0, 0, 0);
        }

        SCHED_FENCE();
        __builtin_amdgcn_s_barrier();
        SCHED_FENCE();
        cur ^= 1;
    }
    #undef ST256

    #pragma unroll
    for (int mi = 0; mi < 8; mi++)
        #pragma unroll
        for (int ni = 0; ni < 4; ni++) {
            int col = n0 + wc * 64 + ni * 16 + lo;
            if (col >= N) continue;
            #pragma unroll
            for (int rr = 0; rr < 4; rr++) {
                int row = m0 + wr * 128 + mi * 16 + hi * 4 + rr;
                C[(long)row * N + col] = acc[mi][ni][rr];
            }
        }
}

// ---------- 64xBN GEMM, BK=64, swizzled, counted-vmcnt 2-phase ----------
template<int BN, int OUTBF16, int ACT, int PARTIAL>
__global__ __launch_bounds__(256) void gemm64(
    const __bf16* __restrict__ A, const __bf16* __restrict__ Bt,
    const float* __restrict__ bias, void* __restrict__ C,
    int N, int K, int GM, int GN, int NS)
{
    constexpr int NB = BN / 32;
    const int total = GM * GN * NS;
    const int q = total >> 3, r = total & 7;
    const int x = blockIdx.x & 7, jj = blockIdx.x >> 3;
    const int w0 = (x < r) ? x * (q + 1) + jj : r * (q + 1) + (x - r) * q + jj;
    const int sp = w0 / (GM * GN);
    const int rem = w0 - sp * (GM * GN);
    const int m0 = (rem % GM) * 64;
    const int n0 = (rem / GM) * BN;

    __shared__ __bf16 As[2][64 * 64];
    __shared__ __bf16 Bs[2][BN * 64];
    const int t = threadIdx.x;
    const int wv = t >> 6, lane = t & 63;
    const int lo = lane & 15, hi = lane >> 4;
    const int wr = wv >> 1, wc = wv & 1;

    f32x4 acc[2][NB] = {};

    const int srow = t >> 3;
    const int skx  = (((t & 7) ^ (srow & 7)) << 3);
    const int sldst = t * 8;
    #define ST64(bf, kk) do { \
        _Pragma("unroll") \
        for (int i = 0; i < 2; i++) \
            GLDS16(A + (long)(m0 + i * 32 + srow) * K + (kk) + skx, &As[bf][i * 2048 + sldst]); \
        _Pragma("unroll") \
        for (int i = 0; i < NB; i++) \
            GLDS16(Bt + (long)(n0 + i * 32 + srow) * K + (kk) + skx, &Bs[bf][i * 2048 + sldst]); \
    } while (0)

    const int Ksp = K / NS;
    const int kbeg = sp * Ksp;
    const int T = Ksp >> 6;

    ST64(0, kbeg);
    int cur = 0;
    for (int it = 0; it < T; it++) {
        if (it + 1 < T) {
            ST64(cur ^ 1, kbeg + (it + 1) * 64);
            if constexpr (NB == 4) asm volatile("s_waitcnt vmcnt(6)" ::: "memory");
            else                   asm volatile("s_waitcnt vmcnt(4)" ::: "memory");
        } else {
            asm volatile("s_waitcnt vmcnt(0)" ::: "memory");
        }
        SCHED_FENCE();
        __builtin_amdgcn_s_barrier();
        SCHED_FENCE();

        #pragma unroll
        for (int kh = 0; kh < 2; kh++) {
            bf16x8 afr[2], bfr[NB];
            #pragma unroll
            for (int mi = 0; mi < 2; mi++)
                afr[mi] = *reinterpret_cast<const bf16x8*>(&As[cur][fragoff(wr * 32 + mi * 16 + lo, kh, hi)]);
            #pragma unroll
            for (int ni = 0; ni < NB; ni++)
                bfr[ni] = *reinterpret_cast<const bf16x8*>(&Bs[cur][fragoff(wc * (BN / 2) + ni * 16 + lo, kh, hi)]);
            #pragma unroll
            for (int mi = 0; mi < 2; mi++)
                #pragma unroll
                for (int ni = 0; ni < NB; ni++)
                    acc[mi][ni] = __builtin_amdgcn_mfma_f32_16x16x32_bf16(afr[mi], bfr[ni], acc[mi][ni], 0, 0, 0);
        }

        SCHED_FENCE();
        __builtin_amdgcn_s_barrier();
        SCHED_FENCE();
        cur ^= 1;
    }
    #undef ST64

    const long coff = PARTIAL ? (long)sp * GM * 64 * N : 0;
    #pragma unroll
    for (int mi = 0; mi < 2; mi++)
        #pragma unroll
        for (int ni = 0; ni < NB; ni++) {
            int col = n0 + wc * (BN / 2) + ni * 16 + lo;
            float bv = (!PARTIAL && bias) ? bias[col] : 0.f;
            #pragma unroll
            for (int rr = 0; rr < 4; rr++) {
                int row = m0 + wr * 32 + mi * 16 + hi * 4 + rr;
                float v = acc[mi][ni][rr] + bv;
                if (ACT) v = gelu_f(v);
                if (OUTBF16) ((__bf16*)C)[(long)row * N + col] = (__bf16)v;
                else         ((float*)C)[coff + (long)row * N + col] = v;
            }
        }
}

// ---------- fallback 64x64 GEMM (BK=32) ----------
template<int OUTBF16, int ACT, int RES>
__global__ __launch_bounds__(256) void gemm_bb(
    const __bf16* __restrict__ A, const __bf16* __restrict__ Bt,
    const float* __restrict__ bias, const float* __restrict__ res,
    void* __restrict__ C, int N, int K)
{
    __shared__ __bf16 As[64 * 32];
    __shared__ __bf16 Bs[64 * 32];
    const int t = threadIdx.x;
    const int m0 = blockIdx.x * 64;
    const int n0 = blockIdx.y * 64;
    const int w = t >> 6, lane = t & 63;
    const int lo = lane & 15, hi = lane >> 4;
    const int wr = w >> 1, wc = w & 1;

    f32x4 acc[2][2] = {};

    for (int k0 = 0; k0 < K; k0 += 32) {
        __syncthreads();
        GLDS16(A  + (long)(m0 + (t >> 2)) * K + k0 + ((t & 3) << 3), &As[t * 8]);
        GLDS16(Bt + (long)(n0 + (t >> 2)) * K + k0 + ((t & 3) << 3), &Bs[t * 8]);
        __syncthreads();
        bf16x8 afr[2], bfr[2];
        #pragma unroll
        for (int mi = 0; mi < 2; mi++)
            afr[mi] = *reinterpret_cast<const bf16x8*>(&As[(wr * 32 + mi * 16 + lo) * 32 + hi * 8]);
        #pragma unroll
        for (int ni = 0; ni < 2; ni++)
            bfr[ni] = *reinterpret_cast<const bf16x8*>(&Bs[(wc * 32 + ni * 16 + lo) * 32 + hi * 8]);
        #pragma unroll
        for (int mi = 0; mi < 2; mi++)
            #pragma unroll
            for (int ni = 0; ni < 2; ni++)
                acc[mi][ni] = __builtin_amdgcn_mfma_f32_16x16x32_bf16(afr[mi], bfr[ni], acc[mi][ni], 0, 0, 0);
    }

    #pragma unroll
    for (int mi = 0; mi < 2; mi++)
        #pragma unroll
        for (int ni = 0; ni < 2; ni++) {
            int col = n0 + wc * 32 + ni * 16 + lo;
            float bv = bias ? bias[col] : 0.f;
            #pragma unroll
            for (int rr = 0; rr < 4; rr++) {
                int row = m0 + wr * 32 + mi * 16 + hi * 4 + rr;
                float v = acc[mi][ni][rr] + bv;
                if (ACT) v = gelu_f(v);
                if (RES) v += res[(long)row * N + col];
                if (OUTBF16) ((__bf16*)C)[(long)row * N + col] = (__bf16)v;
                else         ((float*)C)[(long)row * N + col] = v;
            }
        }
}

// ---------- LM head fallback: A bf16 (glds), Wt[N][K] fp32 reg-staged ----------
__global__ __launch_bounds__(256) void gemm_lm(
    const __bf16* __restrict__ A, const float* __restrict__ Wt,
    float* __restrict__ C, int N, int K)
{
    __shared__ __bf16 As[128 * 32];
    __shared__ __bf16 Bs[128 * 32];
    const int t = threadIdx.x;
    const int m0 = blockIdx.x * 128;
    const int n0 = blockIdx.y * 128;
    const int w = t >> 6, lane = t & 63;
    const int lo = lane & 15, hi = lane >> 4;
    const int wr = w >> 1, wc = w & 1;

    f32x4 acc[4][4] = {};

    for (int k0 = 0; k0 < K; k0 += 32) {
        __syncthreads();
        #pragma unroll
        for (int i = 0; i < 2; i++) {
            int c = i * 256 + t;
            GLDS16(A + (long)(m0 + (c >> 2)) * K + k0 + ((c & 3) << 3), &As[c * 8]);
        }
        #pragma unroll
        for (int i = 0; i < 2; i++) {
            int c = i * 256 + t;
            int nr = n0 + (c >> 2);
            bf16x8 bv;
            if (nr < N) {
                const float* wp = Wt + (long)nr * K + k0 + ((c & 3) << 3);
                float4 b0 = *reinterpret_cast<const float4*>(wp);
                float4 b1 = *reinterpret_cast<const float4*>(wp + 4);
                bv[0] = (__bf16)b0.x; bv[1] = (__bf16)b0.y; bv[2] = (__bf16)b0.z; bv[3] = (__bf16)b0.w;
                bv[4] = (__bf16)b1.x; bv[5] = (__bf16)b1.y; bv[6] = (__bf16)b1.z; bv[7] = (__bf16)b1.w;
            } else {
                #pragma unroll
                for (int qq = 0; qq < 8; qq++) bv[qq] = (__bf16)0.f;
            }
            *reinterpret_cast<bf16x8*>(&Bs[c * 8]) = bv;
        }
        __syncthreads();
        bf16x8 afr[4], bfr[4];
        #pragma unroll
        for (int mi = 0; mi < 4; mi++)
            afr[mi] = *reinterpret_cast<const bf16x8*>(&As[(wr * 64 + mi * 16 + lo) * 32 + hi * 8]);
        #pragma unroll
        for (int ni = 0; ni < 4; ni++)
            bfr[ni] = *reinterpret_cast<const bf16x8*>(&Bs[(wc * 64 + ni * 16 + lo) * 32 + hi * 8]);
        #pragma unroll
        for (int mi = 0; mi < 4; mi++)
            #pragma unroll
            for (int ni = 0; ni < 4; ni++)
                acc[mi][ni] = __builtin_amdgcn_mfma_f32_16x16x32_bf16(afr[mi], bfr[ni], acc[mi][ni], 0, 0, 0);
    }

    #pragma unroll
    for (int mi = 0; mi < 4; mi++)
        #pragma unroll
        for (int ni = 0; ni < 4; ni++) {
            int col = n0 + wc * 64 + ni * 16 + lo;
            if (col < N) {
                #pragma unroll
                for (int rr = 0; rr < 4; rr++) {
                    int row = m0 + wr * 64 + mi * 16 + hi * 4 + rr;
                    C[(long)row * N + col] = acc[mi][ni][rr];
                }
            }
        }
}

// ---------- merged: attention (blocks 0..255) + aux BW work (blocks >= 256) ----------
// aux_mode 0: none; 1: tcvt of next layer's weights; 2: wcvt of wte
__global__ __launch_bounds__(256) void attn_aux(
    const __bf16* __restrict__ qkv,
    const float* __restrict__ imgk, const float* __restrict__ imgv,
    const float* __restrict__ amask, __bf16* __restrict__ out,
    int aux_mode,
    const float* __restrict__ Wa, const float* __restrict__ Wp,
    const float* __restrict__ Wf, const float* __restrict__ Wf2,
    __bf16* __restrict__ oa, __bf16* __restrict__ op,
    __bf16* __restrict__ of, __bf16* __restrict__ of2,
    const float* __restrict__ wte, __bf16* __restrict__ wteb, long nvalid)
{
    __shared__ __align__(16) char smem[28416];
    const int bid = blockIdx.x;
    if (bid >= 256) {
        if (aux_mode == 1)
            tcvt_body(bid - 256, Wa, Wp, Wf, Wf2, oa, op, of, of2, (float*)smem);
        else
            wcvt_body(bid - 256, wte, wteb, nvalid);
        return;
    }

    __bf16 (*Ks)[72] = (__bf16(*)[72])(smem);
    __bf16 (*Vt)[72] = (__bf16(*)[72])(smem + 9216);
    __bf16 (*Ps)[16][72] = (__bf16(*)[16][72])(smem + 18432);
    float* kimg_s = (float*)(smem + 27648);
    float* amv_s  = (float*)(smem + 27904);

    const int qb = bid & 7;
    const int h  = (bid >> 3) & 15;
    const int b  = bid >> 7;
    const int t = threadIdx.x, w = t >> 6, lane = t & 63;
    const int lo = lane & 15, hi = lane >> 4;

    const int kr8 = t >> 2, kd8 = (t & 3) * 16;
    const int vr8 = t & 63, vd8 = (t >> 6) * 16;

    const __bf16* qrow = qkv + (long)(b * 512 + qb * 64 + w * 16 + lo) * 3072 + h * 64;
    bf16x8 qf0 = *reinterpret_cast<const bf16x8*>(qrow + hi * 8);
    bf16x8 qf1 = *reinterpret_cast<const bf16x8*>(qrow + 32 + hi * 8);

    if (t < 64) kimg_s[t] = imgk[b * 1024 + h * 64 + t];
    __syncthreads();

    float simg = 0.f;
    #pragma unroll
    for (int i = 0; i < 8; i++)
        simg += (float)qf0[i] * kimg_s[hi * 8 + i] + (float)qf1[i] * kimg_s[32 + hi * 8 + i];
    simg += __shfl_xor(simg, 16);
    simg += __shfl_xor(simg, 32);
    simg *= 0.125f;

    float pimg[4], l_part[4];
    f32x4 o_acc[4];
    #pragma unroll
    for (int rr = 0; rr < 4; rr++) {
        pimg[rr] = __expf(__shfl(simg, hi * 4 + rr));
        l_part[rr] = 0.f;
    }
    #pragma unroll
    for (int df = 0; df < 4; df++) {
        float vi = imgv[b * 1024 + h * 64 + df * 16 + lo];
        #pragma unroll
        for (int rr = 0; rr < 4; rr++) o_acc[df][rr] = pimg[rr] * vi;
    }

    bf16x8 ck0, ck1, cv0, cv1;
    {
        const __bf16* ks = qkv + (long)(b * 512 + kr8) * 3072 + 1024 + h * 64 + kd8;
        ck0 = *reinterpret_cast<const bf16x8*>(ks);
        ck1 = *reinterpret_cast<const bf16x8*>(ks + 8);
        const __bf16* vs = qkv + (long)(b * 512 + vr8) * 3072 + 2048 + h * 64 + vd8;
        cv0 = *reinterpret_cast<const bf16x8*>(vs);
        cv1 = *reinterpret_cast<const bf16x8*>(vs + 8);
    }

    for (int kb = 0; kb <= qb; kb++) {
        bf16x8 nk0, nk1, nv0, nv1;
        const bool more = (kb < qb);
        if (more) {
            const __bf16* ks = qkv + (long)(b * 512 + (kb + 1) * 64 + kr8) * 3072 + 1024 + h * 64 + kd8;
            nk0 = *reinterpret_cast<const bf16x8*>(ks);
            nk1 = *reinterpret_cast<const bf16x8*>(ks + 8);
            const __bf16* vs = qkv + (long)(b * 512 + (kb + 1) * 64 + vr8) * 3072 + 2048 + h * 64 + vd8;
            nv0 = *reinterpret_cast<const bf16x8*>(vs);
            nv1 = *reinterpret_cast<const bf16x8*>(vs + 8);
        }
        __syncthreads();
        *reinterpret_cast<bf16x8*>(&Ks[kr8][kd8])     = ck0;
        *reinterpret_cast<bf16x8*>(&Ks[kr8][kd8 + 8]) = ck1;
        #pragma unroll
        for (int i = 0; i < 8; i++) { Vt[vd8 + i][vr8] = cv0[i]; Vt[vd8 + 8 + i][vr8] = cv1[i]; }
        if (t < 64) amv_s[t] = (1.0f - amask[b * 512 + kb * 64 + t]) * -10000.0f;
        __syncthreads();

        f32x4 sf[4];
        #pragma unroll
        for (int js = 0; js < 4; js++) {
            bf16x8 kf0 = *reinterpret_cast<const bf16x8*>(&Ks[js * 16 + lo][hi * 8]);
            bf16x8 kf1 = *reinterpret_cast<const bf16x8*>(&Ks[js * 16 + lo][32 + hi * 8]);
            f32x4 a = {};
            a = __builtin_amdgcn_mfma_f32_16x16x32_bf16(qf0, kf0, a, 0, 0, 0);
            a = __builtin_amdgcn_mfma_f32_16x16x32_bf16(qf1, kf1, a, 0, 0, 0);
            sf[js] = a;
        }
        #pragma unroll
        for (int js = 0; js < 4; js++) {
            float amv = amv_s[js * 16 + lo];
            #pragma unroll
            for (int rr = 0; rr < 4; rr++) {
                float sv = sf[js][rr] * 0.125f + amv;
                if (kb == qb) {
                    int qrw = w * 16 + hi * 4 + rr;
                    if (js * 16 + lo > qrw) sv = -10000.0f + amv;
                }
                float p = __expf(sv);
                l_part[rr] += p;
                Ps[w][hi * 4 + rr][js * 16 + lo] = (__bf16)p;
            }
        }
        #pragma unroll
        for (int jb = 0; jb < 2; jb++) {
            bf16x8 pf = *reinterpret_cast<const bf16x8*>(&Ps[w][lo][jb * 32 + hi * 8]);
            #pragma unroll
            for (int df = 0; df < 4; df++) {
                bf16x8 vf = *reinterpret_cast<const bf16x8*>(&Vt[df * 16 + lo][jb * 32 + hi * 8]);
                o_acc[df] = __builtin_amdgcn_mfma_f32_16x16x32_bf16(pf, vf, o_acc[df], 0, 0, 0);
            }
        }
        if (more) { ck0 = nk0; ck1 = nk1; cv0 = nv0; cv1 = nv1; }
    }

    float linv[4];
    #pragma unroll
    for (int rr = 0; rr < 4; rr++) {
        float ls = l_part[rr];
        #pragma unroll
        for (int off = 1; off < 16; off <<= 1) ls += __shfl_xor(ls, off);
        linv[rr] = 1.0f / (pimg[rr] + ls);
    }
    #pragma unroll
    for (int df = 0; df < 4; df++)
        #pragma unroll
        for (int rr = 0; rr < 4; rr++) {
            long row = b * 512 + qb * 64 + w * 16 + hi * 4 + rr;
            out[row * 1024 + h * 64 + df * 16 + lo] = (__bf16)(o_acc[df][rr] * linv[rr]);
        }
}

// ---------- host orchestration ----------
extern "C" void kernel_launch(void* const* d_in, const int* in_sizes, int n_in,
                              void* d_out, int out_size, void* d_ws, size_t ws_size,
                              hipStream_t stream) {
    (void)in_sizes; (void)n_in; (void)out_size;
    const int*   ids   = (const int*)d_in[0];
    const float* amask = (const float*)d_in[1];
    const float* ihs   = (const float*)d_in[2];
    const float* wte   = (const float*)d_in[3];
    const float* ftW1  = (const float*)d_in[4];
    const float* ftb1  = (const float*)d_in[5];
    const float* ftW2  = (const float*)d_in[6];
    const float* ftb2  = (const float*)d_in[7];
    const float* ln1g  = (const float*)d_in[8];
    const float* ln1b  = (const float*)d_in[9];
    const float* Wattn = (const float*)d_in[10];
    const float* battn = (const float*)d_in[11];
    const float* Wuk   = (const float*)d_in[12];
    const float* buk   = (const float*)d_in[13];
    const float* Wuv   = (const float*)d_in[14];
    const float* buv   = (const float*)d_in[15];
    const float* Wproj = (const float*)d_in[16];
    const float* bproj = (const float*)d_in[17];
    const float* ln2g  = (const float*)d_in[18];
    const float* ln2b  = (const float*)d_in[19];
    const float* Wfc   = (const float*)d_in[20];
    const float* bfc   = (const float*)d_in[21];
    const float* Wfc2  = (const float*)d_in[22];
    const float* bfc2  = (const float*)d_in[23];
    const float* lnfg  = (const float*)d_in[24];
    const float* lnfb  = (const float*)d_in[25];
    float* out = (float*)d_out;

    const long VP2 = 50432;              // V padded to multiple of 256
    const long NVALID = 50257L * 1024;
    char* base = (char*)d_ws;
    float* ftmp  = (float*)(base);
    float* img   = (float*)(base + (1 << 13));
    float* imgk  = (float*)(base + (1 << 14));
    float* imgv  = (float*)(base + 114688);
    float* part  = (float*)(base + 212992);
    float* h     = (float*)(base + 1048576);
    char* p = base + 5 * 1048576;
    __bf16* xb    = (__bf16*)p; p += 2 * 1048576;
    __bf16* qkvb  = (__bf16*)p; p += 6 * 1048576;
    __bf16* attob = (__bf16*)p; p += 2 * 1048576;
    __bf16* ffb   = (__bf16*)p; p += 8 * 1048576;
    __bf16* wtA0  = (__bf16*)p; p += 6 * 1048576;
    __bf16* wtP0  = (__bf16*)p; p += 2 * 1048576;
    __bf16* wtF0  = (__bf16*)p; p += 8 * 1048576;
    __bf16* wtF20 = (__bf16*)p; p += 8 * 1048576;
    __bf16* wteb  = (__bf16*)p; p += VP2 * 1024 * 2;
    size_t need1 = (size_t)(p - base);
    float* part_g = (float*)(base + need1);
    size_t need2 = need1 + 4 * 1048576 * sizeof(float);
    char* p2 = base + need2;
    __bf16* wtA1  = (__bf16*)p2; p2 += 6 * 1048576;
    __bf16* wtP1  = (__bf16*)p2; p2 += 2 * 1048576;
    __bf16* wtF1  = (__bf16*)p2; p2 += 8 * 1048576;
    __bf16* wtF21 = (__bf16*)p2; p2 += 8 * 1048576;
    size_t need3 = (size_t)(p2 - base);
    const bool big1 = (ws_size >= need1);
    const bool big2 = (ws_size >= need2);
    const bool big3 = (ws_size >= need3);

    __bf16* wtA_s[2]  = {wtA0, wtA1};
    __bf16* wtP_s[2]  = {wtP0, wtP1};
    __bf16* wtF_s[2]  = {wtF0, wtF1};
    __bf16* wtF2_s[2] = {wtF20, wtF21};

    dim3 b256(256);

    // image feature transform + batched K/V projections
    gemv_part<<<dim3(16, 8, 1), b256, 0, stream>>>(ihs, 1024, ftW1, 0, part, 1024, 1024);
    gemv_reduce<<<dim3(8), b256, 0, stream>>>(part, ftb1, 0, ftmp, 1024, 1, 1);
    gemv_part<<<dim3(16, 8, 1), b256, 0, stream>>>(ftmp, 1024, ftW2, 0, part, 1024, 1024);
    gemv_reduce<<<dim3(8), b256, 0, stream>>>(part, ftb2, 0, img, 1024, 1, 0);
    gemv_kv_part<<<dim3(16, 4, 24), b256, 0, stream>>>(img, Wuk, Wuv, part);
    gemv_kv_reduce<<<dim3(192), b256, 0, stream>>>(part, buk, buv, imgk, imgv);

    embed_ln<<<dim3(1024), b256, 0, stream>>>(ids, wte, h, xb, ln1g, ln1b);
    // stage layer-0 weights (set 0)
    tcvt_std<<<dim3(3072), b256, 0, stream>>>(
        Wattn, Wproj, Wfc, Wfc2, wtA0, wtP0, wtF0, wtF20);

    for (int l = 0; l < 12; l++) {
        const int cs = big3 ? (l & 1) : 0;
        __bf16* cA  = wtA_s[cs];
        __bf16* cP  = wtP_s[cs];
        __bf16* cF  = wtF_s[cs];
        __bf16* cF2 = wtF2_s[cs];

        if (!big3 && l > 0) {
            tcvt_std<<<dim3(3072), b256, 0, stream>>>(
                Wattn + (long)l * 1024 * 3072, Wproj + (long)l * 1024 * 1024,
                Wfc + (long)l * 1024 * 4096, Wfc2 + (long)l * 4096 * 1024,
                wtA0, wtP0, wtF0, wtF20);
        }

        // qkv
        gemm64<128, 1, 0, 0><<<dim3(384), b256, 0, stream>>>(
            xb, cA, battn + l * 3072, qkvb, 3072, 1024, 16, 24, 1);

        // attn + hidden aux work
        if (big3 && l < 11) {
            const int ns = (l + 1) & 1;
            attn_aux<<<dim3(256 + 3072), b256, 0, stream>>>(
                qkvb, imgk + l * 2048, imgv + l * 2048, amask, attob, 1,
                Wattn + (long)(l + 1) * 1024 * 3072, Wproj + (long)(l + 1) * 1024 * 1024,
                Wfc + (long)(l + 1) * 1024 * 4096, Wfc2 + (long)(l + 1) * 4096 * 1024,
                wtA_s[ns], wtP_s[ns], wtF_s[ns], wtF2_s[ns],
                nullptr, nullptr, 0);
        } else if (big3 && l == 11) {
            attn_aux<<<dim3(256 + 6304), b256, 0, stream>>>(
                qkvb, imgk + l * 2048, imgv + l * 2048, amask, attob, 2,
                nullptr, nullptr, nullptr, nullptr,
                nullptr, nullptr, nullptr, nullptr,
                wte, wteb, NVALID);
        } else {
            attn_aux<<<dim3(256), b256, 0, stream>>>(
                qkvb, imgk + l * 2048, imgv + l * 2048, amask, attob, 0,
                nullptr, nullptr, nullptr, nullptr,
                nullptr, nullptr, nullptr, nullptr,
                nullptr, nullptr, 0);
        }

        const float* ng = (l < 11) ? (ln1g + (l + 1) * 1024) : lnfg;
        const float* nb = (l < 11) ? (ln1b + (l + 1) * 1024) : lnfb;
        if (big2) {
            gemm64<64, 0, 0, 1><<<dim3(512), b256, 0, stream>>>(
                attob, cP, nullptr, part_g, 1024, 1024, 16, 16, 2);
            lnadd_k<2><<<dim3(1024), b256, 0, stream>>>(
                h, part_g, bproj + l * 1024, ln2g + l * 1024, ln2b + l * 1024, xb);
            gemm64<128, 1, 1, 0><<<dim3(512), b256, 0, stream>>>(
                xb, cF, bfc + l * 4096, ffb, 4096, 1024, 16, 32, 1);
            gemm64<128, 0, 0, 1><<<dim3(512), b256, 0, stream>>>(
                ffb, cF2, nullptr, part_g, 1024, 4096, 16, 8, 4);
            lnadd_k<4><<<dim3(1024), b256, 0, stream>>>(
                h, part_g, bfc2 + l * 1024, ng, nb, xb);
        } else {
            gemm_bb<0, 0, 1><<<dim3(16, 16), b256, 0, stream>>>(
                attob, cP, bproj + l * 1024, h, h, 1024, 1024);
            ln_k<<<dim3(1024), b256, 0, stream>>>(h, xb, ln2g + l * 1024, ln2b + l * 1024);
            gemm64<128, 1, 1, 0><<<dim3(512), b256, 0, stream>>>(
                xb, cF, bfc + l * 4096, ffb, 4096, 1024, 16, 32, 1);
            gemm_bb<0, 0, 1><<<dim3(16, 16), b256, 0, stream>>>(
                ffb, cF2, bfc2 + l * 1024, h, h, 1024, 4096);
            ln_k<<<dim3(1024), b256, 0, stream>>>(h, xb, ng, nb);
        }
    }

    // xb holds lnf(h)
    if (big1) {
        if (!big3)  // wcvt wasn't hidden under layer-11 attn
            wcvt_std<<<dim3((unsigned)(VP2 * 1024 / 8192)), b256, 0, stream>>>(wte, wteb, NVALID);
        gemm256<<<dim3(788), dim3(512), 0, stream>>>(
            xb, wteb, out, 50257, 1024, 4, (int)(VP2 / 256));
    } else {
        gemm_lm<<<dim3(8, 393), b256, 0, stream>>>(xb, wte, out, 50257, 1024);
    }
}